// Round 8
// baseline (338.462 us; speedup 1.0000x reference)
//
#include <hip/hip_runtime.h>
#include <hip/hip_bf16.h>

#define N_NODES 50000
#define N_EDGES 800000
#define N_TOT   850000   // edges + self loops
#define MAXD    128      // LDS-staged edges per node; tail handled by fallback

// bucketed CSR build: bucket = dst >> 8 (256 nodes/bucket)
#define NBUCK 196        // ceil(50000/256)
#define BCAP  8192       // fixed bucket capacity (mean 4337, std ~66 -> 58 sigma slack)

typedef __hip_bfloat16 bf16;
typedef __attribute__((ext_vector_type(8))) short bf16x8;   // MFMA A/B frag (4 VGPRs)
typedef __attribute__((ext_vector_type(4))) float f32x4;    // MFMA C/D frag

__device__ __forceinline__ unsigned short f2bu(float v){
  union { bf16 b; unsigned short u; } cv; cv.b = __float2bfloat16(v); return cv.u;
}
__device__ __forceinline__ float bflo(unsigned int d){ return __uint_as_float(d << 16); }
__device__ __forceinline__ float bfhi(unsigned int d){ return __uint_as_float(d & 0xffff0000u); }

// ---------------- W-frag prep + attention-vector fold + bucket-cursor init ----------------
// blocks 0..127: W1,W2 -> bf16 B-frag layout. block 128: ws1/wd1. block 129: init bcur.
__global__ __launch_bounds__(256) void wfrag_kernel(const float* __restrict__ W1, const float* __restrict__ W2,
    const float* __restrict__ a1s, const float* __restrict__ a1d,
    unsigned short* __restrict__ wf1, unsigned short* __restrict__ wf2,
    float* __restrict__ ws1, float* __restrict__ wd1, int* __restrict__ bcur){
  int b = blockIdx.x, tid = threadIdx.x;
  if (b < 128) {
    int i = b*256 + tid;   // 32768 threads exact
    if (i < 16384) {
      int k = i >> 8, n = i & 255;
      int kk = k >> 5, qq = (k >> 3) & 3, j = k & 7, nt = n >> 4, cc = n & 15;
      wf1[(((kk*16 + nt)*4 + qq)*16 + cc)*8 + j] = f2bu(W1[i]);
    } else {
      int i2 = i - 16384;
      int k = i2 >> 6, n = i2 & 63;
      int kk = k >> 5, qq = (k >> 3) & 3, j = k & 7, ch = n >> 4, cc = n & 15;
      wf2[(((kk*4 + ch)*4 + qq)*16 + cc)*8 + j] = f2bu(W2[i2]);
    }
  } else if (b == 128) {
    // ws1[k][h] = sum_c W1[k, h*64+c] * a1s[h, c]   (64x4 each)
    int k = tid >> 2, h = tid & 3;
    const float* wrow = W1 + k*256 + h*64;
    const float* as = a1s + h*64;
    const float* ad = a1d + h*64;
    float ss = 0.f, sd = 0.f;
    #pragma unroll 8
    for (int c = 0; c < 64; ++c) {
      float wv = wrow[c];
      ss = fmaf(wv, as[c], ss);
      sd = fmaf(wv, ad[c], sd);
    }
    ws1[k*4 + h] = ss;
    wd1[k*4 + h] = sd;
  } else {
    if (tid < NBUCK) bcur[tid] = tid * BCAP;
  }
}

// ---------------- CSR build, stage 1: bin edges into 196 bucket regions ----------------
__global__ __launch_bounds__(256) void binscatter_kernel(const int* __restrict__ ei,
    int* __restrict__ bcur, unsigned int* __restrict__ pairbuf){
  __shared__ int hist[NBUCK];
  __shared__ int gbase[NBUCK];
  int tid = threadIdx.x;
  if (tid < NBUCK) hist[tid] = 0;
  __syncthreads();
  int base = blockIdx.x * 4096;
  #pragma unroll 4
  for (int i = 0; i < 16; ++i) {
    int k = base + i*256 + tid;
    if (k < N_TOT) {
      int c = (k < N_EDGES) ? ei[N_EDGES + k] : (k - N_EDGES);
      atomicAdd(&hist[c >> 8], 1);
    }
  }
  __syncthreads();
  if (tid < NBUCK) {
    int h = hist[tid];
    gbase[tid] = h ? atomicAdd(&bcur[tid], h) : 0;
    hist[tid] = 0;                       // reuse as local cursor
  }
  __syncthreads();
  #pragma unroll 4
  for (int i = 0; i < 16; ++i) {
    int k = base + i*256 + tid;
    if (k < N_TOT) {
      int r, c;
      if (k < N_EDGES) { r = ei[k]; c = ei[N_EDGES + k]; } else { r = c = k - N_EDGES; }
      int b = c >> 8;
      int lpos = atomicAdd(&hist[b], 1);
      pairbuf[gbase[b] + lpos] = (unsigned)r | ((unsigned)(c & 255) << 16);
    }
  }
}

// ---------------- CSR build, stage 2: scan the 196 bucket totals -> bucket bases ----------------
__global__ __launch_bounds__(256) void scan196_kernel(const int* __restrict__ bcur,
    int* __restrict__ bbase, int* __restrict__ offs){
  __shared__ int sm[256];
  int tid = threadIdx.x;
  int v = 0;
  if (tid < NBUCK) {
    v = bcur[tid] - tid*BCAP;
    if (v < 0) v = 0; if (v > BCAP) v = BCAP;
  }
  sm[tid] = v;
  __syncthreads();
  for (int off = 1; off < 256; off <<= 1) {
    int t = (tid >= off) ? sm[tid - off] : 0;
    __syncthreads();
    sm[tid] += t;
    __syncthreads();
  }
  if (tid < NBUCK) bbase[tid] = sm[tid] - v;    // exclusive
  if (tid == 0) offs[N_NODES] = N_TOT;
}

// ---------------- CSR build, stage 3: per-bucket count+scan+offs+scatter, one kernel ----------------
__global__ __launch_bounds__(256) void lscatter2_kernel(const unsigned int* __restrict__ pairbuf,
    const int* __restrict__ bcur, const int* __restrict__ bbase,
    int* __restrict__ offs, int* __restrict__ srcs){
  __shared__ int lhist[256];
  __shared__ int lcur[256];
  int b = blockIdx.x, tid = threadIdx.x;
  lhist[tid] = 0;
  __syncthreads();
  int base = b * BCAP;
  int size = bcur[b] - base; if (size > BCAP) size = BCAP; if (size < 0) size = 0;
  for (int j = tid; j < size; j += 256)
    atomicAdd(&lhist[pairbuf[base + j] >> 16], 1);
  __syncthreads();
  int v = lhist[tid];
  lcur[tid] = v;
  __syncthreads();
  for (int off = 1; off < 256; off <<= 1) {
    int t = (tid >= off) ? lcur[tid - off] : 0;
    __syncthreads();
    lcur[tid] += t;
    __syncthreads();
  }
  int excl = lcur[tid] - v;
  int gpos = bbase[b] + excl;
  int node = b*256 + tid;
  if (node < N_NODES) offs[node] = gpos;
  __syncthreads();
  lcur[tid] = gpos;       // per-node cursor
  __syncthreads();
  for (int j = tid; j < size; j += 256) {
    unsigned pv = pairbuf[base + j];
    int pos = atomicAdd(&lcur[pv >> 16], 1);
    srcs[pos] = (int)(pv & 0xFFFFu);
  }
}

// ---------------- xprep: xb = bf16(x); al1{s,d} = x @ w{s,d}1 ----------------
__global__ __launch_bounds__(256) void xprep_kernel(const float* __restrict__ x,
    const float* __restrict__ ws1, const float* __restrict__ wd1,
    unsigned short* __restrict__ xb, float* __restrict__ al1s, float* __restrict__ al1d){
  __shared__ float sws[64][4], swd[64][4];
  int tid = threadIdx.x;
  sws[tid >> 2][tid & 3] = ws1[tid];
  swd[tid >> 2][tid & 3] = wd1[tid];
  __syncthreads();
  int lane = tid & 63, wave = tid >> 6;
  int g = lane & 15, sub = lane >> 4;
  int n = blockIdx.x*16 + wave*4 + sub;     // 50000/16 = 3125 exact
  float4 xv = *(const float4*)(x + (size_t)n*64 + g*4);
  uint2 dd;
  dd.x = (unsigned)f2bu(xv.x) | ((unsigned)f2bu(xv.y) << 16);
  dd.y = (unsigned)f2bu(xv.z) | ((unsigned)f2bu(xv.w) << 16);
  ((uint2*)xb)[(size_t)n*16 + g] = dd;
  int c0 = g*4;
  float ps0 = 0.f, ps1 = 0.f, ps2 = 0.f, ps3 = 0.f;
  float pd0 = 0.f, pd1 = 0.f, pd2 = 0.f, pd3 = 0.f;
  float xc[4] = {xv.x, xv.y, xv.z, xv.w};
  #pragma unroll
  for (int i = 0; i < 4; ++i) {
    int c = c0 + i;
    ps0 = fmaf(xc[i], sws[c][0], ps0); ps1 = fmaf(xc[i], sws[c][1], ps1);
    ps2 = fmaf(xc[i], sws[c][2], ps2); ps3 = fmaf(xc[i], sws[c][3], ps3);
    pd0 = fmaf(xc[i], swd[c][0], pd0); pd1 = fmaf(xc[i], swd[c][1], pd1);
    pd2 = fmaf(xc[i], swd[c][2], pd2); pd3 = fmaf(xc[i], swd[c][3], pd3);
  }
  #pragma unroll
  for (int off = 1; off < 16; off <<= 1) {
    ps0 += __shfl_xor(ps0, off, 64); ps1 += __shfl_xor(ps1, off, 64);
    ps2 += __shfl_xor(ps2, off, 64); ps3 += __shfl_xor(ps3, off, 64);
    pd0 += __shfl_xor(pd0, off, 64); pd1 += __shfl_xor(pd1, off, 64);
    pd2 += __shfl_xor(pd2, off, 64); pd3 += __shfl_xor(pd3, off, 64);
  }
  if (g < 4)      al1s[(size_t)n*4 + g]       = (g==0)?ps0:(g==1)?ps1:(g==2)?ps2:ps3;
  else if (g < 8) al1d[(size_t)n*4 + (g-4)]   = (g==4)?pd0:(g==5)?pd1:(g==6)?pd2:pd3;
}

// ------- Attention layer 1 in x-space: ag[n,h,:64] = sum_j alpha_{j,h} * xb[r_j]
// zero-padded p-buffer (no bounds mask) + unroll 2 (VGPR ~28 -> 65% occupancy [R7])
__global__ __launch_bounds__(256, 8) void attn1x_kernel(const unsigned short* __restrict__ xb,
    const float* __restrict__ al1s, const float* __restrict__ al1d,
    const int* __restrict__ offs, const int* __restrict__ srcs,
    bf16* __restrict__ ag){
  __shared__ __align__(16) float ebuf[4][MAXD+4][4];     // p values, +4 zero pad
  __shared__ int sbuf[4][MAXD+4];

  int wave = threadIdx.x >> 6, lane = threadIdx.x & 63;
  int n = blockIdx.x*4 + wave;          // 50000 % 4 == 0: no tail
  int start = offs[n], end = offs[n+1];
  int deg = end - start;
  int lim = deg < MAXD ? deg : MAXD;
  float4 aldv = *(const float4*)(al1d + (size_t)n*4);
  float ald0 = aldv.x, ald1 = aldv.y, ald2 = aldv.z, ald3 = aldv.w;

  // stage pass: gather als, e=lrelu, p=exp(e); stage p+src; lane sums
  float s0 = 0.f, s1 = 0.f, s2 = 0.f, s3 = 0.f;
  {
    int idx = lane;
    for (int j = start + lane; j < end; j += 64, idx += 64) {
      int r = srcs[j];
      float4 als = *(const float4*)(al1s + (size_t)r*4);
      float e0 = als.x + ald0; e0 = e0 >= 0.f ? e0 : 0.2f*e0; float p0 = __expf(e0); s0 += p0;
      float e1 = als.y + ald1; e1 = e1 >= 0.f ? e1 : 0.2f*e1; float p1 = __expf(e1); s1 += p1;
      float e2 = als.z + ald2; e2 = e2 >= 0.f ? e2 : 0.2f*e2; float p2 = __expf(e2); s2 += p2;
      float e3 = als.w + ald3; e3 = e3 >= 0.f ? e3 : 0.2f*e3; float p3 = __expf(e3); s3 += p3;
      if (idx < MAXD) {
        sbuf[wave][idx] = r;
        *(float4*)&ebuf[wave][idx][0] = make_float4(p0, p1, p2, p3);
      }
    }
  }
  // zero-pad 4 slots past lim: aggregation loop then needs no bounds mask
  if (lane < 4) {
    int ip = lim + lane;
    sbuf[wave][ip] = 0;
    *(float4*)&ebuf[wave][ip][0] = make_float4(0.f, 0.f, 0.f, 0.f);
  }
  #pragma unroll
  for (int off = 32; off; off >>= 1) {
    s0 += __shfl_xor(s0, off, 64);
    s1 += __shfl_xor(s1, off, 64);
    s2 += __shfl_xor(s2, off, 64);
    s3 += __shfl_xor(s3, off, 64);
  }
  float inv0 = 1.f/(s0 + 1e-16f), inv1 = 1.f/(s1 + 1e-16f);
  float inv2 = 1.f/(s2 + 1e-16f), inv3 = 1.f/(s3 + 1e-16f);

  // aggregation: lane -> (edge-slot es=lane>>4 of 4, ch-lane cl=lane&15: ch cl*4..cl*4+3)
  int cl = lane & 15, es = lane >> 4;
  float acc[4][4];
  #pragma unroll
  for (int h = 0; h < 4; ++h)
    #pragma unroll
    for (int i = 0; i < 4; ++i) acc[h][i] = 0.f;
  {
    const uint2* base2 = (const uint2*)xb;   // row = 16 uint2 (128B)
    #pragma unroll 2
    for (int jj = 0; jj < lim; jj += 4) {
      int idx = jj + es;                     // <= lim+2 < lim+4 (padded)
      int r = sbuf[wave][idx];
      float4 pv = *(const float4*)&ebuf[wave][idx][0];
      uint2 d = base2[(size_t)r*16 + cl];
      float c0 = bflo(d.x), c1 = bfhi(d.x), c2 = bflo(d.y), c3 = bfhi(d.y);
      acc[0][0] = fmaf(pv.x, c0, acc[0][0]); acc[0][1] = fmaf(pv.x, c1, acc[0][1]);
      acc[0][2] = fmaf(pv.x, c2, acc[0][2]); acc[0][3] = fmaf(pv.x, c3, acc[0][3]);
      acc[1][0] = fmaf(pv.y, c0, acc[1][0]); acc[1][1] = fmaf(pv.y, c1, acc[1][1]);
      acc[1][2] = fmaf(pv.y, c2, acc[1][2]); acc[1][3] = fmaf(pv.y, c3, acc[1][3]);
      acc[2][0] = fmaf(pv.z, c0, acc[2][0]); acc[2][1] = fmaf(pv.z, c1, acc[2][1]);
      acc[2][2] = fmaf(pv.z, c2, acc[2][2]); acc[2][3] = fmaf(pv.z, c3, acc[2][3]);
      acc[3][0] = fmaf(pv.w, c0, acc[3][0]); acc[3][1] = fmaf(pv.w, c1, acc[3][1]);
      acc[3][2] = fmaf(pv.w, c2, acc[3][2]); acc[3][3] = fmaf(pv.w, c3, acc[3][3]);
    }
  }
  if (deg > MAXD) {       // rare overflow tail: recompute p per lane (masked scalar path)
    const uint2* base2 = (const uint2*)xb;
    for (int jj = MAXD; jj < deg; jj += 4) {
      int idx = jj + es;
      bool ok = idx < deg;
      int j = ok ? (start + idx) : start;
      int r = srcs[j];
      float4 als = *(const float4*)(al1s + (size_t)r*4);
      float e0 = als.x + ald0; e0 = e0 >= 0.f ? e0 : 0.2f*e0; float p0 = __expf(e0);
      float e1 = als.y + ald1; e1 = e1 >= 0.f ? e1 : 0.2f*e1; float p1 = __expf(e1);
      float e2 = als.z + ald2; e2 = e2 >= 0.f ? e2 : 0.2f*e2; float p2 = __expf(e2);
      float e3 = als.w + ald3; e3 = e3 >= 0.f ? e3 : 0.2f*e3; float p3 = __expf(e3);
      float m = ok ? 1.f : 0.f;
      uint2 d = base2[(size_t)r*16 + cl];
      float c0 = bflo(d.x)*m, c1 = bfhi(d.x)*m, c2 = bflo(d.y)*m, c3 = bfhi(d.y)*m;
      acc[0][0] = fmaf(p0, c0, acc[0][0]); acc[0][1] = fmaf(p0, c1, acc[0][1]);
      acc[0][2] = fmaf(p0, c2, acc[0][2]); acc[0][3] = fmaf(p0, c3, acc[0][3]);
      acc[1][0] = fmaf(p1, c0, acc[1][0]); acc[1][1] = fmaf(p1, c1, acc[1][1]);
      acc[1][2] = fmaf(p1, c2, acc[1][2]); acc[1][3] = fmaf(p1, c3, acc[1][3]);
      acc[2][0] = fmaf(p2, c0, acc[2][0]); acc[2][1] = fmaf(p2, c1, acc[2][1]);
      acc[2][2] = fmaf(p2, c2, acc[2][2]); acc[2][3] = fmaf(p2, c3, acc[2][3]);
      acc[3][0] = fmaf(p3, c0, acc[3][0]); acc[3][1] = fmaf(p3, c1, acc[3][1]);
      acc[3][2] = fmaf(p3, c2, acc[3][2]); acc[3][3] = fmaf(p3, c3, acc[3][3]);
    }
  }
  // fold the 4 edge slots (lane bits 4,5)
  #pragma unroll
  for (int h = 0; h < 4; ++h)
    #pragma unroll
    for (int i = 0; i < 4; ++i) {
      acc[h][i] += __shfl_xor(acc[h][i], 16, 64);
      acc[h][i] += __shfl_xor(acc[h][i], 32, 64);
    }
  // lane l writes head h=es, channels cl*4..cl*4+3: ag[n][es*64 + cl*4 ...] (coalesced 512B/row)
  {
    float invh = (es==0)?inv0:(es==1)?inv1:(es==2)?inv2:inv3;
    float o0 = ((es==0)?acc[0][0]:(es==1)?acc[1][0]:(es==2)?acc[2][0]:acc[3][0]) * invh;
    float o1 = ((es==0)?acc[0][1]:(es==1)?acc[1][1]:(es==2)?acc[2][1]:acc[3][1]) * invh;
    float o2 = ((es==0)?acc[0][2]:(es==1)?acc[1][2]:(es==2)?acc[2][2]:acc[3][2]) * invh;
    float o3 = ((es==0)?acc[0][3]:(es==1)?acc[1][3]:(es==2)?acc[2][3]:acc[3][3]) * invh;
    uint2 dd;
    dd.x = (unsigned)f2bu(o0) | ((unsigned)f2bu(o1) << 16);
    dd.y = (unsigned)f2bu(o2) | ((unsigned)f2bu(o3) << 16);
    ((uint2*)ag)[(size_t)n*64 + lane] = dd;
  }
}

// ---------------- GEMM1b (MFMA, block-diagonal): h1[:, h*64:+64] = elu(ag[:,h,:] @ W1[, h] + b1)
__global__ __launch_bounds__(256) void gemm1b_kernel(const unsigned short* __restrict__ ag,
    const unsigned short* __restrict__ wf1, const float* __restrict__ b1, bf16* __restrict__ h1){
  __shared__ __align__(16) unsigned short ctile[32*264];       // half-tile bf16, 16.5KB
  int tid = threadIdx.x, wave = tid >> 6, lane = tid & 63;
  int q = lane >> 4, c = lane & 15;
  int n0 = blockIdx.x * 64;

  union { uint4 u; bf16x8 v; } bfr[2][4];
  #pragma unroll
  for (int kk = 0; kk < 2; ++kk)
    #pragma unroll
    for (int nti = 0; nti < 4; ++nti)
      bfr[kk][nti].u = *(const uint4*)(wf1 + (size_t)((((kk*16 + wave*4 + nti)*4 + q)*16 + c)*8));

  float b1v[4];
  #pragma unroll
  for (int nti = 0; nti < 4; ++nti) b1v[nti] = b1[(wave*4 + nti)*16 + c];

  #pragma unroll
  for (int half = 0; half < 2; ++half) {
    #pragma unroll
    for (int sti = 0; sti < 2; ++sti) {
      int st = half*2 + sti;
      int row = n0 + st*16 + c;
      if (row >= N_NODES) row = N_NODES - 1;   // tail clamp; stores guarded below
      bf16x8 afr[2];
      #pragma unroll
      for (int kk = 0; kk < 2; ++kk) {
        union { uint4 u; bf16x8 v; } a;
        a.u = *(const uint4*)(ag + (size_t)row*256 + wave*64 + kk*32 + q*8);
        afr[kk] = a.v;
      }
      #pragma unroll
      for (int nti = 0; nti < 4; ++nti) {
        f32x4 acc = {0.f, 0.f, 0.f, 0.f};
        #pragma unroll
        for (int kk = 0; kk < 2; ++kk)
          acc = __builtin_amdgcn_mfma_f32_16x16x32_bf16(afr[kk], bfr[kk][nti].v, acc, 0, 0, 0);
        int lrow = sti*16 + q*4, nt = wave*4 + nti;
        #pragma unroll
        for (int r = 0; r < 4; ++r) {
          float o = acc[r] + b1v[nti];
          o = o > 0.f ? o : expm1f(o);
          ctile[(lrow + r)*264 + nt*16 + c] = f2bu(o);
        }
      }
    }
    __syncthreads();
    // store phase: wave w -> local rows w*8..w*8+7; coalesced 512B/row
    #pragma unroll 1
    for (int i = 0; i < 8; ++i) {
      int lr = wave*8 + i;
      int node = n0 + half*32 + lr;
      if (node < N_NODES) {
        uint2 dd = *(const uint2*)&ctile[lr*264 + lane*4];
        ((uint2*)h1)[(size_t)node*64 + lane] = dd;
      }
    }
    __syncthreads();
  }
}

// ---------------- GEMM2 (MFMA): h2pre = h1 @ W2  [50000,256]bf16 x [256,64], fused al2 ----------------
__global__ __launch_bounds__(256) void gemm2_kernel(const bf16* __restrict__ h1, const unsigned short* __restrict__ wf2,
    const float* __restrict__ a2s, const float* __restrict__ a2d,
    bf16* __restrict__ h2pre, float* __restrict__ al2s, float* __restrict__ al2d){
  __shared__ __align__(16) float ctile[64][65];               // padded
  int tid = threadIdx.x, wave = tid >> 6, lane = tid & 63;
  int q = lane >> 4, c = lane & 15;
  int n0 = blockIdx.x * 64;

  union { uint4 u; bf16x8 v; } bfr[8];
  #pragma unroll
  for (int kk = 0; kk < 8; ++kk)
    bfr[kk].u = *(const uint4*)(wf2 + (size_t)((((kk*4 + wave)*4 + q)*16 + c)*8));

  const unsigned short* h1u = (const unsigned short*)h1;
  #pragma unroll 1
  for (int st = 0; st < 4; ++st) {
    if (n0 + st*16 >= N_NODES) break;
    f32x4 acc = {0.f, 0.f, 0.f, 0.f};
    size_t arow = (size_t)(n0 + st*16 + c)*256 + q*8;
    #pragma unroll
    for (int kk = 0; kk < 8; ++kk) {
      union { uint4 u; bf16x8 v; } a;
      a.u = *(const uint4*)(h1u + arow + kk*32);
      acc = __builtin_amdgcn_mfma_f32_16x16x32_bf16(a.v, bfr[kk].v, acc, 0, 0, 0);
    }
    #pragma unroll
    for (int r = 0; r < 4; ++r)
      ctile[st*16 + q*4 + r][wave*16 + c] = acc[r];
  }
  __syncthreads();

  float as = a2s[lane], ad = a2d[lane];
  #pragma unroll 1
  for (int i = 0; i < 16; ++i) {
    int node = n0 + wave*16 + i;
    if (node >= N_NODES) break;
    float val = ctile[wave*16 + i][lane];
    ((unsigned short*)h2pre)[(size_t)node*64 + lane] = f2bu(val);
    float ps = val*as, pd = val*ad;
    #pragma unroll
    for (int off = 32; off; off >>= 1) { ps += __shfl_xor(ps, off, 64); pd += __shfl_xor(pd, off, 64); }
    if (lane == 0) { al2s[node] = ps; al2d[node] = pd; }
  }
}

// ---------------- Attention layer 2 (H=1) + fused node head + u/v (distributed epilogue) ----------------
// After the fold, each es-group of 8 lanes holds the full 64-ch h2 row (lane cl has ch cl*8..cl*8+7):
// node_out via 8x float4 Wn loads + 32 fma/lane + 3-level shuffle; u/v via 16 fma + 3-level shuffle.
__global__ __launch_bounds__(512, 8) void attn2_kernel(const bf16* __restrict__ h2pre,
    const float* __restrict__ al2s, const float* __restrict__ al2d,
    const int* __restrict__ offs, const int* __restrict__ srcs,
    const float* __restrict__ b2, const float* __restrict__ Wn, const float* __restrict__ bn,
    const float* __restrict__ We,
    float* __restrict__ u, float* __restrict__ v, float* __restrict__ node_out){
  __shared__ float ebuf[8][MAXD+8];             // p values, +8 zero pad
  __shared__ int   sbuf[8][MAXD+8];
  int wave = threadIdx.x >> 6, lane = threadIdx.x & 63;
  int n = blockIdx.x*8 + wave;        // exact
  int start = offs[n], end = offs[n+1];
  int deg = end - start;
  int lim = deg < MAXD ? deg : MAXD;
  float ald = al2d[n];

  float sm = 0.f;
  {
    int idx = lane;
    for (int j = start + lane; j < end; j += 64, idx += 64) {
      int r = srcs[j];
      float t = al2s[r] + ald; t = t >= 0.f ? t : 0.2f*t;
      float p = __expf(t); sm += p;
      if (idx < MAXD) { sbuf[wave][idx] = r; ebuf[wave][idx] = p; }
    }
  }
  if (lane < 8) { int ip = lim + lane; sbuf[wave][ip] = 0; ebuf[wave][ip] = 0.f; }
  #pragma unroll
  for (int off = 32; off; off >>= 1) sm += __shfl_xor(sm, off, 64);
  float inv = 1.f/(sm + 1e-16f);

  // aggregation: lane -> (edge-slot es=lane>>3, channel-lane cl=lane&7); uint4 = channels cl*8..cl*8+7
  int cl = lane & 7, es = lane >> 3;
  float acc0 = 0.f, acc1 = 0.f, acc2 = 0.f, acc3 = 0.f;
  float acc4 = 0.f, acc5 = 0.f, acc6 = 0.f, acc7 = 0.f;
  {
    const uint4* base4 = (const uint4*)h2pre;   // row = 8 uint4
    #pragma unroll 2
    for (int jj = 0; jj < lim; jj += 8) {
      int idx = jj + es;                        // <= lim+6 < lim+8 (padded)
      int r = sbuf[wave][idx];
      float p = ebuf[wave][idx];
      uint4 d = base4[(size_t)r*8 + cl];
      acc0 = fmaf(p, bflo(d.x), acc0);
      acc1 = fmaf(p, bfhi(d.x), acc1);
      acc2 = fmaf(p, bflo(d.y), acc2);
      acc3 = fmaf(p, bfhi(d.y), acc3);
      acc4 = fmaf(p, bflo(d.z), acc4);
      acc5 = fmaf(p, bfhi(d.z), acc5);
      acc6 = fmaf(p, bflo(d.w), acc6);
      acc7 = fmaf(p, bfhi(d.w), acc7);
    }
  }
  if (deg > MAXD) {     // rare overflow tail
    const uint4* base4 = (const uint4*)h2pre;
    for (int jj = MAXD; jj < deg; jj += 8) {
      int idx = jj + es;
      bool ok = idx < deg;
      int j = ok ? (start + idx) : start;
      int r = srcs[j];
      float t = al2s[r] + ald; t = t >= 0.f ? t : 0.2f*t;
      float p = ok ? __expf(t) : 0.f;
      uint4 d = base4[(size_t)r*8 + cl];
      acc0 = fmaf(p, bflo(d.x), acc0);
      acc1 = fmaf(p, bfhi(d.x), acc1);
      acc2 = fmaf(p, bflo(d.y), acc2);
      acc3 = fmaf(p, bfhi(d.y), acc3);
      acc4 = fmaf(p, bflo(d.z), acc4);
      acc5 = fmaf(p, bfhi(d.z), acc5);
      acc6 = fmaf(p, bflo(d.w), acc6);
      acc7 = fmaf(p, bfhi(d.w), acc7);
    }
  }
  // fold the 8 edge-slots (xor butterfly over lane bits 3,4,5); all lanes end with full ch sums
  #pragma unroll
  for (int off = 8; off < 64; off <<= 1) {
    acc0 += __shfl_xor(acc0, off, 64);
    acc1 += __shfl_xor(acc1, off, 64);
    acc2 += __shfl_xor(acc2, off, 64);
    acc3 += __shfl_xor(acc3, off, 64);
    acc4 += __shfl_xor(acc4, off, 64);
    acc5 += __shfl_xor(acc5, off, 64);
    acc6 += __shfl_xor(acc6, off, 64);
    acc7 += __shfl_xor(acc7, off, 64);
  }

  // post-ELU h2 channels cl*8..cl*8+7 in every lane
  float4 b2a = *(const float4*)(b2 + cl*8);
  float4 b2b = *(const float4*)(b2 + cl*8 + 4);
  float ov[8];
  ov[0] = acc0*inv + b2a.x; ov[0] = ov[0] > 0.f ? ov[0] : expm1f(ov[0]);
  ov[1] = acc1*inv + b2a.y; ov[1] = ov[1] > 0.f ? ov[1] : expm1f(ov[1]);
  ov[2] = acc2*inv + b2a.z; ov[2] = ov[2] > 0.f ? ov[2] : expm1f(ov[2]);
  ov[3] = acc3*inv + b2a.w; ov[3] = ov[3] > 0.f ? ov[3] : expm1f(ov[3]);
  ov[4] = acc4*inv + b2b.x; ov[4] = ov[4] > 0.f ? ov[4] : expm1f(ov[4]);
  ov[5] = acc5*inv + b2b.y; ov[5] = ov[5] > 0.f ? ov[5] : expm1f(ov[5]);
  ov[6] = acc6*inv + b2b.z; ov[6] = ov[6] > 0.f ? ov[6] : expm1f(ov[6]);
  ov[7] = acc7*inv + b2b.w; ov[7] = ov[7] > 0.f ? ov[7] : expm1f(ov[7]);

  // node_out = h2 @ Wn + bn (Wn [64,32]): es-group g handles cols g*4..g*4+3
  {
    int c0 = cl*8;
    float p0 = 0.f, p1 = 0.f, p2 = 0.f, p3 = 0.f;
    #pragma unroll
    for (int i = 0; i < 8; ++i) {
      float4 wr = *(const float4*)(Wn + (size_t)(c0 + i)*32 + es*4);
      p0 = fmaf(ov[i], wr.x, p0);
      p1 = fmaf(ov[i], wr.y, p1);
      p2 = fmaf(ov[i], wr.z, p2);
      p3 = fmaf(ov[i], wr.w, p3);
    }
    #pragma unroll
    for (int off = 1; off < 8; off <<= 1) {
      p0 += __shfl_xor(p0, off, 64);
      p1 += __shfl_xor(p1, off, 64);
      p2 += __shfl_xor(p2, off, 64);
      p3 += __shfl_xor(p3, off, 64);
    }
    if (cl < 4) {
      float pr = (cl==0)?p0:(cl==1)?p1:(cl==2)?p2:p3;
      int j = es*4 + cl;
      node_out[(size_t)n*32 + j] = pr + bn[j];
    }
  }
  // u = h2 . We[0:64], v = h2 . We[64:128]
  {
    int c0 = cl*8;
    float4 wea = *(const float4*)(We + c0);
    float4 web = *(const float4*)(We + c0 + 4);
    float4 wva = *(const float4*)(We + 64 + c0);
    float4 wvb = *(const float4*)(We + 64 + c0 + 4);
    float pu = ov[0]*wea.x + ov[1]*wea.y + ov[2]*wea.z + ov[3]*wea.w
             + ov[4]*web.x + ov[5]*web.y + ov[6]*web.z + ov[7]*web.w;
    float pv = ov[0]*wva.x + ov[1]*wva.y + ov[2]*wva.z + ov[3]*wva.w
             + ov[4]*wvb.x + ov[5]*wvb.y + ov[6]*wvb.z + ov[7]*wvb.w;
    #pragma unroll
    for (int off = 1; off < 8; off <<= 1) {
      pu += __shfl_xor(pu, off, 64);
      pv += __shfl_xor(pv, off, 64);
    }
    if (lane == 0) { u[n] = pu; v[n] = pv; }
  }
}

// ---------------- Edge head: out = u[row] + v[col] + edge_attr . We[128:144] + be ----------------
__global__ __launch_bounds__(256) void edge_kernel(const int* __restrict__ ei, const float* __restrict__ ea,
    const float* __restrict__ u, const float* __restrict__ v,
    const float* __restrict__ We, const float* __restrict__ be, float* __restrict__ out){
  int k = blockIdx.x*256 + threadIdx.x;   // grid is exact: 800000/256
  int r = ei[k], c = ei[N_EDGES + k];
  float val = u[r] + v[c] + be[0];
  const float4* wp = (const float4*)(We + 128);
  const float4* p  = (const float4*)(ea + (size_t)k*16);
  #pragma unroll
  for (int jj = 0; jj < 4; jj++) {
    float4 q = p[jj], wq = wp[jj];
    val = fmaf(q.x, wq.x, val);
    val = fmaf(q.y, wq.y, val);
    val = fmaf(q.z, wq.z, val);
    val = fmaf(q.w, wq.w, val);
  }
  out[k] = val;
}

extern "C" void kernel_launch(void* const* d_in, const int* in_sizes, int n_in,
                              void* d_out, int out_size, void* d_ws, size_t ws_size,
                              hipStream_t stream) {
  const float* x   = (const float*)d_in[0];
  const int*   ei  = (const int*)d_in[1];
  const float* ea  = (const float*)d_in[2];
  const float* W1  = (const float*)d_in[3];
  const float* a1s = (const float*)d_in[4];
  const float* a1d = (const float*)d_in[5];
  const float* b1  = (const float*)d_in[6];
  const float* W2  = (const float*)d_in[7];
  const float* a2s = (const float*)d_in[8];
  const float* a2d = (const float*)d_in[9];
  const float* b2  = (const float*)d_in[10];
  const float* Wn  = (const float*)d_in[11];
  const float* bn  = (const float*)d_in[12];
  const float* We  = (const float*)d_in[13];
  const float* be  = (const float*)d_in[14];
  float* out = (float*)d_out;

  // ---- workspace layout, peak 64,000,224 B, 16B-aligned ----
  char* w = (char*)d_ws;
  int*   offs   = (int*)(w);                        //       0 .. 200,016
  unsigned short* wf1 = (unsigned short*)(w + 200016); // 32,768 B
  float* ws1    = (float*)(w + 232784);             // 1,024 B
  float* wd1    = (float*)(w + 233808);             // 1,024 B
  unsigned short* wf2 = (unsigned short*)(w + 234832); // 32,768 B (.. 267,600)
  int*   bcur   = (int*)(w + 400016);               // 784 B bucket cursors
  int*   bbase  = (int*)(w + 400816);               // 784 B bucket bases
  int*   srcs   = (int*)(w + 600016);               // 600,016 .. 4,000,016
  float* al1s   = (float*)(w + 4000016);            // [N,4] fp32, .. 4,800,016
  float* al1d   = (float*)(w + 4800016);            // [N,4] fp32, .. 5,600,016
  float* al2s   = (float*)(w + 5600016);            // [N] fp32,  .. 5,800,016
  float* al2d   = (float*)(w + 5800016);            // .. 6,000,016
  float* uu     = (float*)(w + 6000016);            // .. 6,200,016
  float* vv     = (float*)(w + 6200016);            // .. 6,400,016
  bf16*  h2pre  = (bf16*)(w + 6400016);             // [N,64] bf16, .. 12,800,016 (xb aliases BEFORE gemm2)
  bf16*  ag     = (bf16*)(w + 12800016);            // [N,256] bf16 aggregate, .. 38,400,016
  bf16*  h1     = (bf16*)(w + 38400224);            // [N,256] bf16, .. 64,000,224
  unsigned short* xb  = (unsigned short*)h2pre;     // [N,64] bf16 x-table; dead before gemm2 writes h2pre
  unsigned int* pairbuf = (unsigned int*)h1;        // 6.4 MB bucket regions (h1 dead until gemm1b)

  wfrag_kernel     <<<130, 256, 0, stream>>>(W1, W2, a1s, a1d, wf1, wf2, ws1, wd1, bcur);
  binscatter_kernel<<<(N_TOT + 4095)/4096, 256, 0, stream>>>(ei, bcur, pairbuf);
  scan196_kernel   <<<1, 256, 0, stream>>>(bcur, bbase, offs);
  lscatter2_kernel <<<NBUCK, 256, 0, stream>>>(pairbuf, bcur, bbase, offs, srcs);
  xprep_kernel     <<<N_NODES/16, 256, 0, stream>>>(x, ws1, wd1, xb, al1s, al1d);
  attn1x_kernel    <<<N_NODES/4, 256, 0, stream>>>(xb, al1s, al1d, offs, srcs, ag);
  gemm1b_kernel    <<<(N_NODES + 63)/64, 256, 0, stream>>>((const unsigned short*)ag, wf1, b1, h1);
  gemm2_kernel     <<<(N_NODES + 63)/64, 256, 0, stream>>>(h1, wf2, a2s, a2d, h2pre, al2s, al2d);
  attn2_kernel     <<<N_NODES/8, 512, 0, stream>>>(h2pre, al2s, al2d, offs, srcs, b2, Wn, bn, We,
                                                   uu, vv, out);
  edge_kernel      <<<N_EDGES/256, 256, 0, stream>>>(ei, ea, uu, vv, We, be, out + (size_t)N_NODES*32);
}

// Round 9
// 314.479 us; speedup vs baseline: 1.0763x; 1.0763x over previous
//
#include <hip/hip_runtime.h>
#include <hip/hip_bf16.h>

#define N_NODES 50000
#define N_EDGES 800000
#define N_TOT   850000   // edges + self loops
#define MAXD    128      // LDS-staged edges per node; tail handled by fallback

// bucketed CSR build: bucket = dst >> 8 (256 nodes/bucket)
#define NBUCK 196        // ceil(50000/256)
#define BCAP  8192       // fixed bucket capacity (mean 4337, std ~66 -> 58 sigma slack)

typedef __hip_bfloat16 bf16;
typedef __attribute__((ext_vector_type(8))) short bf16x8;   // MFMA A/B frag (4 VGPRs)
typedef __attribute__((ext_vector_type(4))) float f32x4;    // MFMA C/D frag

__device__ __forceinline__ unsigned short f2bu(float v){
  union { bf16 b; unsigned short u; } cv; cv.b = __float2bfloat16(v); return cv.u;
}
__device__ __forceinline__ float bflo(unsigned int d){ return __uint_as_float(d << 16); }
__device__ __forceinline__ float bfhi(unsigned int d){ return __uint_as_float(d & 0xffff0000u); }

// ---------------- W-frag prep + attention-vector fold + bucket-cursor init ----------------
// blocks 0..127: W1,W2 -> bf16 B-frag layout. block 128: ws1/wd1. block 129: init bcur.
__global__ __launch_bounds__(256) void wfrag_kernel(const float* __restrict__ W1, const float* __restrict__ W2,
    const float* __restrict__ a1s, const float* __restrict__ a1d,
    unsigned short* __restrict__ wf1, unsigned short* __restrict__ wf2,
    float* __restrict__ ws1, float* __restrict__ wd1, int* __restrict__ bcur){
  int b = blockIdx.x, tid = threadIdx.x;
  if (b < 128) {
    int i = b*256 + tid;   // 32768 threads exact
    if (i < 16384) {
      int k = i >> 8, n = i & 255;
      int kk = k >> 5, qq = (k >> 3) & 3, j = k & 7, nt = n >> 4, cc = n & 15;
      wf1[(((kk*16 + nt)*4 + qq)*16 + cc)*8 + j] = f2bu(W1[i]);
    } else {
      int i2 = i - 16384;
      int k = i2 >> 6, n = i2 & 63;
      int kk = k >> 5, qq = (k >> 3) & 3, j = k & 7, ch = n >> 4, cc = n & 15;
      wf2[(((kk*4 + ch)*4 + qq)*16 + cc)*8 + j] = f2bu(W2[i2]);
    }
  } else if (b == 128) {
    // ws1[k][h] = sum_c W1[k, h*64+c] * a1s[h, c]   (64x4 each)
    int k = tid >> 2, h = tid & 3;
    const float* wrow = W1 + k*256 + h*64;
    const float* as = a1s + h*64;
    const float* ad = a1d + h*64;
    float ss = 0.f, sd = 0.f;
    #pragma unroll 8
    for (int c = 0; c < 64; ++c) {
      float wv = wrow[c];
      ss = fmaf(wv, as[c], ss);
      sd = fmaf(wv, ad[c], sd);
    }
    ws1[k*4 + h] = ss;
    wd1[k*4 + h] = sd;
  } else {
    if (tid < NBUCK) bcur[tid] = tid * BCAP;
  }
}

// ---------------- CSR build, stage 1: bin edges into 196 bucket regions ----------------
__global__ __launch_bounds__(256) void binscatter_kernel(const int* __restrict__ ei,
    int* __restrict__ bcur, unsigned int* __restrict__ pairbuf){
  __shared__ int hist[NBUCK];
  __shared__ int gbase[NBUCK];
  int tid = threadIdx.x;
  if (tid < NBUCK) hist[tid] = 0;
  __syncthreads();
  int base = blockIdx.x * 4096;
  #pragma unroll 4
  for (int i = 0; i < 16; ++i) {
    int k = base + i*256 + tid;
    if (k < N_TOT) {
      int c = (k < N_EDGES) ? ei[N_EDGES + k] : (k - N_EDGES);
      atomicAdd(&hist[c >> 8], 1);
    }
  }
  __syncthreads();
  if (tid < NBUCK) {
    int h = hist[tid];
    gbase[tid] = h ? atomicAdd(&bcur[tid], h) : 0;
    hist[tid] = 0;                       // reuse as local cursor
  }
  __syncthreads();
  #pragma unroll 4
  for (int i = 0; i < 16; ++i) {
    int k = base + i*256 + tid;
    if (k < N_TOT) {
      int r, c;
      if (k < N_EDGES) { r = ei[k]; c = ei[N_EDGES + k]; } else { r = c = k - N_EDGES; }
      int b = c >> 8;
      int lpos = atomicAdd(&hist[b], 1);
      pairbuf[gbase[b] + lpos] = (unsigned)r | ((unsigned)(c & 255) << 16);
    }
  }
}

// ---------------- CSR build, stage 2: scan the 196 bucket totals -> bucket bases ----------------
__global__ __launch_bounds__(256) void scan196_kernel(const int* __restrict__ bcur,
    int* __restrict__ bbase, int* __restrict__ offs){
  __shared__ int sm[256];
  int tid = threadIdx.x;
  int v = 0;
  if (tid < NBUCK) {
    v = bcur[tid] - tid*BCAP;
    if (v < 0) v = 0; if (v > BCAP) v = BCAP;
  }
  sm[tid] = v;
  __syncthreads();
  for (int off = 1; off < 256; off <<= 1) {
    int t = (tid >= off) ? sm[tid - off] : 0;
    __syncthreads();
    sm[tid] += t;
    __syncthreads();
  }
  if (tid < NBUCK) bbase[tid] = sm[tid] - v;    // exclusive
  if (tid == 0) offs[N_NODES] = N_TOT;
}

// ---------------- CSR build, stage 3: per-bucket count+scan+offs+scatter, one kernel ----------------
__global__ __launch_bounds__(256) void lscatter2_kernel(const unsigned int* __restrict__ pairbuf,
    const int* __restrict__ bcur, const int* __restrict__ bbase,
    int* __restrict__ offs, int* __restrict__ srcs){
  __shared__ int lhist[256];
  __shared__ int lcur[256];
  int b = blockIdx.x, tid = threadIdx.x;
  lhist[tid] = 0;
  __syncthreads();
  int base = b * BCAP;
  int size = bcur[b] - base; if (size > BCAP) size = BCAP; if (size < 0) size = 0;
  for (int j = tid; j < size; j += 256)
    atomicAdd(&lhist[pairbuf[base + j] >> 16], 1);
  __syncthreads();
  int v = lhist[tid];
  lcur[tid] = v;
  __syncthreads();
  for (int off = 1; off < 256; off <<= 1) {
    int t = (tid >= off) ? lcur[tid - off] : 0;
    __syncthreads();
    lcur[tid] += t;
    __syncthreads();
  }
  int excl = lcur[tid] - v;
  int gpos = bbase[b] + excl;
  int node = b*256 + tid;
  if (node < N_NODES) offs[node] = gpos;
  __syncthreads();
  lcur[tid] = gpos;       // per-node cursor
  __syncthreads();
  for (int j = tid; j < size; j += 256) {
    unsigned pv = pairbuf[base + j];
    int pos = atomicAdd(&lcur[pv >> 16], 1);
    srcs[pos] = (int)(pv & 0xFFFFu);
  }
}

// ---------------- xprep: xb = bf16(x); al1{s,d} = x @ w{s,d}1 ----------------
__global__ __launch_bounds__(256) void xprep_kernel(const float* __restrict__ x,
    const float* __restrict__ ws1, const float* __restrict__ wd1,
    unsigned short* __restrict__ xb, float* __restrict__ al1s, float* __restrict__ al1d){
  __shared__ float sws[64][4], swd[64][4];
  int tid = threadIdx.x;
  sws[tid >> 2][tid & 3] = ws1[tid];
  swd[tid >> 2][tid & 3] = wd1[tid];
  __syncthreads();
  int lane = tid & 63, wave = tid >> 6;
  int g = lane & 15, sub = lane >> 4;
  int n = blockIdx.x*16 + wave*4 + sub;     // 50000/16 = 3125 exact
  float4 xv = *(const float4*)(x + (size_t)n*64 + g*4);
  uint2 dd;
  dd.x = (unsigned)f2bu(xv.x) | ((unsigned)f2bu(xv.y) << 16);
  dd.y = (unsigned)f2bu(xv.z) | ((unsigned)f2bu(xv.w) << 16);
  ((uint2*)xb)[(size_t)n*16 + g] = dd;
  int c0 = g*4;
  float ps0 = 0.f, ps1 = 0.f, ps2 = 0.f, ps3 = 0.f;
  float pd0 = 0.f, pd1 = 0.f, pd2 = 0.f, pd3 = 0.f;
  float xc[4] = {xv.x, xv.y, xv.z, xv.w};
  #pragma unroll
  for (int i = 0; i < 4; ++i) {
    int c = c0 + i;
    ps0 = fmaf(xc[i], sws[c][0], ps0); ps1 = fmaf(xc[i], sws[c][1], ps1);
    ps2 = fmaf(xc[i], sws[c][2], ps2); ps3 = fmaf(xc[i], sws[c][3], ps3);
    pd0 = fmaf(xc[i], swd[c][0], pd0); pd1 = fmaf(xc[i], swd[c][1], pd1);
    pd2 = fmaf(xc[i], swd[c][2], pd2); pd3 = fmaf(xc[i], swd[c][3], pd3);
  }
  #pragma unroll
  for (int off = 1; off < 16; off <<= 1) {
    ps0 += __shfl_xor(ps0, off, 64); ps1 += __shfl_xor(ps1, off, 64);
    ps2 += __shfl_xor(ps2, off, 64); ps3 += __shfl_xor(ps3, off, 64);
    pd0 += __shfl_xor(pd0, off, 64); pd1 += __shfl_xor(pd1, off, 64);
    pd2 += __shfl_xor(pd2, off, 64); pd3 += __shfl_xor(pd3, off, 64);
  }
  if (g < 4)      al1s[(size_t)n*4 + g]       = (g==0)?ps0:(g==1)?ps1:(g==2)?ps2:ps3;
  else if (g < 8) al1d[(size_t)n*4 + (g-4)]   = (g==4)?pd0:(g==5)?pd1:(g==6)?pd2:pd3;
}

// ------- Attention layer 1 in x-space: ag[n,h,:64] = sum_j alpha_{j,h} * xb[r_j]
// zero-padded p-buffer (no bounds mask) + unroll 2 (VGPR ~28 -> 65% occupancy [R7])
__global__ __launch_bounds__(256, 8) void attn1x_kernel(const unsigned short* __restrict__ xb,
    const float* __restrict__ al1s, const float* __restrict__ al1d,
    const int* __restrict__ offs, const int* __restrict__ srcs,
    bf16* __restrict__ ag){
  __shared__ __align__(16) float ebuf[4][MAXD+4][4];     // p values, +4 zero pad
  __shared__ int sbuf[4][MAXD+4];

  int wave = threadIdx.x >> 6, lane = threadIdx.x & 63;
  int n = blockIdx.x*4 + wave;          // 50000 % 4 == 0: no tail
  int start = offs[n], end = offs[n+1];
  int deg = end - start;
  int lim = deg < MAXD ? deg : MAXD;
  float4 aldv = *(const float4*)(al1d + (size_t)n*4);
  float ald0 = aldv.x, ald1 = aldv.y, ald2 = aldv.z, ald3 = aldv.w;

  // stage pass: gather als, e=lrelu, p=exp(e); stage p+src; lane sums
  float s0 = 0.f, s1 = 0.f, s2 = 0.f, s3 = 0.f;
  {
    int idx = lane;
    for (int j = start + lane; j < end; j += 64, idx += 64) {
      int r = srcs[j];
      float4 als = *(const float4*)(al1s + (size_t)r*4);
      float e0 = als.x + ald0; e0 = e0 >= 0.f ? e0 : 0.2f*e0; float p0 = __expf(e0); s0 += p0;
      float e1 = als.y + ald1; e1 = e1 >= 0.f ? e1 : 0.2f*e1; float p1 = __expf(e1); s1 += p1;
      float e2 = als.z + ald2; e2 = e2 >= 0.f ? e2 : 0.2f*e2; float p2 = __expf(e2); s2 += p2;
      float e3 = als.w + ald3; e3 = e3 >= 0.f ? e3 : 0.2f*e3; float p3 = __expf(e3); s3 += p3;
      if (idx < MAXD) {
        sbuf[wave][idx] = r;
        *(float4*)&ebuf[wave][idx][0] = make_float4(p0, p1, p2, p3);
      }
    }
  }
  // zero-pad 4 slots past lim: aggregation loop then needs no bounds mask
  if (lane < 4) {
    int ip = lim + lane;
    sbuf[wave][ip] = 0;
    *(float4*)&ebuf[wave][ip][0] = make_float4(0.f, 0.f, 0.f, 0.f);
  }
  #pragma unroll
  for (int off = 32; off; off >>= 1) {
    s0 += __shfl_xor(s0, off, 64);
    s1 += __shfl_xor(s1, off, 64);
    s2 += __shfl_xor(s2, off, 64);
    s3 += __shfl_xor(s3, off, 64);
  }
  float inv0 = 1.f/(s0 + 1e-16f), inv1 = 1.f/(s1 + 1e-16f);
  float inv2 = 1.f/(s2 + 1e-16f), inv3 = 1.f/(s3 + 1e-16f);

  // aggregation: lane -> (edge-slot es=lane>>4 of 4, ch-lane cl=lane&15: ch cl*4..cl*4+3)
  int cl = lane & 15, es = lane >> 4;
  float acc[4][4];
  #pragma unroll
  for (int h = 0; h < 4; ++h)
    #pragma unroll
    for (int i = 0; i < 4; ++i) acc[h][i] = 0.f;
  {
    const uint2* base2 = (const uint2*)xb;   // row = 16 uint2 (128B)
    #pragma unroll 2
    for (int jj = 0; jj < lim; jj += 4) {
      int idx = jj + es;                     // <= lim+2 < lim+4 (padded)
      int r = sbuf[wave][idx];
      float4 pv = *(const float4*)&ebuf[wave][idx][0];
      uint2 d = base2[(size_t)r*16 + cl];
      float c0 = bflo(d.x), c1 = bfhi(d.x), c2 = bflo(d.y), c3 = bfhi(d.y);
      acc[0][0] = fmaf(pv.x, c0, acc[0][0]); acc[0][1] = fmaf(pv.x, c1, acc[0][1]);
      acc[0][2] = fmaf(pv.x, c2, acc[0][2]); acc[0][3] = fmaf(pv.x, c3, acc[0][3]);
      acc[1][0] = fmaf(pv.y, c0, acc[1][0]); acc[1][1] = fmaf(pv.y, c1, acc[1][1]);
      acc[1][2] = fmaf(pv.y, c2, acc[1][2]); acc[1][3] = fmaf(pv.y, c3, acc[1][3]);
      acc[2][0] = fmaf(pv.z, c0, acc[2][0]); acc[2][1] = fmaf(pv.z, c1, acc[2][1]);
      acc[2][2] = fmaf(pv.z, c2, acc[2][2]); acc[2][3] = fmaf(pv.z, c3, acc[2][3]);
      acc[3][0] = fmaf(pv.w, c0, acc[3][0]); acc[3][1] = fmaf(pv.w, c1, acc[3][1]);
      acc[3][2] = fmaf(pv.w, c2, acc[3][2]); acc[3][3] = fmaf(pv.w, c3, acc[3][3]);
    }
  }
  if (deg > MAXD) {       // rare overflow tail: recompute p per lane (masked scalar path)
    const uint2* base2 = (const uint2*)xb;
    for (int jj = MAXD; jj < deg; jj += 4) {
      int idx = jj + es;
      bool ok = idx < deg;
      int j = ok ? (start + idx) : start;
      int r = srcs[j];
      float4 als = *(const float4*)(al1s + (size_t)r*4);
      float e0 = als.x + ald0; e0 = e0 >= 0.f ? e0 : 0.2f*e0; float p0 = __expf(e0);
      float e1 = als.y + ald1; e1 = e1 >= 0.f ? e1 : 0.2f*e1; float p1 = __expf(e1);
      float e2 = als.z + ald2; e2 = e2 >= 0.f ? e2 : 0.2f*e2; float p2 = __expf(e2);
      float e3 = als.w + ald3; e3 = e3 >= 0.f ? e3 : 0.2f*e3; float p3 = __expf(e3);
      float m = ok ? 1.f : 0.f;
      uint2 d = base2[(size_t)r*16 + cl];
      float c0 = bflo(d.x)*m, c1 = bfhi(d.x)*m, c2 = bflo(d.y)*m, c3 = bfhi(d.y)*m;
      acc[0][0] = fmaf(p0, c0, acc[0][0]); acc[0][1] = fmaf(p0, c1, acc[0][1]);
      acc[0][2] = fmaf(p0, c2, acc[0][2]); acc[0][3] = fmaf(p0, c3, acc[0][3]);
      acc[1][0] = fmaf(p1, c0, acc[1][0]); acc[1][1] = fmaf(p1, c1, acc[1][1]);
      acc[1][2] = fmaf(p1, c2, acc[1][2]); acc[1][3] = fmaf(p1, c3, acc[1][3]);
      acc[2][0] = fmaf(p2, c0, acc[2][0]); acc[2][1] = fmaf(p2, c1, acc[2][1]);
      acc[2][2] = fmaf(p2, c2, acc[2][2]); acc[2][3] = fmaf(p2, c3, acc[2][3]);
      acc[3][0] = fmaf(p3, c0, acc[3][0]); acc[3][1] = fmaf(p3, c1, acc[3][1]);
      acc[3][2] = fmaf(p3, c2, acc[3][2]); acc[3][3] = fmaf(p3, c3, acc[3][3]);
    }
  }
  // fold the 4 edge slots (lane bits 4,5)
  #pragma unroll
  for (int h = 0; h < 4; ++h)
    #pragma unroll
    for (int i = 0; i < 4; ++i) {
      acc[h][i] += __shfl_xor(acc[h][i], 16, 64);
      acc[h][i] += __shfl_xor(acc[h][i], 32, 64);
    }
  // lane l writes head h=es, channels cl*4..cl*4+3: ag[n][es*64 + cl*4 ...] (coalesced 512B/row)
  {
    float invh = (es==0)?inv0:(es==1)?inv1:(es==2)?inv2:inv3;
    float o0 = ((es==0)?acc[0][0]:(es==1)?acc[1][0]:(es==2)?acc[2][0]:acc[3][0]) * invh;
    float o1 = ((es==0)?acc[0][1]:(es==1)?acc[1][1]:(es==2)?acc[2][1]:acc[3][1]) * invh;
    float o2 = ((es==0)?acc[0][2]:(es==1)?acc[1][2]:(es==2)?acc[2][2]:acc[3][2]) * invh;
    float o3 = ((es==0)?acc[0][3]:(es==1)?acc[1][3]:(es==2)?acc[2][3]:acc[3][3]) * invh;
    uint2 dd;
    dd.x = (unsigned)f2bu(o0) | ((unsigned)f2bu(o1) << 16);
    dd.y = (unsigned)f2bu(o2) | ((unsigned)f2bu(o3) << 16);
    ((uint2*)ag)[(size_t)n*64 + lane] = dd;
  }
}

// ---------------- GEMM1b (MFMA, block-diagonal): h1[:, h*64:+64] = elu(ag[:,h,:] @ W1[, h] + b1)
__global__ __launch_bounds__(256) void gemm1b_kernel(const unsigned short* __restrict__ ag,
    const unsigned short* __restrict__ wf1, const float* __restrict__ b1, bf16* __restrict__ h1){
  __shared__ __align__(16) unsigned short ctile[32*264];       // half-tile bf16, 16.5KB
  int tid = threadIdx.x, wave = tid >> 6, lane = tid & 63;
  int q = lane >> 4, c = lane & 15;
  int n0 = blockIdx.x * 64;

  union { uint4 u; bf16x8 v; } bfr[2][4];
  #pragma unroll
  for (int kk = 0; kk < 2; ++kk)
    #pragma unroll
    for (int nti = 0; nti < 4; ++nti)
      bfr[kk][nti].u = *(const uint4*)(wf1 + (size_t)((((kk*16 + wave*4 + nti)*4 + q)*16 + c)*8));

  float b1v[4];
  #pragma unroll
  for (int nti = 0; nti < 4; ++nti) b1v[nti] = b1[(wave*4 + nti)*16 + c];

  #pragma unroll
  for (int half = 0; half < 2; ++half) {
    #pragma unroll
    for (int sti = 0; sti < 2; ++sti) {
      int st = half*2 + sti;
      int row = n0 + st*16 + c;
      if (row >= N_NODES) row = N_NODES - 1;   // tail clamp; stores guarded below
      bf16x8 afr[2];
      #pragma unroll
      for (int kk = 0; kk < 2; ++kk) {
        union { uint4 u; bf16x8 v; } a;
        a.u = *(const uint4*)(ag + (size_t)row*256 + wave*64 + kk*32 + q*8);
        afr[kk] = a.v;
      }
      #pragma unroll
      for (int nti = 0; nti < 4; ++nti) {
        f32x4 acc = {0.f, 0.f, 0.f, 0.f};
        #pragma unroll
        for (int kk = 0; kk < 2; ++kk)
          acc = __builtin_amdgcn_mfma_f32_16x16x32_bf16(afr[kk], bfr[kk][nti].v, acc, 0, 0, 0);
        int lrow = sti*16 + q*4, nt = wave*4 + nti;
        #pragma unroll
        for (int r = 0; r < 4; ++r) {
          float o = acc[r] + b1v[nti];
          o = o > 0.f ? o : expm1f(o);
          ctile[(lrow + r)*264 + nt*16 + c] = f2bu(o);
        }
      }
    }
    __syncthreads();
    // store phase: wave w -> local rows w*8..w*8+7; coalesced 512B/row
    #pragma unroll 1
    for (int i = 0; i < 8; ++i) {
      int lr = wave*8 + i;
      int node = n0 + half*32 + lr;
      if (node < N_NODES) {
        uint2 dd = *(const uint2*)&ctile[lr*264 + lane*4];
        ((uint2*)h1)[(size_t)node*64 + lane] = dd;
      }
    }
    __syncthreads();
  }
}

// ---------------- GEMM2 (MFMA): h2pre = h1 @ W2  [50000,256]bf16 x [256,64], fused al2 ----------------
__global__ __launch_bounds__(256) void gemm2_kernel(const bf16* __restrict__ h1, const unsigned short* __restrict__ wf2,
    const float* __restrict__ a2s, const float* __restrict__ a2d,
    bf16* __restrict__ h2pre, float* __restrict__ al2s, float* __restrict__ al2d){
  __shared__ __align__(16) float ctile[64][65];               // padded
  int tid = threadIdx.x, wave = tid >> 6, lane = tid & 63;
  int q = lane >> 4, c = lane & 15;
  int n0 = blockIdx.x * 64;

  union { uint4 u; bf16x8 v; } bfr[8];
  #pragma unroll
  for (int kk = 0; kk < 8; ++kk)
    bfr[kk].u = *(const uint4*)(wf2 + (size_t)((((kk*4 + wave)*4 + q)*16 + c)*8));

  const unsigned short* h1u = (const unsigned short*)h1;
  #pragma unroll 1
  for (int st = 0; st < 4; ++st) {
    if (n0 + st*16 >= N_NODES) break;
    f32x4 acc = {0.f, 0.f, 0.f, 0.f};
    size_t arow = (size_t)(n0 + st*16 + c)*256 + q*8;
    #pragma unroll
    for (int kk = 0; kk < 8; ++kk) {
      union { uint4 u; bf16x8 v; } a;
      a.u = *(const uint4*)(h1u + arow + kk*32);
      acc = __builtin_amdgcn_mfma_f32_16x16x32_bf16(a.v, bfr[kk].v, acc, 0, 0, 0);
    }
    #pragma unroll
    for (int r = 0; r < 4; ++r)
      ctile[st*16 + q*4 + r][wave*16 + c] = acc[r];
  }
  __syncthreads();

  float as = a2s[lane], ad = a2d[lane];
  #pragma unroll 1
  for (int i = 0; i < 16; ++i) {
    int node = n0 + wave*16 + i;
    if (node >= N_NODES) break;
    float val = ctile[wave*16 + i][lane];
    ((unsigned short*)h2pre)[(size_t)node*64 + lane] = f2bu(val);
    float ps = val*as, pd = val*ad;
    #pragma unroll
    for (int off = 32; off; off >>= 1) { ps += __shfl_xor(ps, off, 64); pd += __shfl_xor(pd, off, 64); }
    if (lane == 0) { al2s[node] = ps; al2d[node] = pd; }
  }
}

// ---------------- Attention layer 2 (H=1, no max pass), slim: writes post-ELU h2 (fp32) only ----------------
__global__ __launch_bounds__(512, 8) void attn2_kernel(const bf16* __restrict__ h2pre,
    const float* __restrict__ al2s, const float* __restrict__ al2d,
    const int* __restrict__ offs, const int* __restrict__ srcs,
    const float* __restrict__ b2, float* __restrict__ h2f){
  __shared__ float ebuf[8][MAXD+8];             // p values, +8 zero pad
  __shared__ int   sbuf[8][MAXD+8];
  int wave = threadIdx.x >> 6, lane = threadIdx.x & 63;
  int n = blockIdx.x*8 + wave;        // exact
  int start = offs[n], end = offs[n+1];
  int deg = end - start;
  int lim = deg < MAXD ? deg : MAXD;
  float ald = al2d[n];

  float sm = 0.f;
  {
    int idx = lane;
    for (int j = start + lane; j < end; j += 64, idx += 64) {
      int r = srcs[j];
      float t = al2s[r] + ald; t = t >= 0.f ? t : 0.2f*t;
      float p = __expf(t); sm += p;
      if (idx < MAXD) { sbuf[wave][idx] = r; ebuf[wave][idx] = p; }
    }
  }
  if (lane < 8) { int ip = lim + lane; sbuf[wave][ip] = 0; ebuf[wave][ip] = 0.f; }
  #pragma unroll
  for (int off = 32; off; off >>= 1) sm += __shfl_xor(sm, off, 64);
  float inv = 1.f/(sm + 1e-16f);

  // aggregation: lane -> (edge-slot es=lane>>3, channel-lane cl=lane&7); uint4 = channels cl*8..cl*8+7
  // padded p-buffer: no bounds mask in hot loop
  int cl = lane & 7, es = lane >> 3;
  float acc0 = 0.f, acc1 = 0.f, acc2 = 0.f, acc3 = 0.f;
  float acc4 = 0.f, acc5 = 0.f, acc6 = 0.f, acc7 = 0.f;
  {
    const uint4* base4 = (const uint4*)h2pre;   // row = 8 uint4
    #pragma unroll 2
    for (int jj = 0; jj < lim; jj += 8) {
      int idx = jj + es;                        // <= lim+6 < lim+8 (padded)
      int r = sbuf[wave][idx];
      float p = ebuf[wave][idx];
      uint4 d = base4[(size_t)r*8 + cl];
      acc0 = fmaf(p, bflo(d.x), acc0);
      acc1 = fmaf(p, bfhi(d.x), acc1);
      acc2 = fmaf(p, bflo(d.y), acc2);
      acc3 = fmaf(p, bfhi(d.y), acc3);
      acc4 = fmaf(p, bflo(d.z), acc4);
      acc5 = fmaf(p, bfhi(d.z), acc5);
      acc6 = fmaf(p, bflo(d.w), acc6);
      acc7 = fmaf(p, bfhi(d.w), acc7);
    }
  }
  if (deg > MAXD) {     // rare overflow tail
    const uint4* base4 = (const uint4*)h2pre;
    for (int jj = MAXD; jj < deg; jj += 8) {
      int idx = jj + es;
      bool ok = idx < deg;
      int j = ok ? (start + idx) : start;
      int r = srcs[j];
      float t = al2s[r] + ald; t = t >= 0.f ? t : 0.2f*t;
      float p = ok ? __expf(t) : 0.f;
      uint4 d = base4[(size_t)r*8 + cl];
      acc0 = fmaf(p, bflo(d.x), acc0);
      acc1 = fmaf(p, bfhi(d.x), acc1);
      acc2 = fmaf(p, bflo(d.y), acc2);
      acc3 = fmaf(p, bfhi(d.y), acc3);
      acc4 = fmaf(p, bflo(d.z), acc4);
      acc5 = fmaf(p, bfhi(d.z), acc5);
      acc6 = fmaf(p, bflo(d.w), acc6);
      acc7 = fmaf(p, bfhi(d.w), acc7);
    }
  }
  // fold the 8 edge-slots (xor butterfly over lane bits 3,4,5)
  #pragma unroll
  for (int off = 8; off < 64; off <<= 1) {
    acc0 += __shfl_xor(acc0, off, 64);
    acc1 += __shfl_xor(acc1, off, 64);
    acc2 += __shfl_xor(acc2, off, 64);
    acc3 += __shfl_xor(acc3, off, 64);
    acc4 += __shfl_xor(acc4, off, 64);
    acc5 += __shfl_xor(acc5, off, 64);
    acc6 += __shfl_xor(acc6, off, 64);
    acc7 += __shfl_xor(acc7, off, 64);
  }

  if (es == 0) {
    float4 b2a = *(const float4*)(b2 + cl*8);
    float4 b2b = *(const float4*)(b2 + cl*8 + 4);
    float o0 = acc0*inv + b2a.x; o0 = o0 > 0.f ? o0 : expm1f(o0);
    float o1 = acc1*inv + b2a.y; o1 = o1 > 0.f ? o1 : expm1f(o1);
    float o2 = acc2*inv + b2a.z; o2 = o2 > 0.f ? o2 : expm1f(o2);
    float o3 = acc3*inv + b2a.w; o3 = o3 > 0.f ? o3 : expm1f(o3);
    float o4 = acc4*inv + b2b.x; o4 = o4 > 0.f ? o4 : expm1f(o4);
    float o5 = acc5*inv + b2b.y; o5 = o5 > 0.f ? o5 : expm1f(o5);
    float o6 = acc6*inv + b2b.z; o6 = o6 > 0.f ? o6 : expm1f(o6);
    float o7 = acc7*inv + b2b.w; o7 = o7 > 0.f ? o7 : expm1f(o7);
    *(float4*)(h2f + (size_t)n*64 + cl*8)     = make_float4(o0, o1, o2, o3);
    *(float4*)(h2f + (size_t)n*64 + cl*8 + 4) = make_float4(o4, o5, o6, o7);
  }
}

// ---------------- Node head: node_out = h2 @ Wn + bn; u = h2.We[0:64]; v = h2.We[64:128] ----------------
__global__ __launch_bounds__(256) void head_kernel(const float* __restrict__ h2f,
    const float* __restrict__ Wn, const float* __restrict__ bn, const float* __restrict__ We,
    float* __restrict__ u, float* __restrict__ v, float* __restrict__ node_out){
  __shared__ __align__(16) float sh[8][64];
  int tid = threadIdx.x;
  int nb = blockIdx.x*8;              // 50000/8 = 6250 exact
  {
    float2 t = *(const float2*)(h2f + (size_t)nb*64 + tid*2);
    *(float2*)&sh[tid >> 5][(tid & 31)*2] = t;
  }
  __syncthreads();
  int wave = tid >> 6, lane = tid & 63;
  int sub = lane >> 5, j = lane & 31;
  int local = wave*2 + sub;           // 0..7
  int n = nb + local;
  const float* h = sh[local];
  // node_out = h . Wn[:,j]
  float a = 0.f;
  #pragma unroll 16
  for (int k = 0; k < 64; ++k)
    a = fmaf(h[k], Wn[k*32 + j], a);
  node_out[(size_t)n*32 + j] = a + bn[j];
  // u,v partials over k = j, j+32; butterfly within the 32-lane group
  float pu = h[j]*We[j] + h[j+32]*We[j+32];
  float pv = h[j]*We[64+j] + h[j+32]*We[96+j];
  #pragma unroll
  for (int off = 1; off < 32; off <<= 1) {
    pu += __shfl_xor(pu, off, 64);
    pv += __shfl_xor(pv, off, 64);
  }
  if (j == 0) { u[n] = pu; v[n] = pv; }
}

// ---------------- Edge head: out = u[row] + v[col] + edge_attr . We[128:144] + be ----------------
__global__ __launch_bounds__(256) void edge_kernel(const int* __restrict__ ei, const float* __restrict__ ea,
    const float* __restrict__ u, const float* __restrict__ v,
    const float* __restrict__ We, const float* __restrict__ be, float* __restrict__ out){
  int k = blockIdx.x*256 + threadIdx.x;   // grid is exact: 800000/256
  int r = ei[k], c = ei[N_EDGES + k];
  float val = u[r] + v[c] + be[0];
  const float4* wp = (const float4*)(We + 128);
  const float4* p  = (const float4*)(ea + (size_t)k*16);
  #pragma unroll
  for (int jj = 0; jj < 4; jj++) {
    float4 q = p[jj], wq = wp[jj];
    val = fmaf(q.x, wq.x, val);
    val = fmaf(q.y, wq.y, val);
    val = fmaf(q.z, wq.z, val);
    val = fmaf(q.w, wq.w, val);
  }
  out[k] = val;
}

extern "C" void kernel_launch(void* const* d_in, const int* in_sizes, int n_in,
                              void* d_out, int out_size, void* d_ws, size_t ws_size,
                              hipStream_t stream) {
  const float* x   = (const float*)d_in[0];
  const int*   ei  = (const int*)d_in[1];
  const float* ea  = (const float*)d_in[2];
  const float* W1  = (const float*)d_in[3];
  const float* a1s = (const float*)d_in[4];
  const float* a1d = (const float*)d_in[5];
  const float* b1  = (const float*)d_in[6];
  const float* W2  = (const float*)d_in[7];
  const float* a2s = (const float*)d_in[8];
  const float* a2d = (const float*)d_in[9];
  const float* b2  = (const float*)d_in[10];
  const float* Wn  = (const float*)d_in[11];
  const float* bn  = (const float*)d_in[12];
  const float* We  = (const float*)d_in[13];
  const float* be  = (const float*)d_in[14];
  float* out = (float*)d_out;

  // ---- workspace layout, peak 64,000,224 B, 16B-aligned ----
  char* w = (char*)d_ws;
  int*   offs   = (int*)(w);                        //       0 .. 200,016
  unsigned short* wf1 = (unsigned short*)(w + 200016); // 32,768 B
  float* ws1    = (float*)(w + 232784);             // 1,024 B
  float* wd1    = (float*)(w + 233808);             // 1,024 B
  unsigned short* wf2 = (unsigned short*)(w + 234832); // 32,768 B (.. 267,600)
  int*   bcur   = (int*)(w + 400016);               // 784 B bucket cursors
  int*   bbase  = (int*)(w + 400816);               // 784 B bucket bases
  int*   srcs   = (int*)(w + 600016);               // 600,016 .. 4,000,016
  float* al1s   = (float*)(w + 4000016);            // [N,4] fp32, .. 4,800,016
  float* al1d   = (float*)(w + 4800016);            // [N,4] fp32, .. 5,600,016
  float* al2s   = (float*)(w + 5600016);            // [N] fp32,  .. 5,800,016
  float* al2d   = (float*)(w + 5800016);            // .. 6,000,016
  float* uu     = (float*)(w + 6000016);            // .. 6,200,016
  float* vv     = (float*)(w + 6200016);            // .. 6,400,016
  bf16*  h2pre  = (bf16*)(w + 6400016);             // [N,64] bf16, .. 12,800,016 (xb aliases BEFORE gemm2)
  bf16*  ag     = (bf16*)(w + 12800016);            // [N,256] bf16 aggregate, .. 38,400,016
  bf16*  h1     = (bf16*)(w + 38400224);            // [N,256] bf16, .. 64,000,224
  unsigned short* xb  = (unsigned short*)h2pre;     // [N,64] bf16 x-table; dead before gemm2 writes h2pre
  unsigned int* pairbuf = (unsigned int*)h1;        // 6.4 MB bucket regions (h1 dead until gemm1b)
  float* h2f = (float*)ag;                          // [N,64] fp32 post-ELU h2 (ag dead after gemm1b)

  wfrag_kernel     <<<130, 256, 0, stream>>>(W1, W2, a1s, a1d, wf1, wf2, ws1, wd1, bcur);
  binscatter_kernel<<<(N_TOT + 4095)/4096, 256, 0, stream>>>(ei, bcur, pairbuf);
  scan196_kernel   <<<1, 256, 0, stream>>>(bcur, bbase, offs);
  lscatter2_kernel <<<NBUCK, 256, 0, stream>>>(pairbuf, bcur, bbase, offs, srcs);
  xprep_kernel     <<<N_NODES/16, 256, 0, stream>>>(x, ws1, wd1, xb, al1s, al1d);
  attn1x_kernel    <<<N_NODES/4, 256, 0, stream>>>(xb, al1s, al1d, offs, srcs, ag);
  gemm1b_kernel    <<<(N_NODES + 63)/64, 256, 0, stream>>>((const unsigned short*)ag, wf1, b1, h1);
  gemm2_kernel     <<<(N_NODES + 63)/64, 256, 0, stream>>>(h1, wf2, a2s, a2d, h2pre, al2s, al2d);
  attn2_kernel     <<<N_NODES/8, 512, 0, stream>>>(h2pre, al2s, al2d, offs, srcs, b2, h2f);
  head_kernel      <<<N_NODES/8, 256, 0, stream>>>(h2f, Wn, bn, We, uu, vv, out);
  edge_kernel      <<<N_EDGES/256, 256, 0, stream>>>(ei, ea, uu, vv, We, be, out + (size_t)N_NODES*32);
}

// Round 10
// 312.885 us; speedup vs baseline: 1.0817x; 1.0051x over previous
//
#include <hip/hip_runtime.h>
#include <hip/hip_bf16.h>

#define N_NODES 50000
#define N_EDGES 800000
#define N_TOT   850000   // edges + self loops
#define MAXD    128      // LDS-staged edges per node; tail handled by fallback

// bucketed CSR build: bucket = dst >> 8 (256 nodes/bucket)
#define NBUCK 196        // ceil(50000/256)
#define BCAP  8192       // fixed bucket capacity (mean 4337, std ~66 -> 58 sigma slack)

typedef __hip_bfloat16 bf16;
typedef __attribute__((ext_vector_type(8))) short bf16x8;   // MFMA A/B frag (4 VGPRs)
typedef __attribute__((ext_vector_type(4))) float f32x4;    // MFMA C/D frag

__device__ __forceinline__ unsigned short f2bu(float v){
  union { bf16 b; unsigned short u; } cv; cv.b = __float2bfloat16(v); return cv.u;
}
__device__ __forceinline__ float bflo(unsigned int d){ return __uint_as_float(d << 16); }
__device__ __forceinline__ float bfhi(unsigned int d){ return __uint_as_float(d & 0xffff0000u); }

// ---------------- W-frag prep + attention-vector fold + bucket-count init ----------------
// blocks 0..127: W1,W2 -> bf16 B-frag layout. block 128: ws1/wd1. block 129: zero bcur (counts).
__global__ __launch_bounds__(256) void wfrag_kernel(const float* __restrict__ W1, const float* __restrict__ W2,
    const float* __restrict__ a1s, const float* __restrict__ a1d,
    unsigned short* __restrict__ wf1, unsigned short* __restrict__ wf2,
    float* __restrict__ ws1, float* __restrict__ wd1, int* __restrict__ bcur){
  int b = blockIdx.x, tid = threadIdx.x;
  if (b < 128) {
    int i = b*256 + tid;   // 32768 threads exact
    if (i < 16384) {
      int k = i >> 8, n = i & 255;
      int kk = k >> 5, qq = (k >> 3) & 3, j = k & 7, nt = n >> 4, cc = n & 15;
      wf1[(((kk*16 + nt)*4 + qq)*16 + cc)*8 + j] = f2bu(W1[i]);
    } else {
      int i2 = i - 16384;
      int k = i2 >> 6, n = i2 & 63;
      int kk = k >> 5, qq = (k >> 3) & 3, j = k & 7, ch = n >> 4, cc = n & 15;
      wf2[(((kk*4 + ch)*4 + qq)*16 + cc)*8 + j] = f2bu(W2[i2]);
    }
  } else if (b == 128) {
    // ws1[k][h] = sum_c W1[k, h*64+c] * a1s[h, c]   (64x4 each)
    int k = tid >> 2, h = tid & 3;
    const float* wrow = W1 + k*256 + h*64;
    const float* as = a1s + h*64;
    const float* ad = a1d + h*64;
    float ss = 0.f, sd = 0.f;
    #pragma unroll 8
    for (int c = 0; c < 64; ++c) {
      float wv = wrow[c];
      ss = fmaf(wv, as[c], ss);
      sd = fmaf(wv, ad[c], sd);
    }
    ws1[k*4 + h] = ss;
    wd1[k*4 + h] = sd;
  } else {
    if (tid < NBUCK) bcur[tid] = 0;     // counts now (not absolute cursors)
  }
}

// ---------------- CSR build, stage 1: bin edges into 196 bucket regions ----------------
__global__ __launch_bounds__(256) void binscatter_kernel(const int* __restrict__ ei,
    int* __restrict__ bcur, unsigned int* __restrict__ pairbuf){
  __shared__ int hist[NBUCK];
  __shared__ int gbase[NBUCK];
  int tid = threadIdx.x;
  if (tid < NBUCK) hist[tid] = 0;
  __syncthreads();
  int base = blockIdx.x * 4096;
  #pragma unroll 4
  for (int i = 0; i < 16; ++i) {
    int k = base + i*256 + tid;
    if (k < N_TOT) {
      int c = (k < N_EDGES) ? ei[N_EDGES + k] : (k - N_EDGES);
      atomicAdd(&hist[c >> 8], 1);
    }
  }
  __syncthreads();
  if (tid < NBUCK) {
    int h = hist[tid];
    gbase[tid] = h ? (tid*BCAP + atomicAdd(&bcur[tid], h)) : 0;
    hist[tid] = 0;                       // reuse as local cursor
  }
  __syncthreads();
  #pragma unroll 4
  for (int i = 0; i < 16; ++i) {
    int k = base + i*256 + tid;
    if (k < N_TOT) {
      int r, c;
      if (k < N_EDGES) { r = ei[k]; c = ei[N_EDGES + k]; } else { r = c = k - N_EDGES; }
      int b = c >> 8;
      int lpos = atomicAdd(&hist[b], 1);
      pairbuf[gbase[b] + lpos] = (unsigned)r | ((unsigned)(c & 255) << 16);
    }
  }
}

// ---------------- CSR build, stage 2: per-bucket {bucket-scan + count + scan + offs + scatter} ----
// Each block redundantly prefix-sums the 196 bucket counts (cheap LDS scan) -> its own bbase;
// removes the separate scan196 dispatch [R10: gap elimination without redundant heavy math].
__global__ __launch_bounds__(256) void lscatter2_kernel(const unsigned int* __restrict__ pairbuf,
    const int* __restrict__ bcur, int* __restrict__ offs, int* __restrict__ srcs){
  __shared__ int sbase[256];
  __shared__ int lhist[256];
  __shared__ int lcur[256];
  int b = blockIdx.x, tid = threadIdx.x;
  // redundant 196-bucket scan
  int sz = 0;
  if (tid < NBUCK) {
    sz = bcur[tid];
    if (sz < 0) sz = 0; if (sz > BCAP) sz = BCAP;
  }
  sbase[tid] = sz;
  lhist[tid] = 0;
  __syncthreads();
  for (int off = 1; off < 256; off <<= 1) {
    int t = (tid >= off) ? sbase[tid - off] : 0;
    __syncthreads();
    sbase[tid] += t;
    __syncthreads();
  }
  int bbase_b = (b == 0) ? 0 : sbase[b - 1];
  int size = sbase[b] - bbase_b;                 // min(bcur[b], BCAP)
  int base = b * BCAP;
  // per-node counts within bucket
  for (int j = tid; j < size; j += 256)
    atomicAdd(&lhist[pairbuf[base + j] >> 16], 1);
  __syncthreads();
  int v = lhist[tid];
  lcur[tid] = v;
  __syncthreads();
  for (int off = 1; off < 256; off <<= 1) {
    int t = (tid >= off) ? lcur[tid - off] : 0;
    __syncthreads();
    lcur[tid] += t;
    __syncthreads();
  }
  int excl = lcur[tid] - v;
  int gpos = bbase_b + excl;
  int node = b*256 + tid;
  if (node < N_NODES) offs[node] = gpos;
  if (b == 0 && tid == 0) offs[N_NODES] = N_TOT;
  __syncthreads();
  lcur[tid] = gpos;       // per-node cursor
  __syncthreads();
  for (int j = tid; j < size; j += 256) {
    unsigned pv = pairbuf[base + j];
    int pos = atomicAdd(&lcur[pv >> 16], 1);
    srcs[pos] = (int)(pv & 0xFFFFu);
  }
}

// ---------------- xprep: xb = bf16(x); al1{s,d} = x @ w{s,d}1 ----------------
__global__ __launch_bounds__(256) void xprep_kernel(const float* __restrict__ x,
    const float* __restrict__ ws1, const float* __restrict__ wd1,
    unsigned short* __restrict__ xb, float* __restrict__ al1s, float* __restrict__ al1d){
  __shared__ float sws[64][4], swd[64][4];
  int tid = threadIdx.x;
  sws[tid >> 2][tid & 3] = ws1[tid];
  swd[tid >> 2][tid & 3] = wd1[tid];
  __syncthreads();
  int lane = tid & 63, wave = tid >> 6;
  int g = lane & 15, sub = lane >> 4;
  int n = blockIdx.x*16 + wave*4 + sub;     // 50000/16 = 3125 exact
  float4 xv = *(const float4*)(x + (size_t)n*64 + g*4);
  uint2 dd;
  dd.x = (unsigned)f2bu(xv.x) | ((unsigned)f2bu(xv.y) << 16);
  dd.y = (unsigned)f2bu(xv.z) | ((unsigned)f2bu(xv.w) << 16);
  ((uint2*)xb)[(size_t)n*16 + g] = dd;
  int c0 = g*4;
  float ps0 = 0.f, ps1 = 0.f, ps2 = 0.f, ps3 = 0.f;
  float pd0 = 0.f, pd1 = 0.f, pd2 = 0.f, pd3 = 0.f;
  float xc[4] = {xv.x, xv.y, xv.z, xv.w};
  #pragma unroll
  for (int i = 0; i < 4; ++i) {
    int c = c0 + i;
    ps0 = fmaf(xc[i], sws[c][0], ps0); ps1 = fmaf(xc[i], sws[c][1], ps1);
    ps2 = fmaf(xc[i], sws[c][2], ps2); ps3 = fmaf(xc[i], sws[c][3], ps3);
    pd0 = fmaf(xc[i], swd[c][0], pd0); pd1 = fmaf(xc[i], swd[c][1], pd1);
    pd2 = fmaf(xc[i], swd[c][2], pd2); pd3 = fmaf(xc[i], swd[c][3], pd3);
  }
  #pragma unroll
  for (int off = 1; off < 16; off <<= 1) {
    ps0 += __shfl_xor(ps0, off, 64); ps1 += __shfl_xor(ps1, off, 64);
    ps2 += __shfl_xor(ps2, off, 64); ps3 += __shfl_xor(ps3, off, 64);
    pd0 += __shfl_xor(pd0, off, 64); pd1 += __shfl_xor(pd1, off, 64);
    pd2 += __shfl_xor(pd2, off, 64); pd3 += __shfl_xor(pd3, off, 64);
  }
  if (g < 4)      al1s[(size_t)n*4 + g]       = (g==0)?ps0:(g==1)?ps1:(g==2)?ps2:ps3;
  else if (g < 8) al1d[(size_t)n*4 + (g-4)]   = (g==4)?pd0:(g==5)?pd1:(g==6)?pd2:pd3;
}

// ------- Attention layer 1 in x-space: ag[n,h,:64] = sum_j alpha_{j,h} * xb[r_j]
// zero-padded p-buffer (no bounds mask) + unroll 2 (VGPR ~28 -> 65% occupancy [R7])
__global__ __launch_bounds__(256, 8) void attn1x_kernel(const unsigned short* __restrict__ xb,
    const float* __restrict__ al1s, const float* __restrict__ al1d,
    const int* __restrict__ offs, const int* __restrict__ srcs,
    bf16* __restrict__ ag){
  __shared__ __align__(16) float ebuf[4][MAXD+4][4];     // p values, +4 zero pad
  __shared__ int sbuf[4][MAXD+4];

  int wave = threadIdx.x >> 6, lane = threadIdx.x & 63;
  int n = blockIdx.x*4 + wave;          // 50000 % 4 == 0: no tail
  int start = offs[n], end = offs[n+1];
  int deg = end - start;
  int lim = deg < MAXD ? deg : MAXD;
  float4 aldv = *(const float4*)(al1d + (size_t)n*4);
  float ald0 = aldv.x, ald1 = aldv.y, ald2 = aldv.z, ald3 = aldv.w;

  // stage pass: gather als, e=lrelu, p=exp(e); stage p+src; lane sums
  float s0 = 0.f, s1 = 0.f, s2 = 0.f, s3 = 0.f;
  {
    int idx = lane;
    for (int j = start + lane; j < end; j += 64, idx += 64) {
      int r = srcs[j];
      float4 als = *(const float4*)(al1s + (size_t)r*4);
      float e0 = als.x + ald0; e0 = e0 >= 0.f ? e0 : 0.2f*e0; float p0 = __expf(e0); s0 += p0;
      float e1 = als.y + ald1; e1 = e1 >= 0.f ? e1 : 0.2f*e1; float p1 = __expf(e1); s1 += p1;
      float e2 = als.z + ald2; e2 = e2 >= 0.f ? e2 : 0.2f*e2; float p2 = __expf(e2); s2 += p2;
      float e3 = als.w + ald3; e3 = e3 >= 0.f ? e3 : 0.2f*e3; float p3 = __expf(e3); s3 += p3;
      if (idx < MAXD) {
        sbuf[wave][idx] = r;
        *(float4*)&ebuf[wave][idx][0] = make_float4(p0, p1, p2, p3);
      }
    }
  }
  // zero-pad 4 slots past lim: aggregation loop then needs no bounds mask
  if (lane < 4) {
    int ip = lim + lane;
    sbuf[wave][ip] = 0;
    *(float4*)&ebuf[wave][ip][0] = make_float4(0.f, 0.f, 0.f, 0.f);
  }
  #pragma unroll
  for (int off = 32; off; off >>= 1) {
    s0 += __shfl_xor(s0, off, 64);
    s1 += __shfl_xor(s1, off, 64);
    s2 += __shfl_xor(s2, off, 64);
    s3 += __shfl_xor(s3, off, 64);
  }
  float inv0 = 1.f/(s0 + 1e-16f), inv1 = 1.f/(s1 + 1e-16f);
  float inv2 = 1.f/(s2 + 1e-16f), inv3 = 1.f/(s3 + 1e-16f);

  // aggregation: lane -> (edge-slot es=lane>>4 of 4, ch-lane cl=lane&15: ch cl*4..cl*4+3)
  int cl = lane & 15, es = lane >> 4;
  float acc[4][4];
  #pragma unroll
  for (int h = 0; h < 4; ++h)
    #pragma unroll
    for (int i = 0; i < 4; ++i) acc[h][i] = 0.f;
  {
    const uint2* base2 = (const uint2*)xb;   // row = 16 uint2 (128B)
    #pragma unroll 2
    for (int jj = 0; jj < lim; jj += 4) {
      int idx = jj + es;                     // <= lim+2 < lim+4 (padded)
      int r = sbuf[wave][idx];
      float4 pv = *(const float4*)&ebuf[wave][idx][0];
      uint2 d = base2[(size_t)r*16 + cl];
      float c0 = bflo(d.x), c1 = bfhi(d.x), c2 = bflo(d.y), c3 = bfhi(d.y);
      acc[0][0] = fmaf(pv.x, c0, acc[0][0]); acc[0][1] = fmaf(pv.x, c1, acc[0][1]);
      acc[0][2] = fmaf(pv.x, c2, acc[0][2]); acc[0][3] = fmaf(pv.x, c3, acc[0][3]);
      acc[1][0] = fmaf(pv.y, c0, acc[1][0]); acc[1][1] = fmaf(pv.y, c1, acc[1][1]);
      acc[1][2] = fmaf(pv.y, c2, acc[1][2]); acc[1][3] = fmaf(pv.y, c3, acc[1][3]);
      acc[2][0] = fmaf(pv.z, c0, acc[2][0]); acc[2][1] = fmaf(pv.z, c1, acc[2][1]);
      acc[2][2] = fmaf(pv.z, c2, acc[2][2]); acc[2][3] = fmaf(pv.z, c3, acc[2][3]);
      acc[3][0] = fmaf(pv.w, c0, acc[3][0]); acc[3][1] = fmaf(pv.w, c1, acc[3][1]);
      acc[3][2] = fmaf(pv.w, c2, acc[3][2]); acc[3][3] = fmaf(pv.w, c3, acc[3][3]);
    }
  }
  if (deg > MAXD) {       // rare overflow tail: recompute p per lane (masked scalar path)
    const uint2* base2 = (const uint2*)xb;
    for (int jj = MAXD; jj < deg; jj += 4) {
      int idx = jj + es;
      bool ok = idx < deg;
      int j = ok ? (start + idx) : start;
      int r = srcs[j];
      float4 als = *(const float4*)(al1s + (size_t)r*4);
      float e0 = als.x + ald0; e0 = e0 >= 0.f ? e0 : 0.2f*e0; float p0 = __expf(e0);
      float e1 = als.y + ald1; e1 = e1 >= 0.f ? e1 : 0.2f*e1; float p1 = __expf(e1);
      float e2 = als.z + ald2; e2 = e2 >= 0.f ? e2 : 0.2f*e2; float p2 = __expf(e2);
      float e3 = als.w + ald3; e3 = e3 >= 0.f ? e3 : 0.2f*e3; float p3 = __expf(e3);
      float m = ok ? 1.f : 0.f;
      uint2 d = base2[(size_t)r*16 + cl];
      float c0 = bflo(d.x)*m, c1 = bfhi(d.x)*m, c2 = bflo(d.y)*m, c3 = bfhi(d.y)*m;
      acc[0][0] = fmaf(p0, c0, acc[0][0]); acc[0][1] = fmaf(p0, c1, acc[0][1]);
      acc[0][2] = fmaf(p0, c2, acc[0][2]); acc[0][3] = fmaf(p0, c3, acc[0][3]);
      acc[1][0] = fmaf(p1, c0, acc[1][0]); acc[1][1] = fmaf(p1, c1, acc[1][1]);
      acc[1][2] = fmaf(p1, c2, acc[1][2]); acc[1][3] = fmaf(p1, c3, acc[1][3]);
      acc[2][0] = fmaf(p2, c0, acc[2][0]); acc[2][1] = fmaf(p2, c1, acc[2][1]);
      acc[2][2] = fmaf(p2, c2, acc[2][2]); acc[2][3] = fmaf(p2, c3, acc[2][3]);
      acc[3][0] = fmaf(p3, c0, acc[3][0]); acc[3][1] = fmaf(p3, c1, acc[3][1]);
      acc[3][2] = fmaf(p3, c2, acc[3][2]); acc[3][3] = fmaf(p3, c3, acc[3][3]);
    }
  }
  // fold the 4 edge slots (lane bits 4,5)
  #pragma unroll
  for (int h = 0; h < 4; ++h)
    #pragma unroll
    for (int i = 0; i < 4; ++i) {
      acc[h][i] += __shfl_xor(acc[h][i], 16, 64);
      acc[h][i] += __shfl_xor(acc[h][i], 32, 64);
    }
  // lane l writes head h=es, channels cl*4..cl*4+3: ag[n][es*64 + cl*4 ...] (coalesced 512B/row)
  {
    float invh = (es==0)?inv0:(es==1)?inv1:(es==2)?inv2:inv3;
    float o0 = ((es==0)?acc[0][0]:(es==1)?acc[1][0]:(es==2)?acc[2][0]:acc[3][0]) * invh;
    float o1 = ((es==0)?acc[0][1]:(es==1)?acc[1][1]:(es==2)?acc[2][1]:acc[3][1]) * invh;
    float o2 = ((es==0)?acc[0][2]:(es==1)?acc[1][2]:(es==2)?acc[2][2]:acc[3][2]) * invh;
    float o3 = ((es==0)?acc[0][3]:(es==1)?acc[1][3]:(es==2)?acc[2][3]:acc[3][3]) * invh;
    uint2 dd;
    dd.x = (unsigned)f2bu(o0) | ((unsigned)f2bu(o1) << 16);
    dd.y = (unsigned)f2bu(o2) | ((unsigned)f2bu(o3) << 16);
    ((uint2*)ag)[(size_t)n*64 + lane] = dd;
  }
}

// ---------------- GEMM1b (MFMA, block-diagonal): h1[:, h*64:+64] = elu(ag[:,h,:] @ W1[, h] + b1)
__global__ __launch_bounds__(256) void gemm1b_kernel(const unsigned short* __restrict__ ag,
    const unsigned short* __restrict__ wf1, const float* __restrict__ b1, bf16* __restrict__ h1){
  __shared__ __align__(16) unsigned short ctile[32*264];       // half-tile bf16, 16.5KB
  int tid = threadIdx.x, wave = tid >> 6, lane = tid & 63;
  int q = lane >> 4, c = lane & 15;
  int n0 = blockIdx.x * 64;

  union { uint4 u; bf16x8 v; } bfr[2][4];
  #pragma unroll
  for (int kk = 0; kk < 2; ++kk)
    #pragma unroll
    for (int nti = 0; nti < 4; ++nti)
      bfr[kk][nti].u = *(const uint4*)(wf1 + (size_t)((((kk*16 + wave*4 + nti)*4 + q)*16 + c)*8));

  float b1v[4];
  #pragma unroll
  for (int nti = 0; nti < 4; ++nti) b1v[nti] = b1[(wave*4 + nti)*16 + c];

  #pragma unroll
  for (int half = 0; half < 2; ++half) {
    #pragma unroll
    for (int sti = 0; sti < 2; ++sti) {
      int st = half*2 + sti;
      int row = n0 + st*16 + c;
      if (row >= N_NODES) row = N_NODES - 1;   // tail clamp; stores guarded below
      bf16x8 afr[2];
      #pragma unroll
      for (int kk = 0; kk < 2; ++kk) {
        union { uint4 u; bf16x8 v; } a;
        a.u = *(const uint4*)(ag + (size_t)row*256 + wave*64 + kk*32 + q*8);
        afr[kk] = a.v;
      }
      #pragma unroll
      for (int nti = 0; nti < 4; ++nti) {
        f32x4 acc = {0.f, 0.f, 0.f, 0.f};
        #pragma unroll
        for (int kk = 0; kk < 2; ++kk)
          acc = __builtin_amdgcn_mfma_f32_16x16x32_bf16(afr[kk], bfr[kk][nti].v, acc, 0, 0, 0);
        int lrow = sti*16 + q*4, nt = wave*4 + nti;
        #pragma unroll
        for (int r = 0; r < 4; ++r) {
          float o = acc[r] + b1v[nti];
          o = o > 0.f ? o : expm1f(o);
          ctile[(lrow + r)*264 + nt*16 + c] = f2bu(o);
        }
      }
    }
    __syncthreads();
    // store phase: wave w -> local rows w*8..w*8+7; coalesced 512B/row
    #pragma unroll 1
    for (int i = 0; i < 8; ++i) {
      int lr = wave*8 + i;
      int node = n0 + half*32 + lr;
      if (node < N_NODES) {
        uint2 dd = *(const uint2*)&ctile[lr*264 + lane*4];
        ((uint2*)h1)[(size_t)node*64 + lane] = dd;
      }
    }
    __syncthreads();
  }
}

// ---------------- GEMM2 (MFMA): h2pre = h1 @ W2  [50000,256]bf16 x [256,64], fused al2 ----------------
__global__ __launch_bounds__(256) void gemm2_kernel(const bf16* __restrict__ h1, const unsigned short* __restrict__ wf2,
    const float* __restrict__ a2s, const float* __restrict__ a2d,
    bf16* __restrict__ h2pre, float* __restrict__ al2s, float* __restrict__ al2d){
  __shared__ __align__(16) float ctile[64][65];               // padded
  int tid = threadIdx.x, wave = tid >> 6, lane = tid & 63;
  int q = lane >> 4, c = lane & 15;
  int n0 = blockIdx.x * 64;

  union { uint4 u; bf16x8 v; } bfr[8];
  #pragma unroll
  for (int kk = 0; kk < 8; ++kk)
    bfr[kk].u = *(const uint4*)(wf2 + (size_t)((((kk*4 + wave)*4 + q)*16 + c)*8));

  const unsigned short* h1u = (const unsigned short*)h1;
  #pragma unroll 1
  for (int st = 0; st < 4; ++st) {
    if (n0 + st*16 >= N_NODES) break;
    f32x4 acc = {0.f, 0.f, 0.f, 0.f};
    size_t arow = (size_t)(n0 + st*16 + c)*256 + q*8;
    #pragma unroll
    for (int kk = 0; kk < 8; ++kk) {
      union { uint4 u; bf16x8 v; } a;
      a.u = *(const uint4*)(h1u + arow + kk*32);
      acc = __builtin_amdgcn_mfma_f32_16x16x32_bf16(a.v, bfr[kk].v, acc, 0, 0, 0);
    }
    #pragma unroll
    for (int r = 0; r < 4; ++r)
      ctile[st*16 + q*4 + r][wave*16 + c] = acc[r];
  }
  __syncthreads();

  float as = a2s[lane], ad = a2d[lane];
  #pragma unroll 1
  for (int i = 0; i < 16; ++i) {
    int node = n0 + wave*16 + i;
    if (node >= N_NODES) break;
    float val = ctile[wave*16 + i][lane];
    ((unsigned short*)h2pre)[(size_t)node*64 + lane] = f2bu(val);
    float ps = val*as, pd = val*ad;
    #pragma unroll
    for (int off = 32; off; off >>= 1) { ps += __shfl_xor(ps, off, 64); pd += __shfl_xor(pd, off, 64); }
    if (lane == 0) { al2s[node] = ps; al2d[node] = pd; }
  }
}

// ---------------- Attention layer 2 (H=1, no max pass), slim: writes post-ELU h2 (fp32) only ----------------
__global__ __launch_bounds__(512, 8) void attn2_kernel(const bf16* __restrict__ h2pre,
    const float* __restrict__ al2s, const float* __restrict__ al2d,
    const int* __restrict__ offs, const int* __restrict__ srcs,
    const float* __restrict__ b2, float* __restrict__ h2f){
  __shared__ float ebuf[8][MAXD+8];             // p values, +8 zero pad
  __shared__ int   sbuf[8][MAXD+8];
  int wave = threadIdx.x >> 6, lane = threadIdx.x & 63;
  int n = blockIdx.x*8 + wave;        // exact
  int start = offs[n], end = offs[n+1];
  int deg = end - start;
  int lim = deg < MAXD ? deg : MAXD;
  float ald = al2d[n];

  float sm = 0.f;
  {
    int idx = lane;
    for (int j = start + lane; j < end; j += 64, idx += 64) {
      int r = srcs[j];
      float t = al2s[r] + ald; t = t >= 0.f ? t : 0.2f*t;
      float p = __expf(t); sm += p;
      if (idx < MAXD) { sbuf[wave][idx] = r; ebuf[wave][idx] = p; }
    }
  }
  if (lane < 8) { int ip = lim + lane; sbuf[wave][ip] = 0; ebuf[wave][ip] = 0.f; }
  #pragma unroll
  for (int off = 32; off; off >>= 1) sm += __shfl_xor(sm, off, 64);
  float inv = 1.f/(sm + 1e-16f);

  // aggregation: lane -> (edge-slot es=lane>>3, channel-lane cl=lane&7); uint4 = channels cl*8..cl*8+7
  // padded p-buffer: no bounds mask in hot loop
  int cl = lane & 7, es = lane >> 3;
  float acc0 = 0.f, acc1 = 0.f, acc2 = 0.f, acc3 = 0.f;
  float acc4 = 0.f, acc5 = 0.f, acc6 = 0.f, acc7 = 0.f;
  {
    const uint4* base4 = (const uint4*)h2pre;   // row = 8 uint4
    #pragma unroll 2
    for (int jj = 0; jj < lim; jj += 8) {
      int idx = jj + es;                        // <= lim+6 < lim+8 (padded)
      int r = sbuf[wave][idx];
      float p = ebuf[wave][idx];
      uint4 d = base4[(size_t)r*8 + cl];
      acc0 = fmaf(p, bflo(d.x), acc0);
      acc1 = fmaf(p, bfhi(d.x), acc1);
      acc2 = fmaf(p, bflo(d.y), acc2);
      acc3 = fmaf(p, bfhi(d.y), acc3);
      acc4 = fmaf(p, bflo(d.z), acc4);
      acc5 = fmaf(p, bfhi(d.z), acc5);
      acc6 = fmaf(p, bflo(d.w), acc6);
      acc7 = fmaf(p, bfhi(d.w), acc7);
    }
  }
  if (deg > MAXD) {     // rare overflow tail
    const uint4* base4 = (const uint4*)h2pre;
    for (int jj = MAXD; jj < deg; jj += 8) {
      int idx = jj + es;
      bool ok = idx < deg;
      int j = ok ? (start + idx) : start;
      int r = srcs[j];
      float t = al2s[r] + ald; t = t >= 0.f ? t : 0.2f*t;
      float p = ok ? __expf(t) : 0.f;
      uint4 d = base4[(size_t)r*8 + cl];
      acc0 = fmaf(p, bflo(d.x), acc0);
      acc1 = fmaf(p, bfhi(d.x), acc1);
      acc2 = fmaf(p, bflo(d.y), acc2);
      acc3 = fmaf(p, bfhi(d.y), acc3);
      acc4 = fmaf(p, bflo(d.z), acc4);
      acc5 = fmaf(p, bfhi(d.z), acc5);
      acc6 = fmaf(p, bflo(d.w), acc6);
      acc7 = fmaf(p, bfhi(d.w), acc7);
    }
  }
  // fold the 8 edge-slots (xor butterfly over lane bits 3,4,5)
  #pragma unroll
  for (int off = 8; off < 64; off <<= 1) {
    acc0 += __shfl_xor(acc0, off, 64);
    acc1 += __shfl_xor(acc1, off, 64);
    acc2 += __shfl_xor(acc2, off, 64);
    acc3 += __shfl_xor(acc3, off, 64);
    acc4 += __shfl_xor(acc4, off, 64);
    acc5 += __shfl_xor(acc5, off, 64);
    acc6 += __shfl_xor(acc6, off, 64);
    acc7 += __shfl_xor(acc7, off, 64);
  }

  if (es == 0) {
    float4 b2a = *(const float4*)(b2 + cl*8);
    float4 b2b = *(const float4*)(b2 + cl*8 + 4);
    float o0 = acc0*inv + b2a.x; o0 = o0 > 0.f ? o0 : expm1f(o0);
    float o1 = acc1*inv + b2a.y; o1 = o1 > 0.f ? o1 : expm1f(o1);
    float o2 = acc2*inv + b2a.z; o2 = o2 > 0.f ? o2 : expm1f(o2);
    float o3 = acc3*inv + b2a.w; o3 = o3 > 0.f ? o3 : expm1f(o3);
    float o4 = acc4*inv + b2b.x; o4 = o4 > 0.f ? o4 : expm1f(o4);
    float o5 = acc5*inv + b2b.y; o5 = o5 > 0.f ? o5 : expm1f(o5);
    float o6 = acc6*inv + b2b.z; o6 = o6 > 0.f ? o6 : expm1f(o6);
    float o7 = acc7*inv + b2b.w; o7 = o7 > 0.f ? o7 : expm1f(o7);
    *(float4*)(h2f + (size_t)n*64 + cl*8)     = make_float4(o0, o1, o2, o3);
    *(float4*)(h2f + (size_t)n*64 + cl*8 + 4) = make_float4(o4, o5, o6, o7);
  }
}

// ---------------- Node head: node_out = h2 @ Wn + bn; u = h2.We[0:64]; v = h2.We[64:128] ----------------
__global__ __launch_bounds__(256) void head_kernel(const float* __restrict__ h2f,
    const float* __restrict__ Wn, const float* __restrict__ bn, const float* __restrict__ We,
    float* __restrict__ u, float* __restrict__ v, float* __restrict__ node_out){
  __shared__ __align__(16) float sh[8][64];
  int tid = threadIdx.x;
  int nb = blockIdx.x*8;              // 50000/8 = 6250 exact
  {
    float2 t = *(const float2*)(h2f + (size_t)nb*64 + tid*2);
    *(float2*)&sh[tid >> 5][(tid & 31)*2] = t;
  }
  __syncthreads();
  int wave = tid >> 6, lane = tid & 63;
  int sub = lane >> 5, j = lane & 31;
  int local = wave*2 + sub;           // 0..7
  int n = nb + local;
  const float* h = sh[local];
  // node_out = h . Wn[:,j]
  float a = 0.f;
  #pragma unroll 16
  for (int k = 0; k < 64; ++k)
    a = fmaf(h[k], Wn[k*32 + j], a);
  node_out[(size_t)n*32 + j] = a + bn[j];
  // u,v partials over k = j, j+32; butterfly within the 32-lane group
  float pu = h[j]*We[j] + h[j+32]*We[j+32];
  float pv = h[j]*We[64+j] + h[j+32]*We[96+j];
  #pragma unroll
  for (int off = 1; off < 32; off <<= 1) {
    pu += __shfl_xor(pu, off, 64);
    pv += __shfl_xor(pv, off, 64);
  }
  if (j == 0) { u[n] = pu; v[n] = pv; }
}

// ---------------- Edge head: out = u[row] + v[col] + edge_attr . We[128:144] + be ----------------
__global__ __launch_bounds__(256) void edge_kernel(const int* __restrict__ ei, const float* __restrict__ ea,
    const float* __restrict__ u, const float* __restrict__ v,
    const float* __restrict__ We, const float* __restrict__ be, float* __restrict__ out){
  int k = blockIdx.x*256 + threadIdx.x;   // grid is exact: 800000/256
  int r = ei[k], c = ei[N_EDGES + k];
  float val = u[r] + v[c] + be[0];
  const float4* wp = (const float4*)(We + 128);
  const float4* p  = (const float4*)(ea + (size_t)k*16);
  #pragma unroll
  for (int jj = 0; jj < 4; jj++) {
    float4 q = p[jj], wq = wp[jj];
    val = fmaf(q.x, wq.x, val);
    val = fmaf(q.y, wq.y, val);
    val = fmaf(q.z, wq.z, val);
    val = fmaf(q.w, wq.w, val);
  }
  out[k] = val;
}

extern "C" void kernel_launch(void* const* d_in, const int* in_sizes, int n_in,
                              void* d_out, int out_size, void* d_ws, size_t ws_size,
                              hipStream_t stream) {
  const float* x   = (const float*)d_in[0];
  const int*   ei  = (const int*)d_in[1];
  const float* ea  = (const float*)d_in[2];
  const float* W1  = (const float*)d_in[3];
  const float* a1s = (const float*)d_in[4];
  const float* a1d = (const float*)d_in[5];
  const float* b1  = (const float*)d_in[6];
  const float* W2  = (const float*)d_in[7];
  const float* a2s = (const float*)d_in[8];
  const float* a2d = (const float*)d_in[9];
  const float* b2  = (const float*)d_in[10];
  const float* Wn  = (const float*)d_in[11];
  const float* bn  = (const float*)d_in[12];
  const float* We  = (const float*)d_in[13];
  const float* be  = (const float*)d_in[14];
  float* out = (float*)d_out;

  // ---- workspace layout, peak 64,000,224 B, 16B-aligned ----
  char* w = (char*)d_ws;
  int*   offs   = (int*)(w);                        //       0 .. 200,016
  unsigned short* wf1 = (unsigned short*)(w + 200016); // 32,768 B
  float* ws1    = (float*)(w + 232784);             // 1,024 B
  float* wd1    = (float*)(w + 233808);             // 1,024 B
  unsigned short* wf2 = (unsigned short*)(w + 234832); // 32,768 B (.. 267,600)
  int*   bcur   = (int*)(w + 400016);               // 784 B bucket counts
  int*   srcs   = (int*)(w + 600016);               // 600,016 .. 4,000,016
  float* al1s   = (float*)(w + 4000016);            // [N,4] fp32, .. 4,800,016
  float* al1d   = (float*)(w + 4800016);            // [N,4] fp32, .. 5,600,016
  float* al2s   = (float*)(w + 5600016);            // [N] fp32,  .. 5,800,016
  float* al2d   = (float*)(w + 5800016);            // .. 6,000,016
  float* uu     = (float*)(w + 6000016);            // .. 6,200,016
  float* vv     = (float*)(w + 6200016);            // .. 6,400,016
  bf16*  h2pre  = (bf16*)(w + 6400016);             // [N,64] bf16, .. 12,800,016 (xb aliases BEFORE gemm2)
  bf16*  ag     = (bf16*)(w + 12800016);            // [N,256] bf16 aggregate, .. 38,400,016
  bf16*  h1     = (bf16*)(w + 38400224);            // [N,256] bf16, .. 64,000,224
  unsigned short* xb  = (unsigned short*)h2pre;     // [N,64] bf16 x-table; dead before gemm2 writes h2pre
  unsigned int* pairbuf = (unsigned int*)h1;        // 6.4 MB bucket regions (h1 dead until gemm1b)
  float* h2f = (float*)ag;                          // [N,64] fp32 post-ELU h2 (ag dead after gemm1b)

  wfrag_kernel     <<<130, 256, 0, stream>>>(W1, W2, a1s, a1d, wf1, wf2, ws1, wd1, bcur);
  binscatter_kernel<<<(N_TOT + 4095)/4096, 256, 0, stream>>>(ei, bcur, pairbuf);
  lscatter2_kernel <<<NBUCK, 256, 0, stream>>>(pairbuf, bcur, offs, srcs);
  xprep_kernel     <<<N_NODES/16, 256, 0, stream>>>(x, ws1, wd1, xb, al1s, al1d);
  attn1x_kernel    <<<N_NODES/4, 256, 0, stream>>>(xb, al1s, al1d, offs, srcs, ag);
  gemm1b_kernel    <<<(N_NODES + 63)/64, 256, 0, stream>>>((const unsigned short*)ag, wf1, b1, h1);
  gemm2_kernel     <<<(N_NODES + 63)/64, 256, 0, stream>>>(h1, wf2, a2s, a2d, h2pre, al2s, al2d);
  attn2_kernel     <<<N_NODES/8, 512, 0, stream>>>(h2pre, al2s, al2d, offs, srcs, b2, h2f);
  head_kernel      <<<N_NODES/8, 256, 0, stream>>>(h2f, Wn, bn, We, uu, vv, out);
  edge_kernel      <<<N_EDGES/256, 256, 0, stream>>>(ei, ea, uu, vv, We, be, out + (size_t)N_NODES*32);
}

// Round 11
// 301.689 us; speedup vs baseline: 1.1219x; 1.0371x over previous
//
#include <hip/hip_runtime.h>
#include <hip/hip_bf16.h>

#define N_NODES 50000
#define N_EDGES 800000
#define N_TOT   850000   // edges + self loops
#define MAXD    128      // LDS-staged edges per node; tail handled by fallback

// bucketed CSR build: bucket = dst >> 8 (256 nodes/bucket)
#define NBUCK 196        // ceil(50000/256)
#define BCAP  8192       // fixed bucket capacity (mean 4337, std ~66 -> 58 sigma slack)

typedef __hip_bfloat16 bf16;
typedef __attribute__((ext_vector_type(8))) short bf16x8;   // MFMA A/B frag (4 VGPRs)
typedef __attribute__((ext_vector_type(4))) float f32x4;    // MFMA C/D frag

__device__ __forceinline__ unsigned short f2bu(float v){
  union { bf16 b; unsigned short u; } cv; cv.b = __float2bfloat16(v); return cv.u;
}
__device__ __forceinline__ float bflo(unsigned int d){ return __uint_as_float(d << 16); }
__device__ __forceinline__ float bfhi(unsigned int d){ return __uint_as_float(d & 0xffff0000u); }

// ---------------- W-frag prep + attention-vector fold + bucket-count init ----------------
// blocks 0..127: W1,W2 -> bf16 B-frag layout. block 128: ws1/wd1. block 129: zero bcur (counts).
__global__ __launch_bounds__(256) void wfrag_kernel(const float* __restrict__ W1, const float* __restrict__ W2,
    const float* __restrict__ a1s, const float* __restrict__ a1d,
    unsigned short* __restrict__ wf1, unsigned short* __restrict__ wf2,
    float* __restrict__ ws1, float* __restrict__ wd1, int* __restrict__ bcur){
  int b = blockIdx.x, tid = threadIdx.x;
  if (b < 128) {
    int i = b*256 + tid;   // 32768 threads exact
    if (i < 16384) {
      int k = i >> 8, n = i & 255;
      int kk = k >> 5, qq = (k >> 3) & 3, j = k & 7, nt = n >> 4, cc = n & 15;
      wf1[(((kk*16 + nt)*4 + qq)*16 + cc)*8 + j] = f2bu(W1[i]);
    } else {
      int i2 = i - 16384;
      int k = i2 >> 6, n = i2 & 63;
      int kk = k >> 5, qq = (k >> 3) & 3, j = k & 7, ch = n >> 4, cc = n & 15;
      wf2[(((kk*4 + ch)*4 + qq)*16 + cc)*8 + j] = f2bu(W2[i2]);
    }
  } else if (b == 128) {
    // ws1[k][h] = sum_c W1[k, h*64+c] * a1s[h, c]   (64x4 each)
    int k = tid >> 2, h = tid & 3;
    const float* wrow = W1 + k*256 + h*64;
    const float* as = a1s + h*64;
    const float* ad = a1d + h*64;
    float ss = 0.f, sd = 0.f;
    #pragma unroll 8
    for (int c = 0; c < 64; ++c) {
      float wv = wrow[c];
      ss = fmaf(wv, as[c], ss);
      sd = fmaf(wv, ad[c], sd);
    }
    ws1[k*4 + h] = ss;
    wd1[k*4 + h] = sd;
  } else {
    if (tid < NBUCK) bcur[tid] = 0;     // counts now (not absolute cursors)
  }
}

// ---------------- CSR build, stage 1: bin edges into 196 bucket regions ----------------
__global__ __launch_bounds__(256) void binscatter_kernel(const int* __restrict__ ei,
    int* __restrict__ bcur, unsigned int* __restrict__ pairbuf){
  __shared__ int hist[NBUCK];
  __shared__ int gbase[NBUCK];
  int tid = threadIdx.x;
  if (tid < NBUCK) hist[tid] = 0;
  __syncthreads();
  int base = blockIdx.x * 4096;
  #pragma unroll 4
  for (int i = 0; i < 16; ++i) {
    int k = base + i*256 + tid;
    if (k < N_TOT) {
      int c = (k < N_EDGES) ? ei[N_EDGES + k] : (k - N_EDGES);
      atomicAdd(&hist[c >> 8], 1);
    }
  }
  __syncthreads();
  if (tid < NBUCK) {
    int h = hist[tid];
    gbase[tid] = h ? (tid*BCAP + atomicAdd(&bcur[tid], h)) : 0;
    hist[tid] = 0;                       // reuse as local cursor
  }
  __syncthreads();
  #pragma unroll 4
  for (int i = 0; i < 16; ++i) {
    int k = base + i*256 + tid;
    if (k < N_TOT) {
      int r, c;
      if (k < N_EDGES) { r = ei[k]; c = ei[N_EDGES + k]; } else { r = c = k - N_EDGES; }
      int b = c >> 8;
      int lpos = atomicAdd(&hist[b], 1);
      pairbuf[gbase[b] + lpos] = (unsigned)r | ((unsigned)(c & 255) << 16);
    }
  }
}

// ---------------- CSR build, stage 2: per-bucket {bucket-scan + count + scan + offs + scatter} ----
__global__ __launch_bounds__(256) void lscatter2_kernel(const unsigned int* __restrict__ pairbuf,
    const int* __restrict__ bcur, int* __restrict__ offs, int* __restrict__ srcs){
  __shared__ int sbase[256];
  __shared__ int lhist[256];
  __shared__ int lcur[256];
  int b = blockIdx.x, tid = threadIdx.x;
  // redundant 196-bucket scan (cheap; removes separate scan dispatch)
  int sz = 0;
  if (tid < NBUCK) {
    sz = bcur[tid];
    if (sz < 0) sz = 0; if (sz > BCAP) sz = BCAP;
  }
  sbase[tid] = sz;
  lhist[tid] = 0;
  __syncthreads();
  for (int off = 1; off < 256; off <<= 1) {
    int t = (tid >= off) ? sbase[tid - off] : 0;
    __syncthreads();
    sbase[tid] += t;
    __syncthreads();
  }
  int bbase_b = (b == 0) ? 0 : sbase[b - 1];
  int size = sbase[b] - bbase_b;                 // min(bcur[b], BCAP)
  int base = b * BCAP;
  // per-node counts within bucket
  for (int j = tid; j < size; j += 256)
    atomicAdd(&lhist[pairbuf[base + j] >> 16], 1);
  __syncthreads();
  int v = lhist[tid];
  lcur[tid] = v;
  __syncthreads();
  for (int off = 1; off < 256; off <<= 1) {
    int t = (tid >= off) ? lcur[tid - off] : 0;
    __syncthreads();
    lcur[tid] += t;
    __syncthreads();
  }
  int excl = lcur[tid] - v;
  int gpos = bbase_b + excl;
  int node = b*256 + tid;
  if (node < N_NODES) offs[node] = gpos;
  if (b == 0 && tid == 0) offs[N_NODES] = N_TOT;
  __syncthreads();
  lcur[tid] = gpos;       // per-node cursor
  __syncthreads();
  for (int j = tid; j < size; j += 256) {
    unsigned pv = pairbuf[base + j];
    int pos = atomicAdd(&lcur[pv >> 16], 1);
    srcs[pos] = (int)(pv & 0xFFFFu);
  }
}

// ---------------- xprep: xb = bf16(x); al1{s,d} = x @ w{s,d}1 ----------------
__global__ __launch_bounds__(256) void xprep_kernel(const float* __restrict__ x,
    const float* __restrict__ ws1, const float* __restrict__ wd1,
    unsigned short* __restrict__ xb, float* __restrict__ al1s, float* __restrict__ al1d){
  __shared__ float sws[64][4], swd[64][4];
  int tid = threadIdx.x;
  sws[tid >> 2][tid & 3] = ws1[tid];
  swd[tid >> 2][tid & 3] = wd1[tid];
  __syncthreads();
  int lane = tid & 63, wave = tid >> 6;
  int g = lane & 15, sub = lane >> 4;
  int n = blockIdx.x*16 + wave*4 + sub;     // 50000/16 = 3125 exact
  float4 xv = *(const float4*)(x + (size_t)n*64 + g*4);
  uint2 dd;
  dd.x = (unsigned)f2bu(xv.x) | ((unsigned)f2bu(xv.y) << 16);
  dd.y = (unsigned)f2bu(xv.z) | ((unsigned)f2bu(xv.w) << 16);
  ((uint2*)xb)[(size_t)n*16 + g] = dd;
  int c0 = g*4;
  float ps0 = 0.f, ps1 = 0.f, ps2 = 0.f, ps3 = 0.f;
  float pd0 = 0.f, pd1 = 0.f, pd2 = 0.f, pd3 = 0.f;
  float xc[4] = {xv.x, xv.y, xv.z, xv.w};
  #pragma unroll
  for (int i = 0; i < 4; ++i) {
    int c = c0 + i;
    ps0 = fmaf(xc[i], sws[c][0], ps0); ps1 = fmaf(xc[i], sws[c][1], ps1);
    ps2 = fmaf(xc[i], sws[c][2], ps2); ps3 = fmaf(xc[i], sws[c][3], ps3);
    pd0 = fmaf(xc[i], swd[c][0], pd0); pd1 = fmaf(xc[i], swd[c][1], pd1);
    pd2 = fmaf(xc[i], swd[c][2], pd2); pd3 = fmaf(xc[i], swd[c][3], pd3);
  }
  #pragma unroll
  for (int off = 1; off < 16; off <<= 1) {
    ps0 += __shfl_xor(ps0, off, 64); ps1 += __shfl_xor(ps1, off, 64);
    ps2 += __shfl_xor(ps2, off, 64); ps3 += __shfl_xor(ps3, off, 64);
    pd0 += __shfl_xor(pd0, off, 64); pd1 += __shfl_xor(pd1, off, 64);
    pd2 += __shfl_xor(pd2, off, 64); pd3 += __shfl_xor(pd3, off, 64);
  }
  if (g < 4)      al1s[(size_t)n*4 + g]       = (g==0)?ps0:(g==1)?ps1:(g==2)?ps2:ps3;
  else if (g < 8) al1d[(size_t)n*4 + (g-4)]   = (g==4)?pd0:(g==5)?pd1:(g==6)?pd2:pd3;
}

// ------- Attention layer 1 in x-space: ag[n,h,:64] = sum_j alpha_{j,h} * xb[r_j]
// zero-padded p-buffer (no bounds mask) + unroll 2 (VGPR ~28 -> 65% occupancy [R7])
__global__ __launch_bounds__(256, 8) void attn1x_kernel(const unsigned short* __restrict__ xb,
    const float* __restrict__ al1s, const float* __restrict__ al1d,
    const int* __restrict__ offs, const int* __restrict__ srcs,
    bf16* __restrict__ ag){
  __shared__ __align__(16) float ebuf[4][MAXD+4][4];     // p values, +4 zero pad
  __shared__ int sbuf[4][MAXD+4];

  int wave = threadIdx.x >> 6, lane = threadIdx.x & 63;
  int n = blockIdx.x*4 + wave;          // 50000 % 4 == 0: no tail
  int start = offs[n], end = offs[n+1];
  int deg = end - start;
  int lim = deg < MAXD ? deg : MAXD;
  float4 aldv = *(const float4*)(al1d + (size_t)n*4);
  float ald0 = aldv.x, ald1 = aldv.y, ald2 = aldv.z, ald3 = aldv.w;

  // stage pass: gather als, e=lrelu, p=exp(e); stage p+src; lane sums
  float s0 = 0.f, s1 = 0.f, s2 = 0.f, s3 = 0.f;
  {
    int idx = lane;
    for (int j = start + lane; j < end; j += 64, idx += 64) {
      int r = srcs[j];
      float4 als = *(const float4*)(al1s + (size_t)r*4);
      float e0 = als.x + ald0; e0 = e0 >= 0.f ? e0 : 0.2f*e0; float p0 = __expf(e0); s0 += p0;
      float e1 = als.y + ald1; e1 = e1 >= 0.f ? e1 : 0.2f*e1; float p1 = __expf(e1); s1 += p1;
      float e2 = als.z + ald2; e2 = e2 >= 0.f ? e2 : 0.2f*e2; float p2 = __expf(e2); s2 += p2;
      float e3 = als.w + ald3; e3 = e3 >= 0.f ? e3 : 0.2f*e3; float p3 = __expf(e3); s3 += p3;
      if (idx < MAXD) {
        sbuf[wave][idx] = r;
        *(float4*)&ebuf[wave][idx][0] = make_float4(p0, p1, p2, p3);
      }
    }
  }
  // zero-pad 4 slots past lim: aggregation loop then needs no bounds mask
  if (lane < 4) {
    int ip = lim + lane;
    sbuf[wave][ip] = 0;
    *(float4*)&ebuf[wave][ip][0] = make_float4(0.f, 0.f, 0.f, 0.f);
  }
  #pragma unroll
  for (int off = 32; off; off >>= 1) {
    s0 += __shfl_xor(s0, off, 64);
    s1 += __shfl_xor(s1, off, 64);
    s2 += __shfl_xor(s2, off, 64);
    s3 += __shfl_xor(s3, off, 64);
  }
  float inv0 = 1.f/(s0 + 1e-16f), inv1 = 1.f/(s1 + 1e-16f);
  float inv2 = 1.f/(s2 + 1e-16f), inv3 = 1.f/(s3 + 1e-16f);

  // aggregation: lane -> (edge-slot es=lane>>4 of 4, ch-lane cl=lane&15: ch cl*4..cl*4+3)
  int cl = lane & 15, es = lane >> 4;
  float acc[4][4];
  #pragma unroll
  for (int h = 0; h < 4; ++h)
    #pragma unroll
    for (int i = 0; i < 4; ++i) acc[h][i] = 0.f;
  {
    const uint2* base2 = (const uint2*)xb;   // row = 16 uint2 (128B)
    #pragma unroll 2
    for (int jj = 0; jj < lim; jj += 4) {
      int idx = jj + es;                     // <= lim+2 < lim+4 (padded)
      int r = sbuf[wave][idx];
      float4 pv = *(const float4*)&ebuf[wave][idx][0];
      uint2 d = base2[(size_t)r*16 + cl];
      float c0 = bflo(d.x), c1 = bfhi(d.x), c2 = bflo(d.y), c3 = bfhi(d.y);
      acc[0][0] = fmaf(pv.x, c0, acc[0][0]); acc[0][1] = fmaf(pv.x, c1, acc[0][1]);
      acc[0][2] = fmaf(pv.x, c2, acc[0][2]); acc[0][3] = fmaf(pv.x, c3, acc[0][3]);
      acc[1][0] = fmaf(pv.y, c0, acc[1][0]); acc[1][1] = fmaf(pv.y, c1, acc[1][1]);
      acc[1][2] = fmaf(pv.y, c2, acc[1][2]); acc[1][3] = fmaf(pv.y, c3, acc[1][3]);
      acc[2][0] = fmaf(pv.z, c0, acc[2][0]); acc[2][1] = fmaf(pv.z, c1, acc[2][1]);
      acc[2][2] = fmaf(pv.z, c2, acc[2][2]); acc[2][3] = fmaf(pv.z, c3, acc[2][3]);
      acc[3][0] = fmaf(pv.w, c0, acc[3][0]); acc[3][1] = fmaf(pv.w, c1, acc[3][1]);
      acc[3][2] = fmaf(pv.w, c2, acc[3][2]); acc[3][3] = fmaf(pv.w, c3, acc[3][3]);
    }
  }
  if (deg > MAXD) {       // rare overflow tail: recompute p per lane (masked scalar path)
    const uint2* base2 = (const uint2*)xb;
    for (int jj = MAXD; jj < deg; jj += 4) {
      int idx = jj + es;
      bool ok = idx < deg;
      int j = ok ? (start + idx) : start;
      int r = srcs[j];
      float4 als = *(const float4*)(al1s + (size_t)r*4);
      float e0 = als.x + ald0; e0 = e0 >= 0.f ? e0 : 0.2f*e0; float p0 = __expf(e0);
      float e1 = als.y + ald1; e1 = e1 >= 0.f ? e1 : 0.2f*e1; float p1 = __expf(e1);
      float e2 = als.z + ald2; e2 = e2 >= 0.f ? e2 : 0.2f*e2; float p2 = __expf(e2);
      float e3 = als.w + ald3; e3 = e3 >= 0.f ? e3 : 0.2f*e3; float p3 = __expf(e3);
      float m = ok ? 1.f : 0.f;
      uint2 d = base2[(size_t)r*16 + cl];
      float c0 = bflo(d.x)*m, c1 = bfhi(d.x)*m, c2 = bflo(d.y)*m, c3 = bfhi(d.y)*m;
      acc[0][0] = fmaf(p0, c0, acc[0][0]); acc[0][1] = fmaf(p0, c1, acc[0][1]);
      acc[0][2] = fmaf(p0, c2, acc[0][2]); acc[0][3] = fmaf(p0, c3, acc[0][3]);
      acc[1][0] = fmaf(p1, c0, acc[1][0]); acc[1][1] = fmaf(p1, c1, acc[1][1]);
      acc[1][2] = fmaf(p1, c2, acc[1][2]); acc[1][3] = fmaf(p1, c3, acc[1][3]);
      acc[2][0] = fmaf(p2, c0, acc[2][0]); acc[2][1] = fmaf(p2, c1, acc[2][1]);
      acc[2][2] = fmaf(p2, c2, acc[2][2]); acc[2][3] = fmaf(p2, c3, acc[2][3]);
      acc[3][0] = fmaf(p3, c0, acc[3][0]); acc[3][1] = fmaf(p3, c1, acc[3][1]);
      acc[3][2] = fmaf(p3, c2, acc[3][2]); acc[3][3] = fmaf(p3, c3, acc[3][3]);
    }
  }
  // fold the 4 edge slots (lane bits 4,5)
  #pragma unroll
  for (int h = 0; h < 4; ++h)
    #pragma unroll
    for (int i = 0; i < 4; ++i) {
      acc[h][i] += __shfl_xor(acc[h][i], 16, 64);
      acc[h][i] += __shfl_xor(acc[h][i], 32, 64);
    }
  // lane l writes head h=es, channels cl*4..cl*4+3: ag[n][es*64 + cl*4 ...] (coalesced 512B/row)
  {
    float invh = (es==0)?inv0:(es==1)?inv1:(es==2)?inv2:inv3;
    float o0 = ((es==0)?acc[0][0]:(es==1)?acc[1][0]:(es==2)?acc[2][0]:acc[3][0]) * invh;
    float o1 = ((es==0)?acc[0][1]:(es==1)?acc[1][1]:(es==2)?acc[2][1]:acc[3][1]) * invh;
    float o2 = ((es==0)?acc[0][2]:(es==1)?acc[1][2]:(es==2)?acc[2][2]:acc[3][2]) * invh;
    float o3 = ((es==0)?acc[0][3]:(es==1)?acc[1][3]:(es==2)?acc[2][3]:acc[3][3]) * invh;
    uint2 dd;
    dd.x = (unsigned)f2bu(o0) | ((unsigned)f2bu(o1) << 16);
    dd.y = (unsigned)f2bu(o2) | ((unsigned)f2bu(o3) << 16);
    ((uint2*)ag)[(size_t)n*64 + lane] = dd;
  }
}

// ---------------- Fused GEMM1b+GEMM2 (MFMA): per 64-node tile,
// phase 1: h1_tile = elu(ag @ W1 + b1) -> LDS bf16 (never touches global; saves 51MB round-trip)
// phase 2: h2pre = h1_tile @ W2 from LDS, fused al2. Dependency is tile-local: gemm2's A-rows
// for tile n0 are exactly gemm1b's outputs for tile n0 [R11 fusion].
__global__ __launch_bounds__(256) void gemm12_kernel(const unsigned short* __restrict__ ag,
    const unsigned short* __restrict__ wf1, const unsigned short* __restrict__ wf2,
    const float* __restrict__ b1, const float* __restrict__ a2s, const float* __restrict__ a2d,
    bf16* __restrict__ h2pre, float* __restrict__ al2s, float* __restrict__ al2d){
  __shared__ __align__(16) unsigned short ctile[64*264];      // h1 tile bf16, 33.8KB (264 = 256+8 pad)
  __shared__ __align__(16) float ctile2[64][65];              // h2 f32 transpose buffer, 16.6KB
  int tid = threadIdx.x, wave = tid >> 6, lane = tid & 63;
  int q = lane >> 4, c = lane & 15;
  int n0 = blockIdx.x * 64;

  // ---- phase 1: gemm1b (block-diagonal W1), output to LDS only ----
  {
    union { uint4 u; bf16x8 v; } bfr[2][4];
    #pragma unroll
    for (int kk = 0; kk < 2; ++kk)
      #pragma unroll
      for (int nti = 0; nti < 4; ++nti)
        bfr[kk][nti].u = *(const uint4*)(wf1 + (size_t)((((kk*16 + wave*4 + nti)*4 + q)*16 + c)*8));

    float b1v[4];
    #pragma unroll
    for (int nti = 0; nti < 4; ++nti) b1v[nti] = b1[(wave*4 + nti)*16 + c];

    #pragma unroll 1
    for (int st = 0; st < 4; ++st) {
      int row = n0 + st*16 + c;
      if (row >= N_NODES) row = N_NODES - 1;   // tail clamp; phase-2 stores guarded below
      bf16x8 afr[2];
      #pragma unroll
      for (int kk = 0; kk < 2; ++kk) {
        union { uint4 u; bf16x8 v; } a;
        a.u = *(const uint4*)(ag + (size_t)row*256 + wave*64 + kk*32 + q*8);
        afr[kk] = a.v;
      }
      #pragma unroll
      for (int nti = 0; nti < 4; ++nti) {
        f32x4 acc = {0.f, 0.f, 0.f, 0.f};
        #pragma unroll
        for (int kk = 0; kk < 2; ++kk)
          acc = __builtin_amdgcn_mfma_f32_16x16x32_bf16(afr[kk], bfr[kk][nti].v, acc, 0, 0, 0);
        int lrow = st*16 + q*4, nt = wave*4 + nti;
        #pragma unroll
        for (int r = 0; r < 4; ++r) {
          float o = acc[r] + b1v[nti];
          o = o > 0.f ? o : expm1f(o);
          ctile[(lrow + r)*264 + nt*16 + c] = f2bu(o);
        }
      }
    }
  }
  __syncthreads();

  // ---- phase 2: gemm2 (h1_tile @ W2), A-frags from LDS ----
  {
    union { uint4 u; bf16x8 v; } bfr[8];
    #pragma unroll
    for (int kk = 0; kk < 8; ++kk)
      bfr[kk].u = *(const uint4*)(wf2 + (size_t)((((kk*4 + wave)*4 + q)*16 + c)*8));

    #pragma unroll 1
    for (int st = 0; st < 4; ++st) {
      if (n0 + st*16 >= N_NODES) break;       // block-uniform
      f32x4 acc = {0.f, 0.f, 0.f, 0.f};
      int arow = (st*16 + c)*264 + q*8;
      #pragma unroll
      for (int kk = 0; kk < 8; ++kk) {
        union { uint4 u; bf16x8 v; } a;
        a.u = *(const uint4*)&ctile[arow + kk*32];
        acc = __builtin_amdgcn_mfma_f32_16x16x32_bf16(a.v, bfr[kk].v, acc, 0, 0, 0);
      }
      #pragma unroll
      for (int r = 0; r < 4; ++r)
        ctile2[st*16 + q*4 + r][wave*16 + c] = acc[r];
    }
  }
  __syncthreads();

  float as = a2s[lane], ad = a2d[lane];
  #pragma unroll 1
  for (int i = 0; i < 16; ++i) {
    int node = n0 + wave*16 + i;
    if (node >= N_NODES) break;
    float val = ctile2[wave*16 + i][lane];
    ((unsigned short*)h2pre)[(size_t)node*64 + lane] = f2bu(val);
    float ps = val*as, pd = val*ad;
    #pragma unroll
    for (int off = 32; off; off >>= 1) { ps += __shfl_xor(ps, off, 64); pd += __shfl_xor(pd, off, 64); }
    if (lane == 0) { al2s[node] = ps; al2d[node] = pd; }
  }
}

// ---------------- Attention layer 2 (H=1, no max pass), slim: writes post-ELU h2 (fp32) only ----------------
__global__ __launch_bounds__(512, 8) void attn2_kernel(const bf16* __restrict__ h2pre,
    const float* __restrict__ al2s, const float* __restrict__ al2d,
    const int* __restrict__ offs, const int* __restrict__ srcs,
    const float* __restrict__ b2, float* __restrict__ h2f){
  __shared__ float ebuf[8][MAXD+8];             // p values, +8 zero pad
  __shared__ int   sbuf[8][MAXD+8];
  int wave = threadIdx.x >> 6, lane = threadIdx.x & 63;
  int n = blockIdx.x*8 + wave;        // exact
  int start = offs[n], end = offs[n+1];
  int deg = end - start;
  int lim = deg < MAXD ? deg : MAXD;
  float ald = al2d[n];

  float sm = 0.f;
  {
    int idx = lane;
    for (int j = start + lane; j < end; j += 64, idx += 64) {
      int r = srcs[j];
      float t = al2s[r] + ald; t = t >= 0.f ? t : 0.2f*t;
      float p = __expf(t); sm += p;
      if (idx < MAXD) { sbuf[wave][idx] = r; ebuf[wave][idx] = p; }
    }
  }
  if (lane < 8) { int ip = lim + lane; sbuf[wave][ip] = 0; ebuf[wave][ip] = 0.f; }
  #pragma unroll
  for (int off = 32; off; off >>= 1) sm += __shfl_xor(sm, off, 64);
  float inv = 1.f/(sm + 1e-16f);

  // aggregation: lane -> (edge-slot es=lane>>3, channel-lane cl=lane&7); uint4 = channels cl*8..cl*8+7
  // padded p-buffer: no bounds mask in hot loop
  int cl = lane & 7, es = lane >> 3;
  float acc0 = 0.f, acc1 = 0.f, acc2 = 0.f, acc3 = 0.f;
  float acc4 = 0.f, acc5 = 0.f, acc6 = 0.f, acc7 = 0.f;
  {
    const uint4* base4 = (const uint4*)h2pre;   // row = 8 uint4
    #pragma unroll 2
    for (int jj = 0; jj < lim; jj += 8) {
      int idx = jj + es;                        // <= lim+6 < lim+8 (padded)
      int r = sbuf[wave][idx];
      float p = ebuf[wave][idx];
      uint4 d = base4[(size_t)r*8 + cl];
      acc0 = fmaf(p, bflo(d.x), acc0);
      acc1 = fmaf(p, bfhi(d.x), acc1);
      acc2 = fmaf(p, bflo(d.y), acc2);
      acc3 = fmaf(p, bfhi(d.y), acc3);
      acc4 = fmaf(p, bflo(d.z), acc4);
      acc5 = fmaf(p, bfhi(d.z), acc5);
      acc6 = fmaf(p, bflo(d.w), acc6);
      acc7 = fmaf(p, bfhi(d.w), acc7);
    }
  }
  if (deg > MAXD) {     // rare overflow tail
    const uint4* base4 = (const uint4*)h2pre;
    for (int jj = MAXD; jj < deg; jj += 8) {
      int idx = jj + es;
      bool ok = idx < deg;
      int j = ok ? (start + idx) : start;
      int r = srcs[j];
      float t = al2s[r] + ald; t = t >= 0.f ? t : 0.2f*t;
      float p = ok ? __expf(t) : 0.f;
      uint4 d = base4[(size_t)r*8 + cl];
      acc0 = fmaf(p, bflo(d.x), acc0);
      acc1 = fmaf(p, bfhi(d.x), acc1);
      acc2 = fmaf(p, bflo(d.y), acc2);
      acc3 = fmaf(p, bfhi(d.y), acc3);
      acc4 = fmaf(p, bflo(d.z), acc4);
      acc5 = fmaf(p, bfhi(d.z), acc5);
      acc6 = fmaf(p, bflo(d.w), acc6);
      acc7 = fmaf(p, bfhi(d.w), acc7);
    }
  }
  // fold the 8 edge-slots (xor butterfly over lane bits 3,4,5)
  #pragma unroll
  for (int off = 8; off < 64; off <<= 1) {
    acc0 += __shfl_xor(acc0, off, 64);
    acc1 += __shfl_xor(acc1, off, 64);
    acc2 += __shfl_xor(acc2, off, 64);
    acc3 += __shfl_xor(acc3, off, 64);
    acc4 += __shfl_xor(acc4, off, 64);
    acc5 += __shfl_xor(acc5, off, 64);
    acc6 += __shfl_xor(acc6, off, 64);
    acc7 += __shfl_xor(acc7, off, 64);
  }

  if (es == 0) {
    float4 b2a = *(const float4*)(b2 + cl*8);
    float4 b2b = *(const float4*)(b2 + cl*8 + 4);
    float o0 = acc0*inv + b2a.x; o0 = o0 > 0.f ? o0 : expm1f(o0);
    float o1 = acc1*inv + b2a.y; o1 = o1 > 0.f ? o1 : expm1f(o1);
    float o2 = acc2*inv + b2a.z; o2 = o2 > 0.f ? o2 : expm1f(o2);
    float o3 = acc3*inv + b2a.w; o3 = o3 > 0.f ? o3 : expm1f(o3);
    float o4 = acc4*inv + b2b.x; o4 = o4 > 0.f ? o4 : expm1f(o4);
    float o5 = acc5*inv + b2b.y; o5 = o5 > 0.f ? o5 : expm1f(o5);
    float o6 = acc6*inv + b2b.z; o6 = o6 > 0.f ? o6 : expm1f(o6);
    float o7 = acc7*inv + b2b.w; o7 = o7 > 0.f ? o7 : expm1f(o7);
    *(float4*)(h2f + (size_t)n*64 + cl*8)     = make_float4(o0, o1, o2, o3);
    *(float4*)(h2f + (size_t)n*64 + cl*8 + 4) = make_float4(o4, o5, o6, o7);
  }
}

// ---------------- Node head: node_out = h2 @ Wn + bn; u = h2.We[0:64]; v = h2.We[64:128] ----------------
__global__ __launch_bounds__(256) void head_kernel(const float* __restrict__ h2f,
    const float* __restrict__ Wn, const float* __restrict__ bn, const float* __restrict__ We,
    float* __restrict__ u, float* __restrict__ v, float* __restrict__ node_out){
  __shared__ __align__(16) float sh[8][64];
  int tid = threadIdx.x;
  int nb = blockIdx.x*8;              // 50000/8 = 6250 exact
  {
    float2 t = *(const float2*)(h2f + (size_t)nb*64 + tid*2);
    *(float2*)&sh[tid >> 5][(tid & 31)*2] = t;
  }
  __syncthreads();
  int wave = tid >> 6, lane = tid & 63;
  int sub = lane >> 5, j = lane & 31;
  int local = wave*2 + sub;           // 0..7
  int n = nb + local;
  const float* h = sh[local];
  // node_out = h . Wn[:,j]
  float a = 0.f;
  #pragma unroll 16
  for (int k = 0; k < 64; ++k)
    a = fmaf(h[k], Wn[k*32 + j], a);
  node_out[(size_t)n*32 + j] = a + bn[j];
  // u,v partials over k = j, j+32; butterfly within the 32-lane group
  float pu = h[j]*We[j] + h[j+32]*We[j+32];
  float pv = h[j]*We[64+j] + h[j+32]*We[96+j];
  #pragma unroll
  for (int off = 1; off < 32; off <<= 1) {
    pu += __shfl_xor(pu, off, 64);
    pv += __shfl_xor(pv, off, 64);
  }
  if (j == 0) { u[n] = pu; v[n] = pv; }
}

// ---------------- Edge head: out = u[row] + v[col] + edge_attr . We[128:144] + be ----------------
__global__ __launch_bounds__(256) void edge_kernel(const int* __restrict__ ei, const float* __restrict__ ea,
    const float* __restrict__ u, const float* __restrict__ v,
    const float* __restrict__ We, const float* __restrict__ be, float* __restrict__ out){
  int k = blockIdx.x*256 + threadIdx.x;   // grid is exact: 800000/256
  int r = ei[k], c = ei[N_EDGES + k];
  float val = u[r] + v[c] + be[0];
  const float4* wp = (const float4*)(We + 128);
  const float4* p  = (const float4*)(ea + (size_t)k*16);
  #pragma unroll
  for (int jj = 0; jj < 4; jj++) {
    float4 q = p[jj], wq = wp[jj];
    val = fmaf(q.x, wq.x, val);
    val = fmaf(q.y, wq.y, val);
    val = fmaf(q.z, wq.z, val);
    val = fmaf(q.w, wq.w, val);
  }
  out[k] = val;
}

extern "C" void kernel_launch(void* const* d_in, const int* in_sizes, int n_in,
                              void* d_out, int out_size, void* d_ws, size_t ws_size,
                              hipStream_t stream) {
  const float* x   = (const float*)d_in[0];
  const int*   ei  = (const int*)d_in[1];
  const float* ea  = (const float*)d_in[2];
  const float* W1  = (const float*)d_in[3];
  const float* a1s = (const float*)d_in[4];
  const float* a1d = (const float*)d_in[5];
  const float* b1  = (const float*)d_in[6];
  const float* W2  = (const float*)d_in[7];
  const float* a2s = (const float*)d_in[8];
  const float* a2d = (const float*)d_in[9];
  const float* b2  = (const float*)d_in[10];
  const float* Wn  = (const float*)d_in[11];
  const float* bn  = (const float*)d_in[12];
  const float* We  = (const float*)d_in[13];
  const float* be  = (const float*)d_in[14];
  float* out = (float*)d_out;

  // ---- workspace layout, peak 64,000,224 B, 16B-aligned ----
  char* w = (char*)d_ws;
  int*   offs   = (int*)(w);                        //       0 .. 200,016
  unsigned short* wf1 = (unsigned short*)(w + 200016); // 32,768 B
  float* ws1    = (float*)(w + 232784);             // 1,024 B
  float* wd1    = (float*)(w + 233808);             // 1,024 B
  unsigned short* wf2 = (unsigned short*)(w + 234832); // 32,768 B (.. 267,600)
  int*   bcur   = (int*)(w + 400016);               // 784 B bucket counts
  int*   srcs   = (int*)(w + 600016);               // 600,016 .. 4,000,016
  float* al1s   = (float*)(w + 4000016);            // [N,4] fp32, .. 4,800,016
  float* al1d   = (float*)(w + 4800016);            // [N,4] fp32, .. 5,600,016
  float* al2s   = (float*)(w + 5600016);            // [N] fp32,  .. 5,800,016
  float* al2d   = (float*)(w + 5800016);            // .. 6,000,016
  float* uu     = (float*)(w + 6000016);            // .. 6,200,016
  float* vv     = (float*)(w + 6200016);            // .. 6,400,016
  bf16*  h2pre  = (bf16*)(w + 6400016);             // [N,64] bf16, .. 12,800,016 (xb aliases BEFORE gemm12)
  bf16*  ag     = (bf16*)(w + 12800016);            // [N,256] bf16 aggregate, .. 38,400,016
  unsigned int* pairbuf = (unsigned int*)(w + 38400224); // 6.8 MB bucket regions (old h1 region; h1 eliminated by gemm12 fusion)
  unsigned short* xb  = (unsigned short*)h2pre;     // [N,64] bf16 x-table; dead before gemm12 writes h2pre
  float* h2f = (float*)ag;                          // [N,64] fp32 post-ELU h2 (ag dead after gemm12)

  wfrag_kernel     <<<130, 256, 0, stream>>>(W1, W2, a1s, a1d, wf1, wf2, ws1, wd1, bcur);
  binscatter_kernel<<<(N_TOT + 4095)/4096, 256, 0, stream>>>(ei, bcur, pairbuf);
  lscatter2_kernel <<<NBUCK, 256, 0, stream>>>(pairbuf, bcur, offs, srcs);
  xprep_kernel     <<<N_NODES/16, 256, 0, stream>>>(x, ws1, wd1, xb, al1s, al1d);
  attn1x_kernel    <<<N_NODES/4, 256, 0, stream>>>(xb, al1s, al1d, offs, srcs, ag);
  gemm12_kernel    <<<(N_NODES + 63)/64, 256, 0, stream>>>((const unsigned short*)ag, wf1, wf2, b1,
                                                           a2s, a2d, h2pre, al2s, al2d);
  attn2_kernel     <<<N_NODES/8, 512, 0, stream>>>(h2pre, al2s, al2d, offs, srcs, b2, h2f);
  head_kernel      <<<N_NODES/8, 256, 0, stream>>>(h2f, Wn, bn, We, uu, vv, out);
  edge_kernel      <<<N_EDGES/256, 256, 0, stream>>>(ei, ea, uu, vv, We, be, out + (size_t)N_NODES*32);
}

// Round 12
// 287.555 us; speedup vs baseline: 1.1770x; 1.0492x over previous
//
#include <hip/hip_runtime.h>
#include <hip/hip_bf16.h>

#define N_NODES 50000
#define N_EDGES 800000
#define N_TOT   850000   // edges + self loops
#define MAXD    128      // LDS-staged edges per node; tail handled by fallback

// bucketed CSR build: bucket = dst >> 8 (256 nodes/bucket)
#define NBUCK 196        // ceil(50000/256)
#define BCAP  8192       // fixed bucket capacity (mean 4337, std ~66 -> 58 sigma slack)

typedef __hip_bfloat16 bf16;
typedef __attribute__((ext_vector_type(8))) short bf16x8;   // MFMA A/B frag (4 VGPRs)
typedef __attribute__((ext_vector_type(4))) float f32x4;    // MFMA C/D frag

__device__ __forceinline__ unsigned short f2bu(float v){
  union { bf16 b; unsigned short u; } cv; cv.b = __float2bfloat16(v); return cv.u;
}
__device__ __forceinline__ float bflo(unsigned int d){ return __uint_as_float(d << 16); }
__device__ __forceinline__ float bfhi(unsigned int d){ return __uint_as_float(d & 0xffff0000u); }

// ---------------- prep1: W-frag/attn-vector prep (blocks 0..128) || binscatter (blocks 129..336) ----
// The two halves are mutually independent (bcur zeroed by hipMemsetAsync before this kernel);
// co-launching deletes one dispatch gap and overlaps their execution [R12].
__global__ __launch_bounds__(256) void prep1_kernel(const float* __restrict__ W1, const float* __restrict__ W2,
    const float* __restrict__ a1s, const float* __restrict__ a1d,
    unsigned short* __restrict__ wf1, unsigned short* __restrict__ wf2,
    float* __restrict__ ws1, float* __restrict__ wd1,
    const int* __restrict__ ei, int* __restrict__ bcur, unsigned int* __restrict__ pairbuf){
  __shared__ int hist[NBUCK];
  __shared__ int gbase[NBUCK];
  int b = blockIdx.x, tid = threadIdx.x;
  if (b < 128) {
    int i = b*256 + tid;   // 32768 threads exact
    if (i < 16384) {
      int k = i >> 8, n = i & 255;
      int kk = k >> 5, qq = (k >> 3) & 3, j = k & 7, nt = n >> 4, cc = n & 15;
      wf1[(((kk*16 + nt)*4 + qq)*16 + cc)*8 + j] = f2bu(W1[i]);
    } else {
      int i2 = i - 16384;
      int k = i2 >> 6, n = i2 & 63;
      int kk = k >> 5, qq = (k >> 3) & 3, j = k & 7, ch = n >> 4, cc = n & 15;
      wf2[(((kk*4 + ch)*4 + qq)*16 + cc)*8 + j] = f2bu(W2[i2]);
    }
  } else if (b == 128) {
    // ws1[k][h] = sum_c W1[k, h*64+c] * a1s[h, c]   (64x4 each)
    int k = tid >> 2, h = tid & 3;
    const float* wrow = W1 + k*256 + h*64;
    const float* as = a1s + h*64;
    const float* ad = a1d + h*64;
    float ss = 0.f, sd = 0.f;
    #pragma unroll 8
    for (int c = 0; c < 64; ++c) {
      float wv = wrow[c];
      ss = fmaf(wv, as[c], ss);
      sd = fmaf(wv, ad[c], sd);
    }
    ws1[k*4 + h] = ss;
    wd1[k*4 + h] = sd;
  } else {
    // ---- binscatter: bin 4096 edges into 196 bucket regions ----
    int bb = b - 129;
    if (tid < NBUCK) hist[tid] = 0;
    __syncthreads();
    int base = bb * 4096;
    #pragma unroll 4
    for (int i = 0; i < 16; ++i) {
      int k = base + i*256 + tid;
      if (k < N_TOT) {
        int c = (k < N_EDGES) ? ei[N_EDGES + k] : (k - N_EDGES);
        atomicAdd(&hist[c >> 8], 1);
      }
    }
    __syncthreads();
    if (tid < NBUCK) {
      int h = hist[tid];
      gbase[tid] = h ? (tid*BCAP + atomicAdd(&bcur[tid], h)) : 0;
      hist[tid] = 0;                       // reuse as local cursor
    }
    __syncthreads();
    #pragma unroll 4
    for (int i = 0; i < 16; ++i) {
      int k = base + i*256 + tid;
      if (k < N_TOT) {
        int r, c;
        if (k < N_EDGES) { r = ei[k]; c = ei[N_EDGES + k]; } else { r = c = k - N_EDGES; }
        int bk = c >> 8;
        int lpos = atomicAdd(&hist[bk], 1);
        pairbuf[gbase[bk] + lpos] = (unsigned)r | ((unsigned)(c & 255) << 16);
      }
    }
  }
}

// ---------------- prep2: lscatter2 (blocks 0..195) || xprep (blocks 196..3320) ----
// lscatter2 depends only on prep1's binscatter half; xprep only on prep1's wfrag half ->
// mutually independent, co-launched [R12].
__global__ __launch_bounds__(256) void prep2_kernel(const unsigned int* __restrict__ pairbuf,
    const int* __restrict__ bcur, int* __restrict__ offs, int* __restrict__ srcs,
    const float* __restrict__ x, const float* __restrict__ ws1, const float* __restrict__ wd1,
    unsigned short* __restrict__ xb, float* __restrict__ al1s, float* __restrict__ al1d){
  __shared__ int sbase[256];       // lscatter2 half
  __shared__ int lhist[256];
  __shared__ int lcur[256];
  __shared__ float sws[64][4], swd[64][4];   // xprep half
  int tid = threadIdx.x;
  if (blockIdx.x < NBUCK) {
    int b = blockIdx.x;
    // redundant 196-bucket scan (cheap; removes separate scan dispatch)
    int sz = 0;
    if (tid < NBUCK) {
      sz = bcur[tid];
      if (sz < 0) sz = 0; if (sz > BCAP) sz = BCAP;
    }
    sbase[tid] = sz;
    lhist[tid] = 0;
    __syncthreads();
    for (int off = 1; off < 256; off <<= 1) {
      int t = (tid >= off) ? sbase[tid - off] : 0;
      __syncthreads();
      sbase[tid] += t;
      __syncthreads();
    }
    int bbase_b = (b == 0) ? 0 : sbase[b - 1];
    int size = sbase[b] - bbase_b;                 // min(bcur[b], BCAP)
    int base = b * BCAP;
    // per-node counts within bucket
    for (int j = tid; j < size; j += 256)
      atomicAdd(&lhist[pairbuf[base + j] >> 16], 1);
    __syncthreads();
    int v = lhist[tid];
    lcur[tid] = v;
    __syncthreads();
    for (int off = 1; off < 256; off <<= 1) {
      int t = (tid >= off) ? lcur[tid - off] : 0;
      __syncthreads();
      lcur[tid] += t;
      __syncthreads();
    }
    int excl = lcur[tid] - v;
    int gpos = bbase_b + excl;
    int node = b*256 + tid;
    if (node < N_NODES) offs[node] = gpos;
    if (b == 0 && tid == 0) offs[N_NODES] = N_TOT;
    __syncthreads();
    lcur[tid] = gpos;       // per-node cursor
    __syncthreads();
    for (int j = tid; j < size; j += 256) {
      unsigned pv = pairbuf[base + j];
      int pos = atomicAdd(&lcur[pv >> 16], 1);
      srcs[pos] = (int)(pv & 0xFFFFu);
    }
  } else {
    // ---- xprep: xb = bf16(x); al1{s,d} = x @ w{s,d}1 ----
    sws[tid >> 2][tid & 3] = ws1[tid];
    swd[tid >> 2][tid & 3] = wd1[tid];
    __syncthreads();
    int lane = tid & 63, wave = tid >> 6;
    int g = lane & 15, sub = lane >> 4;
    int n = (blockIdx.x - NBUCK)*16 + wave*4 + sub;   // 50000/16 = 3125 exact
    float4 xv = *(const float4*)(x + (size_t)n*64 + g*4);
    uint2 dd;
    dd.x = (unsigned)f2bu(xv.x) | ((unsigned)f2bu(xv.y) << 16);
    dd.y = (unsigned)f2bu(xv.z) | ((unsigned)f2bu(xv.w) << 16);
    ((uint2*)xb)[(size_t)n*16 + g] = dd;
    int c0 = g*4;
    float ps0 = 0.f, ps1 = 0.f, ps2 = 0.f, ps3 = 0.f;
    float pd0 = 0.f, pd1 = 0.f, pd2 = 0.f, pd3 = 0.f;
    float xc[4] = {xv.x, xv.y, xv.z, xv.w};
    #pragma unroll
    for (int i = 0; i < 4; ++i) {
      int c = c0 + i;
      ps0 = fmaf(xc[i], sws[c][0], ps0); ps1 = fmaf(xc[i], sws[c][1], ps1);
      ps2 = fmaf(xc[i], sws[c][2], ps2); ps3 = fmaf(xc[i], sws[c][3], ps3);
      pd0 = fmaf(xc[i], swd[c][0], pd0); pd1 = fmaf(xc[i], swd[c][1], pd1);
      pd2 = fmaf(xc[i], swd[c][2], pd2); pd3 = fmaf(xc[i], swd[c][3], pd3);
    }
    #pragma unroll
    for (int off = 1; off < 16; off <<= 1) {
      ps0 += __shfl_xor(ps0, off, 64); ps1 += __shfl_xor(ps1, off, 64);
      ps2 += __shfl_xor(ps2, off, 64); ps3 += __shfl_xor(ps3, off, 64);
      pd0 += __shfl_xor(pd0, off, 64); pd1 += __shfl_xor(pd1, off, 64);
      pd2 += __shfl_xor(pd2, off, 64); pd3 += __shfl_xor(pd3, off, 64);
    }
    if (g < 4)      al1s[(size_t)n*4 + g]       = (g==0)?ps0:(g==1)?ps1:(g==2)?ps2:ps3;
    else if (g < 8) al1d[(size_t)n*4 + (g-4)]   = (g==4)?pd0:(g==5)?pd1:(g==6)?pd2:pd3;
  }
}

// ------- Attention layer 1 in x-space: ag[n,h,:64] = sum_j alpha_{j,h} * xb[r_j]
// zero-padded p-buffer (no bounds mask) + unroll 2 (VGPR ~28 -> 65% occupancy [R7])
__global__ __launch_bounds__(256, 8) void attn1x_kernel(const unsigned short* __restrict__ xb,
    const float* __restrict__ al1s, const float* __restrict__ al1d,
    const int* __restrict__ offs, const int* __restrict__ srcs,
    bf16* __restrict__ ag){
  __shared__ __align__(16) float ebuf[4][MAXD+4][4];     // p values, +4 zero pad
  __shared__ int sbuf[4][MAXD+4];

  int wave = threadIdx.x >> 6, lane = threadIdx.x & 63;
  int n = blockIdx.x*4 + wave;          // 50000 % 4 == 0: no tail
  int start = offs[n], end = offs[n+1];
  int deg = end - start;
  int lim = deg < MAXD ? deg : MAXD;
  float4 aldv = *(const float4*)(al1d + (size_t)n*4);
  float ald0 = aldv.x, ald1 = aldv.y, ald2 = aldv.z, ald3 = aldv.w;

  // stage pass: gather als, e=lrelu, p=exp(e); stage p+src; lane sums
  float s0 = 0.f, s1 = 0.f, s2 = 0.f, s3 = 0.f;
  {
    int idx = lane;
    for (int j = start + lane; j < end; j += 64, idx += 64) {
      int r = srcs[j];
      float4 als = *(const float4*)(al1s + (size_t)r*4);
      float e0 = als.x + ald0; e0 = e0 >= 0.f ? e0 : 0.2f*e0; float p0 = __expf(e0); s0 += p0;
      float e1 = als.y + ald1; e1 = e1 >= 0.f ? e1 : 0.2f*e1; float p1 = __expf(e1); s1 += p1;
      float e2 = als.z + ald2; e2 = e2 >= 0.f ? e2 : 0.2f*e2; float p2 = __expf(e2); s2 += p2;
      float e3 = als.w + ald3; e3 = e3 >= 0.f ? e3 : 0.2f*e3; float p3 = __expf(e3); s3 += p3;
      if (idx < MAXD) {
        sbuf[wave][idx] = r;
        *(float4*)&ebuf[wave][idx][0] = make_float4(p0, p1, p2, p3);
      }
    }
  }
  // zero-pad 4 slots past lim: aggregation loop then needs no bounds mask
  if (lane < 4) {
    int ip = lim + lane;
    sbuf[wave][ip] = 0;
    *(float4*)&ebuf[wave][ip][0] = make_float4(0.f, 0.f, 0.f, 0.f);
  }
  #pragma unroll
  for (int off = 32; off; off >>= 1) {
    s0 += __shfl_xor(s0, off, 64);
    s1 += __shfl_xor(s1, off, 64);
    s2 += __shfl_xor(s2, off, 64);
    s3 += __shfl_xor(s3, off, 64);
  }
  float inv0 = 1.f/(s0 + 1e-16f), inv1 = 1.f/(s1 + 1e-16f);
  float inv2 = 1.f/(s2 + 1e-16f), inv3 = 1.f/(s3 + 1e-16f);

  // aggregation: lane -> (edge-slot es=lane>>4 of 4, ch-lane cl=lane&15: ch cl*4..cl*4+3)
  int cl = lane & 15, es = lane >> 4;
  float acc[4][4];
  #pragma unroll
  for (int h = 0; h < 4; ++h)
    #pragma unroll
    for (int i = 0; i < 4; ++i) acc[h][i] = 0.f;
  {
    const uint2* base2 = (const uint2*)xb;   // row = 16 uint2 (128B)
    #pragma unroll 2
    for (int jj = 0; jj < lim; jj += 4) {
      int idx = jj + es;                     // <= lim+2 < lim+4 (padded)
      int r = sbuf[wave][idx];
      float4 pv = *(const float4*)&ebuf[wave][idx][0];
      uint2 d = base2[(size_t)r*16 + cl];
      float c0 = bflo(d.x), c1 = bfhi(d.x), c2 = bflo(d.y), c3 = bfhi(d.y);
      acc[0][0] = fmaf(pv.x, c0, acc[0][0]); acc[0][1] = fmaf(pv.x, c1, acc[0][1]);
      acc[0][2] = fmaf(pv.x, c2, acc[0][2]); acc[0][3] = fmaf(pv.x, c3, acc[0][3]);
      acc[1][0] = fmaf(pv.y, c0, acc[1][0]); acc[1][1] = fmaf(pv.y, c1, acc[1][1]);
      acc[1][2] = fmaf(pv.y, c2, acc[1][2]); acc[1][3] = fmaf(pv.y, c3, acc[1][3]);
      acc[2][0] = fmaf(pv.z, c0, acc[2][0]); acc[2][1] = fmaf(pv.z, c1, acc[2][1]);
      acc[2][2] = fmaf(pv.z, c2, acc[2][2]); acc[2][3] = fmaf(pv.z, c3, acc[2][3]);
      acc[3][0] = fmaf(pv.w, c0, acc[3][0]); acc[3][1] = fmaf(pv.w, c1, acc[3][1]);
      acc[3][2] = fmaf(pv.w, c2, acc[3][2]); acc[3][3] = fmaf(pv.w, c3, acc[3][3]);
    }
  }
  if (deg > MAXD) {       // rare overflow tail: recompute p per lane (masked scalar path)
    const uint2* base2 = (const uint2*)xb;
    for (int jj = MAXD; jj < deg; jj += 4) {
      int idx = jj + es;
      bool ok = idx < deg;
      int j = ok ? (start + idx) : start;
      int r = srcs[j];
      float4 als = *(const float4*)(al1s + (size_t)r*4);
      float e0 = als.x + ald0; e0 = e0 >= 0.f ? e0 : 0.2f*e0; float p0 = __expf(e0);
      float e1 = als.y + ald1; e1 = e1 >= 0.f ? e1 : 0.2f*e1; float p1 = __expf(e1);
      float e2 = als.z + ald2; e2 = e2 >= 0.f ? e2 : 0.2f*e2; float p2 = __expf(e2);
      float e3 = als.w + ald3; e3 = e3 >= 0.f ? e3 : 0.2f*e3; float p3 = __expf(e3);
      float m = ok ? 1.f : 0.f;
      uint2 d = base2[(size_t)r*16 + cl];
      float c0 = bflo(d.x)*m, c1 = bfhi(d.x)*m, c2 = bflo(d.y)*m, c3 = bfhi(d.y)*m;
      acc[0][0] = fmaf(p0, c0, acc[0][0]); acc[0][1] = fmaf(p0, c1, acc[0][1]);
      acc[0][2] = fmaf(p0, c2, acc[0][2]); acc[0][3] = fmaf(p0, c3, acc[0][3]);
      acc[1][0] = fmaf(p1, c0, acc[1][0]); acc[1][1] = fmaf(p1, c1, acc[1][1]);
      acc[1][2] = fmaf(p1, c2, acc[1][2]); acc[1][3] = fmaf(p1, c3, acc[1][3]);
      acc[2][0] = fmaf(p2, c0, acc[2][0]); acc[2][1] = fmaf(p2, c1, acc[2][1]);
      acc[2][2] = fmaf(p2, c2, acc[2][2]); acc[2][3] = fmaf(p2, c3, acc[2][3]);
      acc[3][0] = fmaf(p3, c0, acc[3][0]); acc[3][1] = fmaf(p3, c1, acc[3][1]);
      acc[3][2] = fmaf(p3, c2, acc[3][2]); acc[3][3] = fmaf(p3, c3, acc[3][3]);
    }
  }
  // fold the 4 edge slots (lane bits 4,5)
  #pragma unroll
  for (int h = 0; h < 4; ++h)
    #pragma unroll
    for (int i = 0; i < 4; ++i) {
      acc[h][i] += __shfl_xor(acc[h][i], 16, 64);
      acc[h][i] += __shfl_xor(acc[h][i], 32, 64);
    }
  // lane l writes head h=es, channels cl*4..cl*4+3: ag[n][es*64 + cl*4 ...] (coalesced 512B/row)
  {
    float invh = (es==0)?inv0:(es==1)?inv1:(es==2)?inv2:inv3;
    float o0 = ((es==0)?acc[0][0]:(es==1)?acc[1][0]:(es==2)?acc[2][0]:acc[3][0]) * invh;
    float o1 = ((es==0)?acc[0][1]:(es==1)?acc[1][1]:(es==2)?acc[2][1]:acc[3][1]) * invh;
    float o2 = ((es==0)?acc[0][2]:(es==1)?acc[1][2]:(es==2)?acc[2][2]:acc[3][2]) * invh;
    float o3 = ((es==0)?acc[0][3]:(es==1)?acc[1][3]:(es==2)?acc[2][3]:acc[3][3]) * invh;
    uint2 dd;
    dd.x = (unsigned)f2bu(o0) | ((unsigned)f2bu(o1) << 16);
    dd.y = (unsigned)f2bu(o2) | ((unsigned)f2bu(o3) << 16);
    ((uint2*)ag)[(size_t)n*64 + lane] = dd;
  }
}

// ---------------- Fused GEMM1b+GEMM2 (MFMA): per 64-node tile,
// phase 1: h1_tile = elu(ag @ W1 + b1) -> LDS bf16; phase 2: h2pre = h1_tile @ W2, fused al2.
__global__ __launch_bounds__(256) void gemm12_kernel(const unsigned short* __restrict__ ag,
    const unsigned short* __restrict__ wf1, const unsigned short* __restrict__ wf2,
    const float* __restrict__ b1, const float* __restrict__ a2s, const float* __restrict__ a2d,
    bf16* __restrict__ h2pre, float* __restrict__ al2s, float* __restrict__ al2d){
  __shared__ __align__(16) unsigned short ctile[64*264];      // h1 tile bf16, 33.8KB (264 = 256+8 pad)
  __shared__ __align__(16) float ctile2[64][65];              // h2 f32 transpose buffer, 16.6KB
  int tid = threadIdx.x, wave = tid >> 6, lane = tid & 63;
  int q = lane >> 4, c = lane & 15;
  int n0 = blockIdx.x * 64;

  // ---- phase 1: gemm1b (block-diagonal W1), output to LDS only ----
  {
    union { uint4 u; bf16x8 v; } bfr[2][4];
    #pragma unroll
    for (int kk = 0; kk < 2; ++kk)
      #pragma unroll
      for (int nti = 0; nti < 4; ++nti)
        bfr[kk][nti].u = *(const uint4*)(wf1 + (size_t)((((kk*16 + wave*4 + nti)*4 + q)*16 + c)*8));

    float b1v[4];
    #pragma unroll
    for (int nti = 0; nti < 4; ++nti) b1v[nti] = b1[(wave*4 + nti)*16 + c];

    #pragma unroll 1
    for (int st = 0; st < 4; ++st) {
      int row = n0 + st*16 + c;
      if (row >= N_NODES) row = N_NODES - 1;   // tail clamp; phase-2 stores guarded below
      bf16x8 afr[2];
      #pragma unroll
      for (int kk = 0; kk < 2; ++kk) {
        union { uint4 u; bf16x8 v; } a;
        a.u = *(const uint4*)(ag + (size_t)row*256 + wave*64 + kk*32 + q*8);
        afr[kk] = a.v;
      }
      #pragma unroll
      for (int nti = 0; nti < 4; ++nti) {
        f32x4 acc = {0.f, 0.f, 0.f, 0.f};
        #pragma unroll
        for (int kk = 0; kk < 2; ++kk)
          acc = __builtin_amdgcn_mfma_f32_16x16x32_bf16(afr[kk], bfr[kk][nti].v, acc, 0, 0, 0);
        int lrow = st*16 + q*4, nt = wave*4 + nti;
        #pragma unroll
        for (int r = 0; r < 4; ++r) {
          float o = acc[r] + b1v[nti];
          o = o > 0.f ? o : expm1f(o);
          ctile[(lrow + r)*264 + nt*16 + c] = f2bu(o);
        }
      }
    }
  }
  __syncthreads();

  // ---- phase 2: gemm2 (h1_tile @ W2), A-frags from LDS ----
  {
    union { uint4 u; bf16x8 v; } bfr[8];
    #pragma unroll
    for (int kk = 0; kk < 8; ++kk)
      bfr[kk].u = *(const uint4*)(wf2 + (size_t)((((kk*4 + wave)*4 + q)*16 + c)*8));

    #pragma unroll 1
    for (int st = 0; st < 4; ++st) {
      if (n0 + st*16 >= N_NODES) break;       // block-uniform
      f32x4 acc = {0.f, 0.f, 0.f, 0.f};
      int arow = (st*16 + c)*264 + q*8;
      #pragma unroll
      for (int kk = 0; kk < 8; ++kk) {
        union { uint4 u; bf16x8 v; } a;
        a.u = *(const uint4*)&ctile[arow + kk*32];
        acc = __builtin_amdgcn_mfma_f32_16x16x32_bf16(a.v, bfr[kk].v, acc, 0, 0, 0);
      }
      #pragma unroll
      for (int r = 0; r < 4; ++r)
        ctile2[st*16 + q*4 + r][wave*16 + c] = acc[r];
    }
  }
  __syncthreads();

  float as = a2s[lane], ad = a2d[lane];
  #pragma unroll 1
  for (int i = 0; i < 16; ++i) {
    int node = n0 + wave*16 + i;
    if (node >= N_NODES) break;
    float val = ctile2[wave*16 + i][lane];
    ((unsigned short*)h2pre)[(size_t)node*64 + lane] = f2bu(val);
    float ps = val*as, pd = val*ad;
    #pragma unroll
    for (int off = 32; off; off >>= 1) { ps += __shfl_xor(ps, off, 64); pd += __shfl_xor(pd, off, 64); }
    if (lane == 0) { al2s[node] = ps; al2d[node] = pd; }
  }
}

// ---------------- Attention layer 2 (H=1, no max pass), slim: writes post-ELU h2 (fp32) only ----------------
__global__ __launch_bounds__(512, 8) void attn2_kernel(const bf16* __restrict__ h2pre,
    const float* __restrict__ al2s, const float* __restrict__ al2d,
    const int* __restrict__ offs, const int* __restrict__ srcs,
    const float* __restrict__ b2, float* __restrict__ h2f){
  __shared__ float ebuf[8][MAXD+8];             // p values, +8 zero pad
  __shared__ int   sbuf[8][MAXD+8];
  int wave = threadIdx.x >> 6, lane = threadIdx.x & 63;
  int n = blockIdx.x*8 + wave;        // exact
  int start = offs[n], end = offs[n+1];
  int deg = end - start;
  int lim = deg < MAXD ? deg : MAXD;
  float ald = al2d[n];

  float sm = 0.f;
  {
    int idx = lane;
    for (int j = start + lane; j < end; j += 64, idx += 64) {
      int r = srcs[j];
      float t = al2s[r] + ald; t = t >= 0.f ? t : 0.2f*t;
      float p = __expf(t); sm += p;
      if (idx < MAXD) { sbuf[wave][idx] = r; ebuf[wave][idx] = p; }
    }
  }
  if (lane < 8) { int ip = lim + lane; sbuf[wave][ip] = 0; ebuf[wave][ip] = 0.f; }
  #pragma unroll
  for (int off = 32; off; off >>= 1) sm += __shfl_xor(sm, off, 64);
  float inv = 1.f/(sm + 1e-16f);

  // aggregation: lane -> (edge-slot es=lane>>3, channel-lane cl=lane&7); uint4 = channels cl*8..cl*8+7
  // padded p-buffer: no bounds mask in hot loop
  int cl = lane & 7, es = lane >> 3;
  float acc0 = 0.f, acc1 = 0.f, acc2 = 0.f, acc3 = 0.f;
  float acc4 = 0.f, acc5 = 0.f, acc6 = 0.f, acc7 = 0.f;
  {
    const uint4* base4 = (const uint4*)h2pre;   // row = 8 uint4
    #pragma unroll 2
    for (int jj = 0; jj < lim; jj += 8) {
      int idx = jj + es;                        // <= lim+6 < lim+8 (padded)
      int r = sbuf[wave][idx];
      float p = ebuf[wave][idx];
      uint4 d = base4[(size_t)r*8 + cl];
      acc0 = fmaf(p, bflo(d.x), acc0);
      acc1 = fmaf(p, bfhi(d.x), acc1);
      acc2 = fmaf(p, bflo(d.y), acc2);
      acc3 = fmaf(p, bfhi(d.y), acc3);
      acc4 = fmaf(p, bflo(d.z), acc4);
      acc5 = fmaf(p, bfhi(d.z), acc5);
      acc6 = fmaf(p, bflo(d.w), acc6);
      acc7 = fmaf(p, bfhi(d.w), acc7);
    }
  }
  if (deg > MAXD) {     // rare overflow tail
    const uint4* base4 = (const uint4*)h2pre;
    for (int jj = MAXD; jj < deg; jj += 8) {
      int idx = jj + es;
      bool ok = idx < deg;
      int j = ok ? (start + idx) : start;
      int r = srcs[j];
      float t = al2s[r] + ald; t = t >= 0.f ? t : 0.2f*t;
      float p = ok ? __expf(t) : 0.f;
      uint4 d = base4[(size_t)r*8 + cl];
      acc0 = fmaf(p, bflo(d.x), acc0);
      acc1 = fmaf(p, bfhi(d.x), acc1);
      acc2 = fmaf(p, bflo(d.y), acc2);
      acc3 = fmaf(p, bfhi(d.y), acc3);
      acc4 = fmaf(p, bflo(d.z), acc4);
      acc5 = fmaf(p, bfhi(d.z), acc5);
      acc6 = fmaf(p, bflo(d.w), acc6);
      acc7 = fmaf(p, bfhi(d.w), acc7);
    }
  }
  // fold the 8 edge-slots (xor butterfly over lane bits 3,4,5)
  #pragma unroll
  for (int off = 8; off < 64; off <<= 1) {
    acc0 += __shfl_xor(acc0, off, 64);
    acc1 += __shfl_xor(acc1, off, 64);
    acc2 += __shfl_xor(acc2, off, 64);
    acc3 += __shfl_xor(acc3, off, 64);
    acc4 += __shfl_xor(acc4, off, 64);
    acc5 += __shfl_xor(acc5, off, 64);
    acc6 += __shfl_xor(acc6, off, 64);
    acc7 += __shfl_xor(acc7, off, 64);
  }

  if (es == 0) {
    float4 b2a = *(const float4*)(b2 + cl*8);
    float4 b2b = *(const float4*)(b2 + cl*8 + 4);
    float o0 = acc0*inv + b2a.x; o0 = o0 > 0.f ? o0 : expm1f(o0);
    float o1 = acc1*inv + b2a.y; o1 = o1 > 0.f ? o1 : expm1f(o1);
    float o2 = acc2*inv + b2a.z; o2 = o2 > 0.f ? o2 : expm1f(o2);
    float o3 = acc3*inv + b2a.w; o3 = o3 > 0.f ? o3 : expm1f(o3);
    float o4 = acc4*inv + b2b.x; o4 = o4 > 0.f ? o4 : expm1f(o4);
    float o5 = acc5*inv + b2b.y; o5 = o5 > 0.f ? o5 : expm1f(o5);
    float o6 = acc6*inv + b2b.z; o6 = o6 > 0.f ? o6 : expm1f(o6);
    float o7 = acc7*inv + b2b.w; o7 = o7 > 0.f ? o7 : expm1f(o7);
    *(float4*)(h2f + (size_t)n*64 + cl*8)     = make_float4(o0, o1, o2, o3);
    *(float4*)(h2f + (size_t)n*64 + cl*8 + 4) = make_float4(o4, o5, o6, o7);
  }
}

// ---------------- Node head: node_out = h2 @ Wn + bn; u = h2.We[0:64]; v = h2.We[64:128] ----------------
__global__ __launch_bounds__(256) void head_kernel(const float* __restrict__ h2f,
    const float* __restrict__ Wn, const float* __restrict__ bn, const float* __restrict__ We,
    float* __restrict__ u, float* __restrict__ v, float* __restrict__ node_out){
  __shared__ __align__(16) float sh[8][64];
  int tid = threadIdx.x;
  int nb = blockIdx.x*8;              // 50000/8 = 6250 exact
  {
    float2 t = *(const float2*)(h2f + (size_t)nb*64 + tid*2);
    *(float2*)&sh[tid >> 5][(tid & 31)*2] = t;
  }
  __syncthreads();
  int wave = tid >> 6, lane = tid & 63;
  int sub = lane >> 5, j = lane & 31;
  int local = wave*2 + sub;           // 0..7
  int n = nb + local;
  const float* h = sh[local];
  // node_out = h . Wn[:,j]
  float a = 0.f;
  #pragma unroll 16
  for (int k = 0; k < 64; ++k)
    a = fmaf(h[k], Wn[k*32 + j], a);
  node_out[(size_t)n*32 + j] = a + bn[j];
  // u,v partials over k = j, j+32; butterfly within the 32-lane group
  float pu = h[j]*We[j] + h[j+32]*We[j+32];
  float pv = h[j]*We[64+j] + h[j+32]*We[96+j];
  #pragma unroll
  for (int off = 1; off < 32; off <<= 1) {
    pu += __shfl_xor(pu, off, 64);
    pv += __shfl_xor(pv, off, 64);
  }
  if (j == 0) { u[n] = pu; v[n] = pv; }
}

// ---------------- Edge head: out = u[row] + v[col] + edge_attr . We[128:144] + be ----------------
__global__ __launch_bounds__(256) void edge_kernel(const int* __restrict__ ei, const float* __restrict__ ea,
    const float* __restrict__ u, const float* __restrict__ v,
    const float* __restrict__ We, const float* __restrict__ be, float* __restrict__ out){
  int k = blockIdx.x*256 + threadIdx.x;   // grid is exact: 800000/256
  int r = ei[k], c = ei[N_EDGES + k];
  float val = u[r] + v[c] + be[0];
  const float4* wp = (const float4*)(We + 128);
  const float4* p  = (const float4*)(ea + (size_t)k*16);
  #pragma unroll
  for (int jj = 0; jj < 4; jj++) {
    float4 q = p[jj], wq = wp[jj];
    val = fmaf(q.x, wq.x, val);
    val = fmaf(q.y, wq.y, val);
    val = fmaf(q.z, wq.z, val);
    val = fmaf(q.w, wq.w, val);
  }
  out[k] = val;
}

extern "C" void kernel_launch(void* const* d_in, const int* in_sizes, int n_in,
                              void* d_out, int out_size, void* d_ws, size_t ws_size,
                              hipStream_t stream) {
  const float* x   = (const float*)d_in[0];
  const int*   ei  = (const int*)d_in[1];
  const float* ea  = (const float*)d_in[2];
  const float* W1  = (const float*)d_in[3];
  const float* a1s = (const float*)d_in[4];
  const float* a1d = (const float*)d_in[5];
  const float* b1  = (const float*)d_in[6];
  const float* W2  = (const float*)d_in[7];
  const float* a2s = (const float*)d_in[8];
  const float* a2d = (const float*)d_in[9];
  const float* b2  = (const float*)d_in[10];
  const float* Wn  = (const float*)d_in[11];
  const float* bn  = (const float*)d_in[12];
  const float* We  = (const float*)d_in[13];
  const float* be  = (const float*)d_in[14];
  float* out = (float*)d_out;

  // ---- workspace layout, peak 64,000,224 B, 16B-aligned ----
  char* w = (char*)d_ws;
  int*   offs   = (int*)(w);                        //       0 .. 200,016
  unsigned short* wf1 = (unsigned short*)(w + 200016); // 32,768 B
  float* ws1    = (float*)(w + 232784);             // 1,024 B
  float* wd1    = (float*)(w + 233808);             // 1,024 B
  unsigned short* wf2 = (unsigned short*)(w + 234832); // 32,768 B (.. 267,600)
  int*   bcur   = (int*)(w + 400016);               // 784 B bucket counts
  int*   srcs   = (int*)(w + 600016);               // 600,016 .. 4,000,016
  float* al1s   = (float*)(w + 4000016);            // [N,4] fp32, .. 4,800,016
  float* al1d   = (float*)(w + 4800016);            // [N,4] fp32, .. 5,600,016
  float* al2s   = (float*)(w + 5600016);            // [N] fp32,  .. 5,800,016
  float* al2d   = (float*)(w + 5800016);            // .. 6,000,016
  float* uu     = (float*)(w + 6000016);            // .. 6,200,016
  float* vv     = (float*)(w + 6200016);            // .. 6,400,016
  bf16*  h2pre  = (bf16*)(w + 6400016);             // [N,64] bf16, .. 12,800,016 (xb aliases BEFORE gemm12)
  bf16*  ag     = (bf16*)(w + 12800016);            // [N,256] bf16 aggregate, .. 38,400,016
  unsigned int* pairbuf = (unsigned int*)(w + 38400224); // 6.8 MB bucket regions
  unsigned short* xb  = (unsigned short*)h2pre;     // [N,64] bf16 x-table; dead before gemm12 writes h2pre
  float* h2f = (float*)ag;                          // [N,64] fp32 post-ELU h2 (ag dead after gemm12)

  hipMemsetAsync(bcur, 0, NBUCK*4, stream);
  prep1_kernel  <<<337, 256, 0, stream>>>(W1, W2, a1s, a1d, wf1, wf2, ws1, wd1, ei, bcur, pairbuf);
  prep2_kernel  <<<NBUCK + N_NODES/16, 256, 0, stream>>>(pairbuf, bcur, offs, srcs,
                                                         x, ws1, wd1, xb, al1s, al1d);
  attn1x_kernel <<<N_NODES/4, 256, 0, stream>>>(xb, al1s, al1d, offs, srcs, ag);
  gemm12_kernel <<<(N_NODES + 63)/64, 256, 0, stream>>>((const unsigned short*)ag, wf1, wf2, b1,
                                                        a2s, a2d, h2pre, al2s, al2d);
  attn2_kernel  <<<N_NODES/8, 512, 0, stream>>>(h2pre, al2s, al2d, offs, srcs, b2, h2f);
  head_kernel   <<<N_NODES/8, 256, 0, stream>>>(h2f, Wn, bn, We, uu, vv, out);
  edge_kernel   <<<N_EDGES/256, 256, 0, stream>>>(ei, ea, uu, vv, We, be, out + (size_t)N_NODES*32);
}

// Round 13
// 282.053 us; speedup vs baseline: 1.2000x; 1.0195x over previous
//
#include <hip/hip_runtime.h>
#include <hip/hip_bf16.h>

#define N_NODES 50000
#define N_EDGES 800000
#define N_TOT   850000   // edges + self loops
#define MAXD    128      // LDS-staged edges per node; tail handled by fallback

// bucketed CSR build: bucket = dst >> 8 (256 nodes/bucket)
#define NBUCK 196        // ceil(50000/256)
#define BCAP  8192       // fixed bucket capacity (mean 4337, std ~66 -> 58 sigma slack)
#define A1BLK (N_NODES/4)    // 12500 attn1x blocks
#define EPBLK 782            // ceil(800000/1024) edge-partial blocks appended to attn1x

typedef __hip_bfloat16 bf16;
typedef __attribute__((ext_vector_type(8))) short bf16x8;   // MFMA A/B frag (4 VGPRs)
typedef __attribute__((ext_vector_type(4))) float f32x4;    // MFMA C/D frag

__device__ __forceinline__ unsigned short f2bu(float v){
  union { bf16 b; unsigned short u; } cv; cv.b = __float2bfloat16(v); return cv.u;
}
__device__ __forceinline__ float bflo(unsigned int d){ return __uint_as_float(d << 16); }
__device__ __forceinline__ float bfhi(unsigned int d){ return __uint_as_float(d & 0xffff0000u); }

// ---------------- prep1: W-frag/attn-vector prep (blocks 0..128) || binscatter (blocks 129..336) ----
__global__ __launch_bounds__(256) void prep1_kernel(const float* __restrict__ W1, const float* __restrict__ W2,
    const float* __restrict__ a1s, const float* __restrict__ a1d,
    unsigned short* __restrict__ wf1, unsigned short* __restrict__ wf2,
    float* __restrict__ ws1, float* __restrict__ wd1,
    const int* __restrict__ ei, int* __restrict__ bcur, unsigned int* __restrict__ pairbuf){
  __shared__ int hist[NBUCK];
  __shared__ int gbase[NBUCK];
  int b = blockIdx.x, tid = threadIdx.x;
  if (b < 128) {
    int i = b*256 + tid;   // 32768 threads exact
    if (i < 16384) {
      int k = i >> 8, n = i & 255;
      int kk = k >> 5, qq = (k >> 3) & 3, j = k & 7, nt = n >> 4, cc = n & 15;
      wf1[(((kk*16 + nt)*4 + qq)*16 + cc)*8 + j] = f2bu(W1[i]);
    } else {
      int i2 = i - 16384;
      int k = i2 >> 6, n = i2 & 63;
      int kk = k >> 5, qq = (k >> 3) & 3, j = k & 7, ch = n >> 4, cc = n & 15;
      wf2[(((kk*4 + ch)*4 + qq)*16 + cc)*8 + j] = f2bu(W2[i2]);
    }
  } else if (b == 128) {
    // ws1[k][h] = sum_c W1[k, h*64+c] * a1s[h, c]   (64x4 each)
    int k = tid >> 2, h = tid & 3;
    const float* wrow = W1 + k*256 + h*64;
    const float* as = a1s + h*64;
    const float* ad = a1d + h*64;
    float ss = 0.f, sd = 0.f;
    #pragma unroll 8
    for (int c = 0; c < 64; ++c) {
      float wv = wrow[c];
      ss = fmaf(wv, as[c], ss);
      sd = fmaf(wv, ad[c], sd);
    }
    ws1[k*4 + h] = ss;
    wd1[k*4 + h] = sd;
  } else {
    // ---- binscatter: bin 4096 edges into 196 bucket regions ----
    int bb = b - 129;
    if (tid < NBUCK) hist[tid] = 0;
    __syncthreads();
    int base = bb * 4096;
    #pragma unroll 4
    for (int i = 0; i < 16; ++i) {
      int k = base + i*256 + tid;
      if (k < N_TOT) {
        int c = (k < N_EDGES) ? ei[N_EDGES + k] : (k - N_EDGES);
        atomicAdd(&hist[c >> 8], 1);
      }
    }
    __syncthreads();
    if (tid < NBUCK) {
      int h = hist[tid];
      gbase[tid] = h ? (tid*BCAP + atomicAdd(&bcur[tid], h)) : 0;
      hist[tid] = 0;                       // reuse as local cursor
    }
    __syncthreads();
    #pragma unroll 4
    for (int i = 0; i < 16; ++i) {
      int k = base + i*256 + tid;
      if (k < N_TOT) {
        int r, c;
        if (k < N_EDGES) { r = ei[k]; c = ei[N_EDGES + k]; } else { r = c = k - N_EDGES; }
        int bk = c >> 8;
        int lpos = atomicAdd(&hist[bk], 1);
        pairbuf[gbase[bk] + lpos] = (unsigned)r | ((unsigned)(c & 255) << 16);
      }
    }
  }
}

// ---------------- prep2: lscatter2 (blocks 0..195) || xprep (blocks 196..3320) ----
__global__ __launch_bounds__(256) void prep2_kernel(const unsigned int* __restrict__ pairbuf,
    const int* __restrict__ bcur, int* __restrict__ offs, int* __restrict__ srcs,
    const float* __restrict__ x, const float* __restrict__ ws1, const float* __restrict__ wd1,
    unsigned short* __restrict__ xb, float* __restrict__ al1s, float* __restrict__ al1d){
  __shared__ int sbase[256];       // lscatter2 half
  __shared__ int lhist[256];
  __shared__ int lcur[256];
  __shared__ float sws[64][4], swd[64][4];   // xprep half
  int tid = threadIdx.x;
  if (blockIdx.x < NBUCK) {
    int b = blockIdx.x;
    // redundant 196-bucket scan (cheap; removes separate scan dispatch)
    int sz = 0;
    if (tid < NBUCK) {
      sz = bcur[tid];
      if (sz < 0) sz = 0; if (sz > BCAP) sz = BCAP;
    }
    sbase[tid] = sz;
    lhist[tid] = 0;
    __syncthreads();
    for (int off = 1; off < 256; off <<= 1) {
      int t = (tid >= off) ? sbase[tid - off] : 0;
      __syncthreads();
      sbase[tid] += t;
      __syncthreads();
    }
    int bbase_b = (b == 0) ? 0 : sbase[b - 1];
    int size = sbase[b] - bbase_b;                 // min(bcur[b], BCAP)
    int base = b * BCAP;
    // per-node counts within bucket
    for (int j = tid; j < size; j += 256)
      atomicAdd(&lhist[pairbuf[base + j] >> 16], 1);
    __syncthreads();
    int v = lhist[tid];
    lcur[tid] = v;
    __syncthreads();
    for (int off = 1; off < 256; off <<= 1) {
      int t = (tid >= off) ? lcur[tid - off] : 0;
      __syncthreads();
      lcur[tid] += t;
      __syncthreads();
    }
    int excl = lcur[tid] - v;
    int gpos = bbase_b + excl;
    int node = b*256 + tid;
    if (node < N_NODES) offs[node] = gpos;
    if (b == 0 && tid == 0) offs[N_NODES] = N_TOT;
    __syncthreads();
    lcur[tid] = gpos;       // per-node cursor
    __syncthreads();
    for (int j = tid; j < size; j += 256) {
      unsigned pv = pairbuf[base + j];
      int pos = atomicAdd(&lcur[pv >> 16], 1);
      srcs[pos] = (int)(pv & 0xFFFFu);
    }
  } else {
    // ---- xprep: xb = bf16(x); al1{s,d} = x @ w{s,d}1 ----
    sws[tid >> 2][tid & 3] = ws1[tid];
    swd[tid >> 2][tid & 3] = wd1[tid];
    __syncthreads();
    int lane = tid & 63, wave = tid >> 6;
    int g = lane & 15, sub = lane >> 4;
    int n = (blockIdx.x - NBUCK)*16 + wave*4 + sub;   // 50000/16 = 3125 exact
    float4 xv = *(const float4*)(x + (size_t)n*64 + g*4);
    uint2 dd;
    dd.x = (unsigned)f2bu(xv.x) | ((unsigned)f2bu(xv.y) << 16);
    dd.y = (unsigned)f2bu(xv.z) | ((unsigned)f2bu(xv.w) << 16);
    ((uint2*)xb)[(size_t)n*16 + g] = dd;
    int c0 = g*4;
    float ps0 = 0.f, ps1 = 0.f, ps2 = 0.f, ps3 = 0.f;
    float pd0 = 0.f, pd1 = 0.f, pd2 = 0.f, pd3 = 0.f;
    float xc[4] = {xv.x, xv.y, xv.z, xv.w};
    #pragma unroll
    for (int i = 0; i < 4; ++i) {
      int c = c0 + i;
      ps0 = fmaf(xc[i], sws[c][0], ps0); ps1 = fmaf(xc[i], sws[c][1], ps1);
      ps2 = fmaf(xc[i], sws[c][2], ps2); ps3 = fmaf(xc[i], sws[c][3], ps3);
      pd0 = fmaf(xc[i], swd[c][0], pd0); pd1 = fmaf(xc[i], swd[c][1], pd1);
      pd2 = fmaf(xc[i], swd[c][2], pd2); pd3 = fmaf(xc[i], swd[c][3], pd3);
    }
    #pragma unroll
    for (int off = 1; off < 16; off <<= 1) {
      ps0 += __shfl_xor(ps0, off, 64); ps1 += __shfl_xor(ps1, off, 64);
      ps2 += __shfl_xor(ps2, off, 64); ps3 += __shfl_xor(ps3, off, 64);
      pd0 += __shfl_xor(pd0, off, 64); pd1 += __shfl_xor(pd1, off, 64);
      pd2 += __shfl_xor(pd2, off, 64); pd3 += __shfl_xor(pd3, off, 64);
    }
    if (g < 4)      al1s[(size_t)n*4 + g]       = (g==0)?ps0:(g==1)?ps1:(g==2)?ps2:ps3;
    else if (g < 8) al1d[(size_t)n*4 + (g-4)]   = (g==4)?pd0:(g==5)?pd1:(g==6)?pd2:pd3;
  }
}

// ------- Attention layer 1 in x-space (blocks 0..12499) || edge-partial (blocks 12500..13281) ----
// edge-partial (epart[k] = ea[k].We[128:144] + be) is independent of all other stages; it rides in
// attn1x's spare HBM bandwidth (attn1x is latency-bound at ~27% BW) [R13].
__global__ __launch_bounds__(256, 8) void attn1x_kernel(const unsigned short* __restrict__ xb,
    const float* __restrict__ al1s, const float* __restrict__ al1d,
    const int* __restrict__ offs, const int* __restrict__ srcs,
    bf16* __restrict__ ag,
    const float* __restrict__ ea, const float* __restrict__ We, const float* __restrict__ be,
    float* __restrict__ epart){
  __shared__ __align__(16) float ebuf[4][MAXD+4][4];     // p values, +4 zero pad
  __shared__ int sbuf[4][MAXD+4];

  if (blockIdx.x >= A1BLK) {
    // ---- edge-partial tail blocks: 1024 edges/block, coalesced 64B/thread ----
    int eb = blockIdx.x - A1BLK;
    const float4* wp = (const float4*)(We + 128);
    float4 w0 = wp[0], w1 = wp[1], w2 = wp[2], w3 = wp[3];
    float bee = be[0];
    int base = eb*1024 + (int)threadIdx.x;
    #pragma unroll
    for (int i = 0; i < 4; ++i) {
      int k = base + i*256;
      if (k < N_EDGES) {
        const float4* p = (const float4*)(ea + (size_t)k*16);
        float4 q0 = p[0], q1 = p[1], q2 = p[2], q3 = p[3];
        float val = bee;
        val = fmaf(q0.x, w0.x, val); val = fmaf(q0.y, w0.y, val);
        val = fmaf(q0.z, w0.z, val); val = fmaf(q0.w, w0.w, val);
        val = fmaf(q1.x, w1.x, val); val = fmaf(q1.y, w1.y, val);
        val = fmaf(q1.z, w1.z, val); val = fmaf(q1.w, w1.w, val);
        val = fmaf(q2.x, w2.x, val); val = fmaf(q2.y, w2.y, val);
        val = fmaf(q2.z, w2.z, val); val = fmaf(q2.w, w2.w, val);
        val = fmaf(q3.x, w3.x, val); val = fmaf(q3.y, w3.y, val);
        val = fmaf(q3.z, w3.z, val); val = fmaf(q3.w, w3.w, val);
        epart[k] = val;
      }
    }
    return;
  }

  int wave = threadIdx.x >> 6, lane = threadIdx.x & 63;
  int n = blockIdx.x*4 + wave;          // 50000 % 4 == 0: no tail
  int start = offs[n], end = offs[n+1];
  int deg = end - start;
  int lim = deg < MAXD ? deg : MAXD;
  float4 aldv = *(const float4*)(al1d + (size_t)n*4);
  float ald0 = aldv.x, ald1 = aldv.y, ald2 = aldv.z, ald3 = aldv.w;

  // stage pass: gather als, e=lrelu, p=exp(e); stage p+src; lane sums
  float s0 = 0.f, s1 = 0.f, s2 = 0.f, s3 = 0.f;
  {
    int idx = lane;
    for (int j = start + lane; j < end; j += 64, idx += 64) {
      int r = srcs[j];
      float4 als = *(const float4*)(al1s + (size_t)r*4);
      float e0 = als.x + ald0; e0 = e0 >= 0.f ? e0 : 0.2f*e0; float p0 = __expf(e0); s0 += p0;
      float e1 = als.y + ald1; e1 = e1 >= 0.f ? e1 : 0.2f*e1; float p1 = __expf(e1); s1 += p1;
      float e2 = als.z + ald2; e2 = e2 >= 0.f ? e2 : 0.2f*e2; float p2 = __expf(e2); s2 += p2;
      float e3 = als.w + ald3; e3 = e3 >= 0.f ? e3 : 0.2f*e3; float p3 = __expf(e3); s3 += p3;
      if (idx < MAXD) {
        sbuf[wave][idx] = r;
        *(float4*)&ebuf[wave][idx][0] = make_float4(p0, p1, p2, p3);
      }
    }
  }
  // zero-pad 4 slots past lim: aggregation loop then needs no bounds mask
  if (lane < 4) {
    int ip = lim + lane;
    sbuf[wave][ip] = 0;
    *(float4*)&ebuf[wave][ip][0] = make_float4(0.f, 0.f, 0.f, 0.f);
  }
  #pragma unroll
  for (int off = 32; off; off >>= 1) {
    s0 += __shfl_xor(s0, off, 64);
    s1 += __shfl_xor(s1, off, 64);
    s2 += __shfl_xor(s2, off, 64);
    s3 += __shfl_xor(s3, off, 64);
  }
  float inv0 = 1.f/(s0 + 1e-16f), inv1 = 1.f/(s1 + 1e-16f);
  float inv2 = 1.f/(s2 + 1e-16f), inv3 = 1.f/(s3 + 1e-16f);

  // aggregation: lane -> (edge-slot es=lane>>4 of 4, ch-lane cl=lane&15: ch cl*4..cl*4+3)
  int cl = lane & 15, es = lane >> 4;
  float acc[4][4];
  #pragma unroll
  for (int h = 0; h < 4; ++h)
    #pragma unroll
    for (int i = 0; i < 4; ++i) acc[h][i] = 0.f;
  {
    const uint2* base2 = (const uint2*)xb;   // row = 16 uint2 (128B)
    #pragma unroll 2
    for (int jj = 0; jj < lim; jj += 4) {
      int idx = jj + es;                     // <= lim+2 < lim+4 (padded)
      int r = sbuf[wave][idx];
      float4 pv = *(const float4*)&ebuf[wave][idx][0];
      uint2 d = base2[(size_t)r*16 + cl];
      float c0 = bflo(d.x), c1 = bfhi(d.x), c2 = bflo(d.y), c3 = bfhi(d.y);
      acc[0][0] = fmaf(pv.x, c0, acc[0][0]); acc[0][1] = fmaf(pv.x, c1, acc[0][1]);
      acc[0][2] = fmaf(pv.x, c2, acc[0][2]); acc[0][3] = fmaf(pv.x, c3, acc[0][3]);
      acc[1][0] = fmaf(pv.y, c0, acc[1][0]); acc[1][1] = fmaf(pv.y, c1, acc[1][1]);
      acc[1][2] = fmaf(pv.y, c2, acc[1][2]); acc[1][3] = fmaf(pv.y, c3, acc[1][3]);
      acc[2][0] = fmaf(pv.z, c0, acc[2][0]); acc[2][1] = fmaf(pv.z, c1, acc[2][1]);
      acc[2][2] = fmaf(pv.z, c2, acc[2][2]); acc[2][3] = fmaf(pv.z, c3, acc[2][3]);
      acc[3][0] = fmaf(pv.w, c0, acc[3][0]); acc[3][1] = fmaf(pv.w, c1, acc[3][1]);
      acc[3][2] = fmaf(pv.w, c2, acc[3][2]); acc[3][3] = fmaf(pv.w, c3, acc[3][3]);
    }
  }
  if (deg > MAXD) {       // rare overflow tail: recompute p per lane (masked scalar path)
    const uint2* base2 = (const uint2*)xb;
    for (int jj = MAXD; jj < deg; jj += 4) {
      int idx = jj + es;
      bool ok = idx < deg;
      int j = ok ? (start + idx) : start;
      int r = srcs[j];
      float4 als = *(const float4*)(al1s + (size_t)r*4);
      float e0 = als.x + ald0; e0 = e0 >= 0.f ? e0 : 0.2f*e0; float p0 = __expf(e0);
      float e1 = als.y + ald1; e1 = e1 >= 0.f ? e1 : 0.2f*e1; float p1 = __expf(e1);
      float e2 = als.z + ald2; e2 = e2 >= 0.f ? e2 : 0.2f*e2; float p2 = __expf(e2);
      float e3 = als.w + ald3; e3 = e3 >= 0.f ? e3 : 0.2f*e3; float p3 = __expf(e3);
      float m = ok ? 1.f : 0.f;
      uint2 d = base2[(size_t)r*16 + cl];
      float c0 = bflo(d.x)*m, c1 = bfhi(d.x)*m, c2 = bflo(d.y)*m, c3 = bfhi(d.y)*m;
      acc[0][0] = fmaf(p0, c0, acc[0][0]); acc[0][1] = fmaf(p0, c1, acc[0][1]);
      acc[0][2] = fmaf(p0, c2, acc[0][2]); acc[0][3] = fmaf(p0, c3, acc[0][3]);
      acc[1][0] = fmaf(p1, c0, acc[1][0]); acc[1][1] = fmaf(p1, c1, acc[1][1]);
      acc[1][2] = fmaf(p1, c2, acc[1][2]); acc[1][3] = fmaf(p1, c3, acc[1][3]);
      acc[2][0] = fmaf(p2, c0, acc[2][0]); acc[2][1] = fmaf(p2, c1, acc[2][1]);
      acc[2][2] = fmaf(p2, c2, acc[2][2]); acc[2][3] = fmaf(p2, c3, acc[2][3]);
      acc[3][0] = fmaf(p3, c0, acc[3][0]); acc[3][1] = fmaf(p3, c1, acc[3][1]);
      acc[3][2] = fmaf(p3, c2, acc[3][2]); acc[3][3] = fmaf(p3, c3, acc[3][3]);
    }
  }
  // fold the 4 edge slots (lane bits 4,5)
  #pragma unroll
  for (int h = 0; h < 4; ++h)
    #pragma unroll
    for (int i = 0; i < 4; ++i) {
      acc[h][i] += __shfl_xor(acc[h][i], 16, 64);
      acc[h][i] += __shfl_xor(acc[h][i], 32, 64);
    }
  // lane l writes head h=es, channels cl*4..cl*4+3: ag[n][es*64 + cl*4 ...] (coalesced 512B/row)
  {
    float invh = (es==0)?inv0:(es==1)?inv1:(es==2)?inv2:inv3;
    float o0 = ((es==0)?acc[0][0]:(es==1)?acc[1][0]:(es==2)?acc[2][0]:acc[3][0]) * invh;
    float o1 = ((es==0)?acc[0][1]:(es==1)?acc[1][1]:(es==2)?acc[2][1]:acc[3][1]) * invh;
    float o2 = ((es==0)?acc[0][2]:(es==1)?acc[1][2]:(es==2)?acc[2][2]:acc[3][2]) * invh;
    float o3 = ((es==0)?acc[0][3]:(es==1)?acc[1][3]:(es==2)?acc[2][3]:acc[3][3]) * invh;
    uint2 dd;
    dd.x = (unsigned)f2bu(o0) | ((unsigned)f2bu(o1) << 16);
    dd.y = (unsigned)f2bu(o2) | ((unsigned)f2bu(o3) << 16);
    ((uint2*)ag)[(size_t)n*64 + lane] = dd;
  }
}

// ---------------- Fused GEMM1b+GEMM2 (MFMA): per 64-node tile,
// phase 1: h1_tile = elu(ag @ W1 + b1) -> LDS bf16; phase 2: h2pre = h1_tile @ W2, fused al2.
__global__ __launch_bounds__(256) void gemm12_kernel(const unsigned short* __restrict__ ag,
    const unsigned short* __restrict__ wf1, const unsigned short* __restrict__ wf2,
    const float* __restrict__ b1, const float* __restrict__ a2s, const float* __restrict__ a2d,
    bf16* __restrict__ h2pre, float* __restrict__ al2s, float* __restrict__ al2d){
  __shared__ __align__(16) unsigned short ctile[64*264];      // h1 tile bf16, 33.8KB (264 = 256+8 pad)
  __shared__ __align__(16) float ctile2[64][65];              // h2 f32 transpose buffer, 16.6KB
  int tid = threadIdx.x, wave = tid >> 6, lane = tid & 63;
  int q = lane >> 4, c = lane & 15;
  int n0 = blockIdx.x * 64;

  // ---- phase 1: gemm1b (block-diagonal W1), output to LDS only ----
  {
    union { uint4 u; bf16x8 v; } bfr[2][4];
    #pragma unroll
    for (int kk = 0; kk < 2; ++kk)
      #pragma unroll
      for (int nti = 0; nti < 4; ++nti)
        bfr[kk][nti].u = *(const uint4*)(wf1 + (size_t)((((kk*16 + wave*4 + nti)*4 + q)*16 + c)*8));

    float b1v[4];
    #pragma unroll
    for (int nti = 0; nti < 4; ++nti) b1v[nti] = b1[(wave*4 + nti)*16 + c];

    #pragma unroll 1
    for (int st = 0; st < 4; ++st) {
      int row = n0 + st*16 + c;
      if (row >= N_NODES) row = N_NODES - 1;   // tail clamp; phase-2 stores guarded below
      bf16x8 afr[2];
      #pragma unroll
      for (int kk = 0; kk < 2; ++kk) {
        union { uint4 u; bf16x8 v; } a;
        a.u = *(const uint4*)(ag + (size_t)row*256 + wave*64 + kk*32 + q*8);
        afr[kk] = a.v;
      }
      #pragma unroll
      for (int nti = 0; nti < 4; ++nti) {
        f32x4 acc = {0.f, 0.f, 0.f, 0.f};
        #pragma unroll
        for (int kk = 0; kk < 2; ++kk)
          acc = __builtin_amdgcn_mfma_f32_16x16x32_bf16(afr[kk], bfr[kk][nti].v, acc, 0, 0, 0);
        int lrow = st*16 + q*4, nt = wave*4 + nti;
        #pragma unroll
        for (int r = 0; r < 4; ++r) {
          float o = acc[r] + b1v[nti];
          o = o > 0.f ? o : expm1f(o);
          ctile[(lrow + r)*264 + nt*16 + c] = f2bu(o);
        }
      }
    }
  }
  __syncthreads();

  // ---- phase 2: gemm2 (h1_tile @ W2), A-frags from LDS ----
  {
    union { uint4 u; bf16x8 v; } bfr[8];
    #pragma unroll
    for (int kk = 0; kk < 8; ++kk)
      bfr[kk].u = *(const uint4*)(wf2 + (size_t)((((kk*4 + wave)*4 + q)*16 + c)*8));

    #pragma unroll 1
    for (int st = 0; st < 4; ++st) {
      if (n0 + st*16 >= N_NODES) break;       // block-uniform
      f32x4 acc = {0.f, 0.f, 0.f, 0.f};
      int arow = (st*16 + c)*264 + q*8;
      #pragma unroll
      for (int kk = 0; kk < 8; ++kk) {
        union { uint4 u; bf16x8 v; } a;
        a.u = *(const uint4*)&ctile[arow + kk*32];
        acc = __builtin_amdgcn_mfma_f32_16x16x32_bf16(a.v, bfr[kk].v, acc, 0, 0, 0);
      }
      #pragma unroll
      for (int r = 0; r < 4; ++r)
        ctile2[st*16 + q*4 + r][wave*16 + c] = acc[r];
    }
  }
  __syncthreads();

  float as = a2s[lane], ad = a2d[lane];
  #pragma unroll 1
  for (int i = 0; i < 16; ++i) {
    int node = n0 + wave*16 + i;
    if (node >= N_NODES) break;
    float val = ctile2[wave*16 + i][lane];
    ((unsigned short*)h2pre)[(size_t)node*64 + lane] = f2bu(val);
    float ps = val*as, pd = val*ad;
    #pragma unroll
    for (int off = 32; off; off >>= 1) { ps += __shfl_xor(ps, off, 64); pd += __shfl_xor(pd, off, 64); }
    if (lane == 0) { al2s[node] = ps; al2d[node] = pd; }
  }
}

// ---------------- Attention layer 2 (H=1, no max pass), slim: writes post-ELU h2 (fp32) only ----------------
__global__ __launch_bounds__(512, 8) void attn2_kernel(const bf16* __restrict__ h2pre,
    const float* __restrict__ al2s, const float* __restrict__ al2d,
    const int* __restrict__ offs, const int* __restrict__ srcs,
    const float* __restrict__ b2, float* __restrict__ h2f){
  __shared__ float ebuf[8][MAXD+8];             // p values, +8 zero pad
  __shared__ int   sbuf[8][MAXD+8];
  int wave = threadIdx.x >> 6, lane = threadIdx.x & 63;
  int n = blockIdx.x*8 + wave;        // exact
  int start = offs[n], end = offs[n+1];
  int deg = end - start;
  int lim = deg < MAXD ? deg : MAXD;
  float ald = al2d[n];

  float sm = 0.f;
  {
    int idx = lane;
    for (int j = start + lane; j < end; j += 64, idx += 64) {
      int r = srcs[j];
      float t = al2s[r] + ald; t = t >= 0.f ? t : 0.2f*t;
      float p = __expf(t); sm += p;
      if (idx < MAXD) { sbuf[wave][idx] = r; ebuf[wave][idx] = p; }
    }
  }
  if (lane < 8) { int ip = lim + lane; sbuf[wave][ip] = 0; ebuf[wave][ip] = 0.f; }
  #pragma unroll
  for (int off = 32; off; off >>= 1) sm += __shfl_xor(sm, off, 64);
  float inv = 1.f/(sm + 1e-16f);

  // aggregation: lane -> (edge-slot es=lane>>3, channel-lane cl=lane&7); uint4 = channels cl*8..cl*8+7
  int cl = lane & 7, es = lane >> 3;
  float acc0 = 0.f, acc1 = 0.f, acc2 = 0.f, acc3 = 0.f;
  float acc4 = 0.f, acc5 = 0.f, acc6 = 0.f, acc7 = 0.f;
  {
    const uint4* base4 = (const uint4*)h2pre;   // row = 8 uint4
    #pragma unroll 2
    for (int jj = 0; jj < lim; jj += 8) {
      int idx = jj + es;                        // <= lim+6 < lim+8 (padded)
      int r = sbuf[wave][idx];
      float p = ebuf[wave][idx];
      uint4 d = base4[(size_t)r*8 + cl];
      acc0 = fmaf(p, bflo(d.x), acc0);
      acc1 = fmaf(p, bfhi(d.x), acc1);
      acc2 = fmaf(p, bflo(d.y), acc2);
      acc3 = fmaf(p, bfhi(d.y), acc3);
      acc4 = fmaf(p, bflo(d.z), acc4);
      acc5 = fmaf(p, bfhi(d.z), acc5);
      acc6 = fmaf(p, bflo(d.w), acc6);
      acc7 = fmaf(p, bfhi(d.w), acc7);
    }
  }
  if (deg > MAXD) {     // rare overflow tail
    const uint4* base4 = (const uint4*)h2pre;
    for (int jj = MAXD; jj < deg; jj += 8) {
      int idx = jj + es;
      bool ok = idx < deg;
      int j = ok ? (start + idx) : start;
      int r = srcs[j];
      float t = al2s[r] + ald; t = t >= 0.f ? t : 0.2f*t;
      float p = ok ? __expf(t) : 0.f;
      uint4 d = base4[(size_t)r*8 + cl];
      acc0 = fmaf(p, bflo(d.x), acc0);
      acc1 = fmaf(p, bfhi(d.x), acc1);
      acc2 = fmaf(p, bflo(d.y), acc2);
      acc3 = fmaf(p, bfhi(d.y), acc3);
      acc4 = fmaf(p, bflo(d.z), acc4);
      acc5 = fmaf(p, bfhi(d.z), acc5);
      acc6 = fmaf(p, bflo(d.w), acc6);
      acc7 = fmaf(p, bfhi(d.w), acc7);
    }
  }
  // fold the 8 edge-slots (xor butterfly over lane bits 3,4,5)
  #pragma unroll
  for (int off = 8; off < 64; off <<= 1) {
    acc0 += __shfl_xor(acc0, off, 64);
    acc1 += __shfl_xor(acc1, off, 64);
    acc2 += __shfl_xor(acc2, off, 64);
    acc3 += __shfl_xor(acc3, off, 64);
    acc4 += __shfl_xor(acc4, off, 64);
    acc5 += __shfl_xor(acc5, off, 64);
    acc6 += __shfl_xor(acc6, off, 64);
    acc7 += __shfl_xor(acc7, off, 64);
  }

  if (es == 0) {
    float4 b2a = *(const float4*)(b2 + cl*8);
    float4 b2b = *(const float4*)(b2 + cl*8 + 4);
    float o0 = acc0*inv + b2a.x; o0 = o0 > 0.f ? o0 : expm1f(o0);
    float o1 = acc1*inv + b2a.y; o1 = o1 > 0.f ? o1 : expm1f(o1);
    float o2 = acc2*inv + b2a.z; o2 = o2 > 0.f ? o2 : expm1f(o2);
    float o3 = acc3*inv + b2a.w; o3 = o3 > 0.f ? o3 : expm1f(o3);
    float o4 = acc4*inv + b2b.x; o4 = o4 > 0.f ? o4 : expm1f(o4);
    float o5 = acc5*inv + b2b.y; o5 = o5 > 0.f ? o5 : expm1f(o5);
    float o6 = acc6*inv + b2b.z; o6 = o6 > 0.f ? o6 : expm1f(o6);
    float o7 = acc7*inv + b2b.w; o7 = o7 > 0.f ? o7 : expm1f(o7);
    *(float4*)(h2f + (size_t)n*64 + cl*8)     = make_float4(o0, o1, o2, o3);
    *(float4*)(h2f + (size_t)n*64 + cl*8 + 4) = make_float4(o4, o5, o6, o7);
  }
}

// ---------------- Node head: node_out = h2 @ Wn + bn; u = h2.We[0:64]; v = h2.We[64:128] ----------------
__global__ __launch_bounds__(256) void head_kernel(const float* __restrict__ h2f,
    const float* __restrict__ Wn, const float* __restrict__ bn, const float* __restrict__ We,
    float* __restrict__ u, float* __restrict__ v, float* __restrict__ node_out){
  __shared__ __align__(16) float sh[8][64];
  int tid = threadIdx.x;
  int nb = blockIdx.x*8;              // 50000/8 = 6250 exact
  {
    float2 t = *(const float2*)(h2f + (size_t)nb*64 + tid*2);
    *(float2*)&sh[tid >> 5][(tid & 31)*2] = t;
  }
  __syncthreads();
  int wave = tid >> 6, lane = tid & 63;
  int sub = lane >> 5, j = lane & 31;
  int local = wave*2 + sub;           // 0..7
  int n = nb + local;
  const float* h = sh[local];
  // node_out = h . Wn[:,j]
  float a = 0.f;
  #pragma unroll 16
  for (int k = 0; k < 64; ++k)
    a = fmaf(h[k], Wn[k*32 + j], a);
  node_out[(size_t)n*32 + j] = a + bn[j];
  // u,v partials over k = j, j+32; butterfly within the 32-lane group
  float pu = h[j]*We[j] + h[j+32]*We[j+32];
  float pv = h[j]*We[64+j] + h[j+32]*We[96+j];
  #pragma unroll
  for (int off = 1; off < 32; off <<= 1) {
    pu += __shfl_xor(pu, off, 64);
    pv += __shfl_xor(pv, off, 64);
  }
  if (j == 0) { u[n] = pu; v[n] = pv; }
}

// ---------------- Edge head (slim): out = u[row] + v[col] + epart[k] ----------------
__global__ __launch_bounds__(256) void edge_kernel(const int* __restrict__ ei,
    const float* __restrict__ u, const float* __restrict__ v,
    const float* __restrict__ epart, float* __restrict__ out){
  int k = blockIdx.x*256 + threadIdx.x;   // grid is exact: 800000/256
  int r = ei[k], c = ei[N_EDGES + k];
  out[k] = u[r] + v[c] + epart[k];
}

extern "C" void kernel_launch(void* const* d_in, const int* in_sizes, int n_in,
                              void* d_out, int out_size, void* d_ws, size_t ws_size,
                              hipStream_t stream) {
  const float* x   = (const float*)d_in[0];
  const int*   ei  = (const int*)d_in[1];
  const float* ea  = (const float*)d_in[2];
  const float* W1  = (const float*)d_in[3];
  const float* a1s = (const float*)d_in[4];
  const float* a1d = (const float*)d_in[5];
  const float* b1  = (const float*)d_in[6];
  const float* W2  = (const float*)d_in[7];
  const float* a2s = (const float*)d_in[8];
  const float* a2d = (const float*)d_in[9];
  const float* b2  = (const float*)d_in[10];
  const float* Wn  = (const float*)d_in[11];
  const float* bn  = (const float*)d_in[12];
  const float* We  = (const float*)d_in[13];
  const float* be  = (const float*)d_in[14];
  float* out = (float*)d_out;

  // ---- workspace layout, peak 64,000,224 B, 16B-aligned ----
  char* w = (char*)d_ws;
  int*   offs   = (int*)(w);                        //       0 .. 200,016
  unsigned short* wf1 = (unsigned short*)(w + 200016); // 32,768 B
  float* ws1    = (float*)(w + 232784);             // 1,024 B
  float* wd1    = (float*)(w + 233808);             // 1,024 B
  unsigned short* wf2 = (unsigned short*)(w + 234832); // 32,768 B (.. 267,600)
  int*   bcur   = (int*)(w + 400016);               // 784 B bucket counts
  int*   srcs   = (int*)(w + 600016);               // 600,016 .. 4,000,016
  float* al1s   = (float*)(w + 4000016);            // [N,4] fp32, .. 4,800,016
  float* al1d   = (float*)(w + 4800016);            // [N,4] fp32, .. 5,600,016
  float* al2s   = (float*)(w + 5600016);            // [N] fp32,  .. 5,800,016
  float* al2d   = (float*)(w + 5800016);            // .. 6,000,016
  float* uu     = (float*)(w + 6000016);            // .. 6,200,016
  float* vv     = (float*)(w + 6200016);            // .. 6,400,016
  bf16*  h2pre  = (bf16*)(w + 6400016);             // [N,64] bf16, .. 12,800,016 (xb aliases BEFORE gemm12)
  bf16*  ag     = (bf16*)(w + 12800016);            // [N,256] bf16 aggregate, .. 38,400,016
  unsigned int* pairbuf = (unsigned int*)(w + 38400224); // 6.4 MB bucket regions .. 44,822,752
  float* epart  = (float*)(w + 48000000);           // [E] fp32 edge partial, .. 51,200,000
  unsigned short* xb  = (unsigned short*)h2pre;     // [N,64] bf16 x-table; dead before gemm12 writes h2pre
  float* h2f = (float*)ag;                          // [N,64] fp32 post-ELU h2 (ag dead after gemm12)

  hipMemsetAsync(bcur, 0, NBUCK*4, stream);
  prep1_kernel  <<<337, 256, 0, stream>>>(W1, W2, a1s, a1d, wf1, wf2, ws1, wd1, ei, bcur, pairbuf);
  prep2_kernel  <<<NBUCK + N_NODES/16, 256, 0, stream>>>(pairbuf, bcur, offs, srcs,
                                                         x, ws1, wd1, xb, al1s, al1d);
  attn1x_kernel <<<A1BLK + EPBLK, 256, 0, stream>>>(xb, al1s, al1d, offs, srcs, ag,
                                                    ea, We, be, epart);
  gemm12_kernel <<<(N_NODES + 63)/64, 256, 0, stream>>>((const unsigned short*)ag, wf1, wf2, b1,
                                                        a2s, a2d, h2pre, al2s, al2d);
  attn2_kernel  <<<N_NODES/8, 512, 0, stream>>>(h2pre, al2s, al2d, offs, srcs, b2, h2f);
  head_kernel   <<<N_NODES/8, 256, 0, stream>>>(h2f, Wn, bn, We, uu, vv, out);
  edge_kernel   <<<N_EDGES/256, 256, 0, stream>>>(ei, uu, vv, epart, out + (size_t)N_NODES*32);
}